// Round 1
// baseline (276.517 us; speedup 1.0000x reference)
//
#include <hip/hip_runtime.h>

// DualAttention: B=4, N=1024, QN=512, C=1024, H=16, D=64
// All GEMM contractions K=1024 (token-dim C) or attention-shaped (D=64 / keys).
// Strategy: cast to bf16, MFMA 16x16x32 bf16 everywhere, fp32 softmax.

using bf16 = __bf16;
typedef __bf16 bf16x4 __attribute__((ext_vector_type(4)));
typedef __bf16 bf16x8 __attribute__((ext_vector_type(8)));
typedef float  f32x4  __attribute__((ext_vector_type(4)));

#define MFMA16(a, b, c) __builtin_amdgcn_mfma_f32_16x16x32_bf16((a), (b), (c), 0, 0, 0)

// XOR swizzle for 128B LDS rows: spread 16-lane row-strided reads across banks.
__device__ __forceinline__ int swz128(int row) { return ((row ^ (row >> 3)) & 7) << 4; }

__device__ __forceinline__ void gl_lds16(const void* g, void* l) {
  __builtin_amdgcn_global_load_lds(
      (const __attribute__((address_space(1))) unsigned int*)g,
      (__attribute__((address_space(3))) unsigned int*)l, 16, 0, 0);
}

// ---------------------------------------------------------------- cast fp32->bf16
__global__ void k_cast(const float* __restrict__ in, bf16* __restrict__ out, int n) {
  int stride = gridDim.x * blockDim.x * 4;
  for (int i = (blockIdx.x * blockDim.x + threadIdx.x) * 4; i < n; i += stride) {
    float4 v = *(const float4*)(in + i);
    bf16x4 o;
    o[0] = (bf16)v.x; o[1] = (bf16)v.y; o[2] = (bf16)v.z; o[3] = (bf16)v.w;
    *(bf16x4*)(out + i) = o;
  }
}

// ---------------------------------------------------------------- GEMM  C[M,N] = A[M,K] * B[N,K]^T
// A row-major [M][1024] bf16, B row-major [N][1024] bf16 (weights).
// 128x128 tile, BK=64, 256 threads (4 waves, 2x2), per-wave 64x64 = 4x4 frags.
template<int N, bool OBF>
__global__ __launch_bounds__(256)
void k_gemm(const bf16* __restrict__ A, const bf16* __restrict__ B,
            void* __restrict__ Cp, const float* __restrict__ bias) {
  constexpr int K = 1024;
  __shared__ bf16 As[128 * 64];
  __shared__ bf16 Bs[128 * 64];
  const int tid = threadIdx.x;
  const int lane = tid & 63, w = tid >> 6;
  const int wr = w >> 1, wc = w & 1;
  const int nbx = N / 128;
  const int tm = (blockIdx.x / nbx) * 128, tn = (blockIdx.x % nbx) * 128;
  const int r0 = lane & 15, kg = lane >> 4;
  f32x4 acc[4][4] = {};
  for (int kk = 0; kk < K; kk += 64) {
    // stage A,B tiles: linear LDS dest (wave-uniform base + lane*16), source
    // pre-swizzled so that swizzled ds_read returns logical data (rule #21).
#pragma unroll
    for (int i = 0; i < 4; i++) {
      int c = i * 256 + tid;
      int row = c >> 3, kb = c & 7;
      int sb = (kb ^ ((row ^ (row >> 3)) & 7)) * 8;  // element offset in row
      gl_lds16(A + (size_t)(tm + row) * K + kk + sb, (char*)As + c * 16);
      gl_lds16(B + (size_t)(tn + row) * K + kk + sb, (char*)Bs + c * 16);
    }
    __syncthreads();
#pragma unroll
    for (int ks = 0; ks < 2; ks++) {
      bf16x8 af[4], bfv[4];
#pragma unroll
      for (int f = 0; f < 4; f++) {
        int rowa = wr * 64 + f * 16 + r0;
        af[f] = *(const bf16x8*)((const char*)As +
                                 ((rowa * 128 + ks * 64 + kg * 16) ^ swz128(rowa)));
        int rowb = wc * 64 + f * 16 + r0;
        bfv[f] = *(const bf16x8*)((const char*)Bs +
                                  ((rowb * 128 + ks * 64 + kg * 16) ^ swz128(rowb)));
      }
#pragma unroll
      for (int mf = 0; mf < 4; mf++)
#pragma unroll
        for (int nf = 0; nf < 4; nf++)
          acc[mf][nf] = MFMA16(af[mf], bfv[nf], acc[mf][nf]);
    }
    __syncthreads();
  }
  // epilogue: C/D layout col=lane&15, row=(lane>>4)*4+reg (m89-verified)
#pragma unroll
  for (int mf = 0; mf < 4; mf++)
#pragma unroll
    for (int j = 0; j < 4; j++) {
      int row = tm + wr * 64 + mf * 16 + kg * 4 + j;
#pragma unroll
      for (int nf = 0; nf < 4; nf++) {
        int col = tn + wc * 64 + nf * 16 + r0;
        float v = acc[mf][nf][j];
        if constexpr (OBF) {
          ((bf16*)Cp)[(size_t)row * N + col] = (bf16)v;
        } else {
          if (bias) v += bias[col];
          ((float*)Cp)[(size_t)row * N + col] = v;
        }
      }
    }
}

// ---------------------------------------------------------------- flash attention pass
// One online-softmax pass over `ntiles` KV tiles of 64 keys. Block = 4 waves,
// each wave owns 16 q-rows. qf = pre-scaled Q fragments (d=0..31, 32..63).
// Kg/Vg: global row pointers for key-token 0 (row stride = kstride/vstride elems).
__device__ __forceinline__ void attn_pass(
    const bf16* __restrict__ Kg, int kstride,
    const bf16* __restrict__ Vg, int vstride,
    int ntiles, const bf16x8* qf,
    bf16* Ks, bf16* Vs, bf16* Pw, int lane,
    f32x4* o, float* m, float* rs) {
  const int r0 = lane & 15, kg = lane >> 4;
  for (int t = 0; t < ntiles; t++) {
    const bf16* Kt = Kg + (size_t)t * 64 * kstride;
    const bf16* Vt = Vg + (size_t)t * 64 * vstride;
    // ---- stage: K via gload_lds (pre-swizzled src), V transposed [d][key]
#pragma unroll
    for (int i = 0; i < 2; i++) {
      int c = i * 256 + (int)threadIdx.x;  // 512 chunks of 16B
      int key = c >> 3, kb = c & 7;
      int sb = (kb ^ ((key ^ (key >> 3)) & 7)) * 8;
      gl_lds16(Kt + (size_t)key * kstride + sb, (char*)Ks + c * 16);
      bf16x8 v = *(const bf16x8*)(Vt + (size_t)key * vstride + kb * 8);
#pragma unroll
      for (int e = 0; e < 8; e++) {
        int d = kb * 8 + e;
        int addr = (d * 128 + key * 2) ^ swz128(d);
        *(bf16*)((char*)Vs + addr) = v[e];
      }
    }
    __syncthreads();
    // ---- S = Q K^T (pre-scaled): 4 key-subtiles x 2 d-halves
    f32x4 s[4];
#pragma unroll
    for (int t4 = 0; t4 < 4; t4++) {
      s[t4] = f32x4{0.f, 0.f, 0.f, 0.f};
#pragma unroll
      for (int ss = 0; ss < 2; ss++) {
        int row = t4 * 16 + r0;
        bf16x8 kf = *(const bf16x8*)((const char*)Ks +
                                     ((row * 128 + ss * 64 + kg * 16) ^ swz128(row)));
        s[t4] = MFMA16(qf[ss], kf, s[t4]);
      }
    }
    // ---- online softmax (rows r = kg*4 + reg; 16-lane groups share rows)
    float fac[4];
#pragma unroll
    for (int r = 0; r < 4; r++) {
      float v = fmaxf(fmaxf(s[0][r], s[1][r]), fmaxf(s[2][r], s[3][r]));
#pragma unroll
      for (int off = 1; off < 16; off <<= 1) v = fmaxf(v, __shfl_xor(v, off));
      float mn = fmaxf(m[r], v);
      fac[r] = __expf(m[r] - mn);
      m[r] = mn;
    }
    float tsum[4] = {0.f, 0.f, 0.f, 0.f};
#pragma unroll
    for (int t4 = 0; t4 < 4; t4++)
#pragma unroll
      for (int r = 0; r < 4; r++) {
        float p = __expf(s[t4][r] - m[r]);
        tsum[r] += p;
        int row = kg * 4 + r;
        int addr = (row * 128 + (t4 * 16 + r0) * 2) ^ swz128(row);
        *(bf16*)((char*)Pw + addr) = (bf16)p;
      }
#pragma unroll
    for (int r = 0; r < 4; r++) {
      float v = tsum[r];
#pragma unroll
      for (int off = 1; off < 16; off <<= 1) v += __shfl_xor(v, off);
      rs[r] = rs[r] * fac[r] + v;
    }
#pragma unroll
    for (int dt = 0; dt < 4; dt++)
#pragma unroll
      for (int r = 0; r < 4; r++) o[dt][r] *= fac[r];
    // ---- O += P V
    bf16x8 pf[2];
#pragma unroll
    for (int ks2 = 0; ks2 < 2; ks2++)
      pf[ks2] = *(const bf16x8*)((const char*)Pw +
                                 ((r0 * 128 + ks2 * 64 + kg * 16) ^ swz128(r0)));
#pragma unroll
    for (int dt = 0; dt < 4; dt++)
#pragma unroll
      for (int ks2 = 0; ks2 < 2; ks2++) {
        int d = dt * 16 + r0;
        bf16x8 vf = *(const bf16x8*)((const char*)Vs +
                                     ((d * 128 + ks2 * 64 + kg * 16) ^ swz128(d)));
        o[dt] = MFMA16(pf[ks2], vf, o[dt]);
      }
    __syncthreads();
  }
}

// ---------------------------------------------------------------- self attention
// QKV: [4096][3072] bf16, col = s*1024 + h*64 + d. Out xat: [4096][1024] bf16.
__global__ __launch_bounds__(256)
void k_attn_self(const bf16* __restrict__ QKV, bf16* __restrict__ xat) {
  __shared__ bf16 Ks[64 * 64], Vs[64 * 64], Pl[4][16 * 64];
  const int qt = blockIdx.x, bh = blockIdx.y;
  const int b = bh >> 4, h = bh & 15;
  const int tid = threadIdx.x, lane = tid & 63, w = tid >> 6;
  const int r0 = lane & 15, kg = lane >> 4;
  const int qtok = b * 1024 + qt * 64 + w * 16;
  bf16x8 qf[2];
#pragma unroll
  for (int ss = 0; ss < 2; ss++) {
    qf[ss] = *(const bf16x8*)(QKV + (size_t)(qtok + r0) * 3072 + h * 64 + ss * 32 + kg * 8);
#pragma unroll
    for (int e = 0; e < 8; e++) qf[ss][e] = (bf16)((float)qf[ss][e] * 0.125f);  // exact
  }
  f32x4 o[4] = {};
  float m[4] = {-__builtin_inff(), -__builtin_inff(), -__builtin_inff(), -__builtin_inff()};
  float rs[4] = {};
  attn_pass(QKV + (size_t)(b * 1024) * 3072 + 1024 + h * 64, 3072,
            QKV + (size_t)(b * 1024) * 3072 + 2048 + h * 64, 3072,
            16, qf, Ks, Vs, Pl[w], lane, o, m, rs);
#pragma unroll
  for (int dt = 0; dt < 4; dt++)
#pragma unroll
    for (int r = 0; r < 4; r++) {
      int tok = qtok + kg * 4 + r;
      xat[(size_t)tok * 1024 + h * 64 + dt * 16 + r0] = (bf16)(o[dt][r] / rs[r]);
    }
}

// ---------------------------------------------------------------- cross attention
// Split softmax: q_attn = tanh(gate[h]) * softmax(QQ·xk0)·xv0 + softmax(QQ·qk)·qv.
// Segments have independent softmaxes, so no concat needed. gate==0 -> skip seg A.
__global__ __launch_bounds__(256)
void k_attn_cross(const bf16* __restrict__ QQKV, const bf16* __restrict__ KV0,
                  const float* __restrict__ gate, bf16* __restrict__ qat) {
  __shared__ bf16 Ks[64 * 64], Vs[64 * 64], Pl[4][16 * 64];
  const int qt = blockIdx.x, bh = blockIdx.y;
  const int b = bh >> 4, h = bh & 15;
  const int tid = threadIdx.x, lane = tid & 63, w = tid >> 6;
  const int r0 = lane & 15, kg = lane >> 4;
  const int qtok = b * 512 + qt * 64 + w * 16;
  bf16x8 qf[2];
#pragma unroll
  for (int ss = 0; ss < 2; ss++) {
    qf[ss] = *(const bf16x8*)(QQKV + (size_t)(qtok + r0) * 3072 + h * 64 + ss * 32 + kg * 8);
#pragma unroll
    for (int e = 0; e < 8; e++) qf[ss][e] = (bf16)((float)qf[ss][e] * 0.125f);
  }
  const float g = tanhf(gate[h]);  // block-uniform
  f32x4 oA[4] = {};
  float mA[4] = {-__builtin_inff(), -__builtin_inff(), -__builtin_inff(), -__builtin_inff()};
  float rsA[4] = {};
  if (g != 0.0f) {
    attn_pass(KV0 + (size_t)(b * 1024) * 2048 + h * 64, 2048,
              KV0 + (size_t)(b * 1024) * 2048 + 1024 + h * 64, 2048,
              16, qf, Ks, Vs, Pl[w], lane, oA, mA, rsA);
  }
  f32x4 oB[4] = {};
  float mB[4] = {-__builtin_inff(), -__builtin_inff(), -__builtin_inff(), -__builtin_inff()};
  float rsB[4] = {};
  attn_pass(QQKV + (size_t)(b * 512) * 3072 + 1024 + h * 64, 3072,
            QQKV + (size_t)(b * 512) * 3072 + 2048 + h * 64, 3072,
            8, qf, Ks, Vs, Pl[w], lane, oB, mB, rsB);
#pragma unroll
  for (int dt = 0; dt < 4; dt++)
#pragma unroll
    for (int r = 0; r < 4; r++) {
      int tok = qtok + kg * 4 + r;
      float v = oB[dt][r] / rsB[r];
      if (g != 0.0f) v += g * (oA[dt][r] / rsA[r]);
      qat[(size_t)tok * 1024 + h * 64 + dt * 16 + r0] = (bf16)v;
    }
}

// ---------------------------------------------------------------- launch
extern "C" void kernel_launch(void* const* d_in, const int* in_sizes, int n_in,
                              void* d_out, int out_size, void* d_ws, size_t ws_size,
                              hipStream_t stream) {
  (void)in_sizes; (void)n_in; (void)out_size; (void)ws_size;
  const float* x       = (const float*)d_in[0];
  const float* query   = (const float*)d_in[1];
  const float* w_qkv   = (const float*)d_in[2];
  const float* w_kv    = (const float*)d_in[3];
  const float* w_qlin  = (const float*)d_in[4];
  const float* gate    = (const float*)d_in[5];
  const float* w_proj  = (const float*)d_in[6];
  const float* b_proj  = (const float*)d_in[7];
  const float* w_qproj = (const float*)d_in[8];
  const float* b_qproj = (const float*)d_in[9];
  float* out = (float*)d_out;

  bf16* p = (bf16*)d_ws;
  bf16* xb = p;      p += (size_t)4096 * 1024;
  bf16* qb = p;      p += (size_t)2048 * 1024;
  bf16* wqkvb = p;   p += (size_t)3072 * 1024;
  bf16* wkvb = p;    p += (size_t)2048 * 1024;
  bf16* wqlinb = p;  p += (size_t)3072 * 1024;
  bf16* wprojb = p;  p += (size_t)1024 * 1024;
  bf16* wqprojb = p; p += (size_t)1024 * 1024;
  bf16* QKV = p;     p += (size_t)4096 * 3072;
  bf16* KV0 = p;     p += (size_t)4096 * 2048;
  bf16* QQKV = p;    p += (size_t)2048 * 3072;
  bf16* xat = p;     p += (size_t)4096 * 1024;
  bf16* qat = p;     p += (size_t)2048 * 1024;

  auto cast = [&](const float* in, bf16* o, int n) {
    int blocks = (n / 4 + 255) / 256;
    if (blocks > 2048) blocks = 2048;
    k_cast<<<blocks, 256, 0, stream>>>(in, o, n);
  };
  cast(x, xb, 4096 * 1024);
  cast(query, qb, 2048 * 1024);
  cast(w_qkv, wqkvb, 3072 * 1024);
  cast(w_kv, wkvb, 2048 * 1024);
  cast(w_qlin, wqlinb, 3072 * 1024);
  cast(w_proj, wprojb, 1024 * 1024);
  cast(w_qproj, wqprojb, 1024 * 1024);

  k_gemm<3072, true><<<dim3(32 * 24), 256, 0, stream>>>(xb, wqkvb, QKV, nullptr);
  k_gemm<2048, true><<<dim3(32 * 16), 256, 0, stream>>>(xb, wkvb, KV0, nullptr);
  k_gemm<3072, true><<<dim3(16 * 24), 256, 0, stream>>>(qb, wqlinb, QQKV, nullptr);

  k_attn_self<<<dim3(16, 64), 256, 0, stream>>>(QKV, xat);
  k_attn_cross<<<dim3(8, 64), 256, 0, stream>>>(QQKV, KV0, gate, qat);

  k_gemm<1024, false><<<dim3(32 * 8), 256, 0, stream>>>(xat, wprojb, out, b_proj);
  k_gemm<1024, false><<<dim3(16 * 8), 256, 0, stream>>>(qat, wqprojb, out + (size_t)4096 * 1024, b_qproj);
}

// Round 2
// 244.254 us; speedup vs baseline: 1.1321x; 1.1321x over previous
//
#include <hip/hip_runtime.h>

// DualAttention: B=4, N=1024, QN=512, C=1024, H=16, D=64
// bf16 MFMA everywhere, fp32 softmax. Attention uses swapped-QK^T (S^T =
// mfma(K,Q)) so softmax is in-register per-lane; P rebuilt into PV A-frags
// via one shfl_xor(32) exchange (no P LDS round trip).

using bf16 = __bf16;
typedef __bf16 bf16x4 __attribute__((ext_vector_type(4)));
typedef __bf16 bf16x8 __attribute__((ext_vector_type(8)));
typedef float  f32x4  __attribute__((ext_vector_type(4)));
typedef float  f32x16 __attribute__((ext_vector_type(16)));
typedef unsigned int u32x4 __attribute__((ext_vector_type(4)));

#define MFMA16(a, b, c) __builtin_amdgcn_mfma_f32_16x16x32_bf16((a), (b), (c), 0, 0, 0)
#define MFMA32(a, b, c) __builtin_amdgcn_mfma_f32_32x32x16_bf16((a), (b), (c), 0, 0, 0)

// XOR swizzle for 128B LDS rows: spread row-strided 16B reads across banks.
__device__ __forceinline__ int swz128(int row) { return ((row ^ (row >> 3)) & 7) << 4; }

__device__ __forceinline__ void gl_lds16(const void* g, void* l) {
  __builtin_amdgcn_global_load_lds(
      (const __attribute__((address_space(1))) unsigned int*)g,
      (__attribute__((address_space(3))) unsigned int*)l, 16, 0, 0);
}

__device__ __forceinline__ unsigned pack2(float a, float b) {
  unsigned short ua = __builtin_bit_cast(unsigned short, (bf16)a);
  unsigned short ub = __builtin_bit_cast(unsigned short, (bf16)b);
  return (unsigned)ua | ((unsigned)ub << 16);
}

// ---------------------------------------------------------------- cast fp32->bf16
__global__ void k_cast(const float* __restrict__ in, bf16* __restrict__ out, int n) {
  int stride = gridDim.x * blockDim.x * 4;
  for (int i = (blockIdx.x * blockDim.x + threadIdx.x) * 4; i < n; i += stride) {
    float4 v = *(const float4*)(in + i);
    bf16x4 o;
    o[0] = (bf16)v.x; o[1] = (bf16)v.y; o[2] = (bf16)v.z; o[3] = (bf16)v.w;
    *(bf16x4*)(out + i) = o;
  }
}

// ---------------------------------------------------------------- GEMM  C[M,N] = A[M,K] * B[N,K]^T
// (unchanged from round 1: 128x128 tile, BK=64, 4 waves, gl_lds + swizzle)
template<int N, bool OBF>
__global__ __launch_bounds__(256)
void k_gemm(const bf16* __restrict__ A, const bf16* __restrict__ B,
            void* __restrict__ Cp, const float* __restrict__ bias) {
  constexpr int K = 1024;
  __shared__ bf16 As[128 * 64];
  __shared__ bf16 Bs[128 * 64];
  const int tid = threadIdx.x;
  const int lane = tid & 63, w = tid >> 6;
  const int wr = w >> 1, wc = w & 1;
  const int nbx = N / 128;
  const int tm = (blockIdx.x / nbx) * 128, tn = (blockIdx.x % nbx) * 128;
  const int r0 = lane & 15, kg = lane >> 4;
  f32x4 acc[4][4] = {};
  for (int kk = 0; kk < K; kk += 64) {
#pragma unroll
    for (int i = 0; i < 4; i++) {
      int c = i * 256 + tid;
      int row = c >> 3, kb = c & 7;
      int sb = (kb ^ ((row ^ (row >> 3)) & 7)) * 8;
      gl_lds16(A + (size_t)(tm + row) * K + kk + sb, (char*)As + c * 16);
      gl_lds16(B + (size_t)(tn + row) * K + kk + sb, (char*)Bs + c * 16);
    }
    __syncthreads();
#pragma unroll
    for (int ks = 0; ks < 2; ks++) {
      bf16x8 af[4], bfv[4];
#pragma unroll
      for (int f = 0; f < 4; f++) {
        int rowa = wr * 64 + f * 16 + r0;
        af[f] = *(const bf16x8*)((const char*)As +
                                 ((rowa * 128 + ks * 64 + kg * 16) ^ swz128(rowa)));
        int rowb = wc * 64 + f * 16 + r0;
        bfv[f] = *(const bf16x8*)((const char*)Bs +
                                  ((rowb * 128 + ks * 64 + kg * 16) ^ swz128(rowb)));
      }
#pragma unroll
      for (int mf = 0; mf < 4; mf++)
#pragma unroll
        for (int nf = 0; nf < 4; nf++)
          acc[mf][nf] = MFMA16(af[mf], bfv[nf], acc[mf][nf]);
    }
    __syncthreads();
  }
#pragma unroll
  for (int mf = 0; mf < 4; mf++)
#pragma unroll
    for (int j = 0; j < 4; j++) {
      int row = tm + wr * 64 + mf * 16 + kg * 4 + j;
#pragma unroll
      for (int nf = 0; nf < 4; nf++) {
        int col = tn + wc * 64 + nf * 16 + r0;
        float v = acc[mf][nf][j];
        if constexpr (OBF) {
          ((bf16*)Cp)[(size_t)row * N + col] = (bf16)v;
        } else {
          if (bias) v += bias[col];
          ((float*)Cp)[(size_t)row * N + col] = v;
        }
      }
    }
}

// ---------------------------------------------------------------- flash attention pass (32x32 MFMA)
// Each wave owns 32 q-rows (q = lane&31). S^T = mfma(K,Q): lane holds the
// 64-key P-row half for its q (pair lane^32 holds other half's quads).
// Softmax in-register; one shfl_xor(32) per quad-pair rebuilds PV A-frags.
template<int NT>  // block threads
__device__ __forceinline__ void attn_pass32(
    const bf16* __restrict__ Kg, int kstride,
    const bf16* __restrict__ Vg, int vstride,
    int ntiles, const bf16x8* qf, bf16* Ks, bf16* Vt,  // Ks,Vt: [2][4096] bf16
    f32x16* o, float& m, float& rs) {
  const int tid = threadIdx.x;
  const int lane = tid & 63;
  const int lq = lane & 31, kg2 = lane >> 5;

  uint4 vreg[256 / NT][2];

  auto stageK = [&](const bf16* Kt, bf16* dst) {
#pragma unroll
    for (int i = 0; i < 512 / NT; i++) {
      int c = i * NT + tid;
      int key = c >> 3, kb = c & 7;
      int sb = (kb ^ ((key ^ (key >> 3)) & 7)) * 8;  // pre-swizzled source
      gl_lds16(Kt + (size_t)key * kstride + sb, (char*)dst + c * 16);
    }
  };
  auto loadV = [&](const bf16* Vtg) {
#pragma unroll
    for (int i = 0; i < 256 / NT; i++) {
      int c = i * NT + tid;
      int kp = c >> 3, ob = c & 7;
      vreg[i][0] = *(const uint4*)(Vtg + (size_t)(2 * kp) * vstride + ob * 8);
      vreg[i][1] = *(const uint4*)(Vtg + (size_t)(2 * kp + 1) * vstride + ob * 8);
    }
  };
  auto writeV = [&](bf16* dst) {  // transpose to V^T[d][key], b32 pair writes
#pragma unroll
    for (int i = 0; i < 256 / NT; i++) {
      int c = i * NT + tid;
      int kp = c >> 3, ob = c & 7;
      const unsigned* a = (const unsigned*)&vreg[i][0];
      const unsigned* b = (const unsigned*)&vreg[i][1];
#pragma unroll
      for (int e2 = 0; e2 < 4; e2++) {
        unsigned lo = a[e2], hi = b[e2];
        unsigned w0 = (lo & 0xffffu) | (hi << 16);
        unsigned w1 = (lo >> 16) | (hi & 0xffff0000u);
        int d0 = ob * 8 + 2 * e2, d1 = d0 + 1;
        *(unsigned*)((char*)dst + ((d0 * 128 + kp * 4) ^ swz128(d0))) = w0;
        *(unsigned*)((char*)dst + ((d1 * 128 + kp * 4) ^ swz128(d1))) = w1;
      }
    }
  };

  // prologue: tile 0 into buffer 0
  stageK(Kg, Ks);
  loadV(Vg);
  writeV(Vt);
  __syncthreads();

  for (int t = 0; t < ntiles; t++) {
    bf16* KsC = Ks + (t & 1) * 4096;
    bf16* VtC = Vt + (t & 1) * 4096;
    bf16* KsN = Ks + ((t & 1) ^ 1) * 4096;
    bf16* VtN = Vt + ((t & 1) ^ 1) * 4096;
    const bool more = (t + 1 < ntiles);
    if (more) {  // issue next-tile loads early (K async into LDS, V into regs)
      stageK(Kg + (size_t)(t + 1) * 64 * kstride, KsN);
      loadV(Vg + (size_t)(t + 1) * 64 * vstride);
    }

    // ---- S^T = mfma(K, Q)
    f32x16 s[2];
    s[0] = (f32x16)0.f; s[1] = (f32x16)0.f;
#pragma unroll
    for (int kb = 0; kb < 2; kb++) {
      int row = kb * 32 + lq;
#pragma unroll
      for (int dw = 0; dw < 4; dw++) {
        bf16x8 kf = *(const bf16x8*)((const char*)KsC +
                                     ((row * 128 + dw * 32 + kg2 * 16) ^ swz128(row)));
        s[kb] = MFMA32(kf, qf[dw], s[kb]);
      }
    }

    // ---- online softmax (per-lane row; pair (lane, lane^32) shares q = lane&31)
    float vmax = s[0][0];
#pragma unroll
    for (int j = 1; j < 16; j++) vmax = fmaxf(vmax, s[0][j]);
#pragma unroll
    for (int j = 0; j < 16; j++) vmax = fmaxf(vmax, s[1][j]);
    vmax = fmaxf(vmax, __shfl_xor(vmax, 32, 64));
    if (__any(vmax > m + 8.0f)) {  // defer-max: rescale only on real growth
      float mn = fmaxf(m, vmax);
      float fac = __expf(m - mn);
      m = mn;
      rs *= fac;
#pragma unroll
      for (int j = 0; j < 16; j++) {
        int rowq = (j & 3) + 8 * (j >> 2) + 4 * kg2;
        float fj = __shfl(fac, rowq, 64);
        o[0][j] *= fj;
        o[1][j] *= fj;
      }
    }
    float tsum = 0.f;
    f32x16 p[2];
#pragma unroll
    for (int kb = 0; kb < 2; kb++)
#pragma unroll
      for (int j = 0; j < 16; j++) {
        float pv = __expf(s[kb][j] - m);
        p[kb][j] = pv;
        tsum += pv;
      }
    tsum += __shfl_xor(tsum, 32, 64);
    rs += tsum;

    // ---- pack P to bf16 quads (lane owns quads 2n+kg2 within each 32-key block)
    unsigned pk[2][4][2];
#pragma unroll
    for (int kb = 0; kb < 2; kb++)
#pragma unroll
      for (int n = 0; n < 4; n++) {
        pk[kb][n][0] = pack2(p[kb][4 * n + 0], p[kb][4 * n + 1]);
        pk[kb][n][1] = pack2(p[kb][4 * n + 2], p[kb][4 * n + 3]);
      }

    // ---- per 16-key window: exchange partner quad, assemble A-frag, PV MFMA
#pragma unroll
    for (int w = 0; w < 4; w++) {
      const int kb = w >> 1, wb = w & 1;
      // push the quad my partner (lane^32) needs: its n_send = 2*wb + (1-kg2)
      unsigned pushA = kg2 ? pk[kb][2 * wb][0] : pk[kb][2 * wb + 1][0];
      unsigned pushB = kg2 ? pk[kb][2 * wb][1] : pk[kb][2 * wb + 1][1];
      unsigned rcvA = __shfl_xor(pushA, 32, 64);
      unsigned rcvB = __shfl_xor(pushB, 32, 64);
      // frag keys = 16w + kg2*8 + 0..7 = quads (4wb+2kg2, 4wb+2kg2+1) of block kb
      u32x4 fu;
      fu[0] = kg2 ? rcvA : pk[kb][2 * wb][0];
      fu[1] = kg2 ? rcvB : pk[kb][2 * wb][1];
      fu[2] = kg2 ? pk[kb][2 * wb + 1][0] : rcvA;
      fu[3] = kg2 ? pk[kb][2 * wb + 1][1] : rcvB;
      bf16x8 pfrag = __builtin_bit_cast(bf16x8, fu);
#pragma unroll
      for (int db = 0; db < 2; db++) {
        int d = db * 32 + lq;
        bf16x8 vf = *(const bf16x8*)((const char*)VtC +
                                     ((d * 128 + w * 32 + kg2 * 16) ^ swz128(d)));
        o[db] = MFMA32(pfrag, vf, o[db]);
      }
    }

    if (more) writeV(VtN);
    __syncthreads();  // implicit vmcnt(0) also drains gl_lds for next tile
  }
}

// ---------------------------------------------------------------- self attention
__global__ __launch_bounds__(128)
void k_attn_self(const bf16* __restrict__ QKV, bf16* __restrict__ xat) {
  __shared__ bf16 Ks[2 * 4096], Vt[2 * 4096];
  const int qt = blockIdx.x, bh = blockIdx.y;
  const int b = bh >> 4, h = bh & 15;
  const int tid = threadIdx.x, lane = tid & 63, wv = tid >> 6;
  const int lq = lane & 31, kg2 = lane >> 5;
  const int qtok = b * 1024 + qt * 64 + wv * 32;
  bf16x8 qf[4];
#pragma unroll
  for (int dw = 0; dw < 4; dw++) {
    qf[dw] = *(const bf16x8*)(QKV + (size_t)(qtok + lq) * 3072 + h * 64 + dw * 16 + kg2 * 8);
#pragma unroll
    for (int e = 0; e < 8; e++) qf[dw][e] = (bf16)((float)qf[dw][e] * 0.125f);  // exact
  }
  f32x16 o[2];
  o[0] = (f32x16)0.f; o[1] = (f32x16)0.f;
  float m = -__builtin_inff(), rs = 0.f;
  attn_pass32<128>(QKV + (size_t)(b * 1024) * 3072 + 1024 + h * 64, 3072,
                   QKV + (size_t)(b * 1024) * 3072 + 2048 + h * 64, 3072,
                   16, qf, Ks, Vt, o, m, rs);
#pragma unroll
  for (int j = 0; j < 16; j++) {
    int rowq = (j & 3) + 8 * (j >> 2) + 4 * kg2;
    float rsj = __shfl(rs, rowq, 64);
    size_t base = (size_t)(qtok + rowq) * 1024 + h * 64;
    xat[base + lq] = (bf16)(o[0][j] / rsj);
    xat[base + 32 + lq] = (bf16)(o[1][j] / rsj);
  }
}

// ---------------------------------------------------------------- cross attention
// Split softmax: out = tanh(gate[h])*softmax(QQ·xk0)·xv0 + softmax(QQ·qk)·qv.
// gate is zero-initialized -> segment A skipped block-uniformly at runtime.
__global__ __launch_bounds__(128)
void k_attn_cross(const bf16* __restrict__ QQKV, const bf16* __restrict__ KV0,
                  const float* __restrict__ gate, bf16* __restrict__ qat) {
  __shared__ bf16 Ks[2 * 4096], Vt[2 * 4096];
  const int qt = blockIdx.x, bh = blockIdx.y;
  const int b = bh >> 4, h = bh & 15;
  const int tid = threadIdx.x, lane = tid & 63, wv = tid >> 6;
  const int lq = lane & 31, kg2 = lane >> 5;
  const int qtok = b * 512 + qt * 64 + wv * 32;
  bf16x8 qf[4];
#pragma unroll
  for (int dw = 0; dw < 4; dw++) {
    qf[dw] = *(const bf16x8*)(QQKV + (size_t)(qtok + lq) * 3072 + h * 64 + dw * 16 + kg2 * 8);
#pragma unroll
    for (int e = 0; e < 8; e++) qf[dw][e] = (bf16)((float)qf[dw][e] * 0.125f);
  }
  const float g = tanhf(gate[h]);  // block-uniform
  f32x16 oA[2];
  oA[0] = (f32x16)0.f; oA[1] = (f32x16)0.f;
  float mA = -__builtin_inff(), rsA = 0.f;
  if (g != 0.0f) {
    attn_pass32<128>(KV0 + (size_t)(b * 1024) * 2048 + h * 64, 2048,
                     KV0 + (size_t)(b * 1024) * 2048 + 1024 + h * 64, 2048,
                     16, qf, Ks, Vt, oA, mA, rsA);
  }
  f32x16 oB[2];
  oB[0] = (f32x16)0.f; oB[1] = (f32x16)0.f;
  float mB = -__builtin_inff(), rsB = 0.f;
  attn_pass32<128>(QQKV + (size_t)(b * 512) * 3072 + 1024 + h * 64, 3072,
                   QQKV + (size_t)(b * 512) * 3072 + 2048 + h * 64, 3072,
                   8, qf, Ks, Vt, oB, mB, rsB);
#pragma unroll
  for (int j = 0; j < 16; j++) {
    int rowq = (j & 3) + 8 * (j >> 2) + 4 * kg2;
    float rsBj = __shfl(rsB, rowq, 64);
    float rsAj = __shfl(rsA, rowq, 64);
    size_t base = (size_t)(qtok + rowq) * 1024 + h * 64;
    float v0 = oB[0][j] / rsBj;
    float v1 = oB[1][j] / rsBj;
    if (g != 0.0f) {
      v0 += g * (oA[0][j] / rsAj);
      v1 += g * (oA[1][j] / rsAj);
    }
    qat[base + lq] = (bf16)v0;
    qat[base + 32 + lq] = (bf16)v1;
  }
}

// ---------------------------------------------------------------- launch
extern "C" void kernel_launch(void* const* d_in, const int* in_sizes, int n_in,
                              void* d_out, int out_size, void* d_ws, size_t ws_size,
                              hipStream_t stream) {
  (void)in_sizes; (void)n_in; (void)out_size; (void)ws_size;
  const float* x       = (const float*)d_in[0];
  const float* query   = (const float*)d_in[1];
  const float* w_qkv   = (const float*)d_in[2];
  const float* w_kv    = (const float*)d_in[3];
  const float* w_qlin  = (const float*)d_in[4];
  const float* gate    = (const float*)d_in[5];
  const float* w_proj  = (const float*)d_in[6];
  const float* b_proj  = (const float*)d_in[7];
  const float* w_qproj = (const float*)d_in[8];
  const float* b_qproj = (const float*)d_in[9];
  float* out = (float*)d_out;

  bf16* p = (bf16*)d_ws;
  bf16* xb = p;      p += (size_t)4096 * 1024;
  bf16* qb = p;      p += (size_t)2048 * 1024;
  bf16* wqkvb = p;   p += (size_t)3072 * 1024;
  bf16* wkvb = p;    p += (size_t)2048 * 1024;
  bf16* wqlinb = p;  p += (size_t)3072 * 1024;
  bf16* wprojb = p;  p += (size_t)1024 * 1024;
  bf16* wqprojb = p; p += (size_t)1024 * 1024;
  bf16* QKV = p;     p += (size_t)4096 * 3072;
  bf16* KV0 = p;     p += (size_t)4096 * 2048;
  bf16* QQKV = p;    p += (size_t)2048 * 3072;
  bf16* xat = p;     p += (size_t)4096 * 1024;
  bf16* qat = p;     p += (size_t)2048 * 1024;

  auto cast = [&](const float* in, bf16* o, int n) {
    int blocks = (n / 4 + 255) / 256;
    if (blocks > 2048) blocks = 2048;
    k_cast<<<blocks, 256, 0, stream>>>(in, o, n);
  };
  cast(x, xb, 4096 * 1024);
  cast(query, qb, 2048 * 1024);
  cast(w_qkv, wqkvb, 3072 * 1024);
  cast(w_kv, wkvb, 2048 * 1024);
  cast(w_qlin, wqlinb, 3072 * 1024);
  cast(w_proj, wprojb, 1024 * 1024);
  cast(w_qproj, wqprojb, 1024 * 1024);

  k_gemm<3072, true><<<dim3(32 * 24), 256, 0, stream>>>(xb, wqkvb, QKV, nullptr);
  k_gemm<2048, true><<<dim3(32 * 16), 256, 0, stream>>>(xb, wkvb, KV0, nullptr);
  k_gemm<3072, true><<<dim3(16 * 24), 256, 0, stream>>>(qb, wqlinb, QQKV, nullptr);

  k_attn_self<<<dim3(16, 64), 128, 0, stream>>>(QKV, xat);
  k_attn_cross<<<dim3(8, 64), 128, 0, stream>>>(QQKV, KV0, gate, qat);

  k_gemm<1024, false><<<dim3(32 * 8), 256, 0, stream>>>(xat, wprojb, out, b_proj);
  k_gemm<1024, false><<<dim3(16 * 8), 256, 0, stream>>>(qat, wqprojb, out + (size_t)4096 * 1024, b_qproj);
}

// Round 3
// 238.108 us; speedup vs baseline: 1.1613x; 1.0258x over previous
//
#include <hip/hip_runtime.h>

// DualAttention: B=4, N=1024, QN=512, C=1024, H=16, D=64
// bf16 MFMA everywhere, fp32 softmax (log2-domain, v_exp_f32 = 2^x).
// Attention: swapped QK^T (S^T = mfma(K,Q)), in-register softmax, P rebuilt
// via one shfl_xor(32); self+cross merged into one dispatch for occupancy.

using bf16 = __bf16;
typedef __bf16 bf16x8 __attribute__((ext_vector_type(8)));
typedef float  f32x4  __attribute__((ext_vector_type(4)));
typedef float  f32x16 __attribute__((ext_vector_type(16)));
typedef unsigned int u32x4 __attribute__((ext_vector_type(4)));

#define MFMA16(a, b, c) __builtin_amdgcn_mfma_f32_16x16x32_bf16((a), (b), (c), 0, 0, 0)
#define MFMA32(a, b, c) __builtin_amdgcn_mfma_f32_32x32x16_bf16((a), (b), (c), 0, 0, 0)

// XOR swizzle for 128B LDS rows: spread row-strided 16B reads across banks.
__device__ __forceinline__ int swz128(int row) { return ((row ^ (row >> 3)) & 7) << 4; }

__device__ __forceinline__ void gl_lds16(const void* g, void* l) {
  __builtin_amdgcn_global_load_lds(
      (const __attribute__((address_space(1))) unsigned int*)g,
      (__attribute__((address_space(3))) unsigned int*)l, 16, 0, 0);
}

__device__ __forceinline__ unsigned pack2(float a, float b) {
  unsigned short ua = __builtin_bit_cast(unsigned short, (bf16)a);
  unsigned short ub = __builtin_bit_cast(unsigned short, (bf16)b);
  return (unsigned)ua | ((unsigned)ub << 16);
}

__device__ __forceinline__ float exp2_fast(float x) {  // v_exp_f32 IS 2^x
  float r;
  asm("v_exp_f32 %0, %1" : "=v"(r) : "v"(x));
  return r;
}

// ---------------------------------------------------------------- fused cast fp32->bf16
// ws layout (elements, M = 1<<20): xb@0(4M) qb@4M(2M) wqkv@6M(3M) wkv@9M(2M)
// wqlin@11M(3M) wproj@14M(1M) wqproj@15M(1M); total 16M. Must match kernel_launch.
__global__ void k_cast_all(const float* __restrict__ s0, const float* __restrict__ s1,
                           const float* __restrict__ s2, const float* __restrict__ s3,
                           const float* __restrict__ s4, const float* __restrict__ s5,
                           const float* __restrict__ s6, bf16* __restrict__ dst) {
  constexpr size_t MM = 1u << 20;
  constexpr size_t o1 = 4 * MM, o2 = 6 * MM, o3 = 9 * MM, o4 = 11 * MM,
                   o5 = 14 * MM, o6 = 15 * MM, total = 16 * MM;
  size_t stride = (size_t)gridDim.x * blockDim.x * 8;
  for (size_t i = ((size_t)blockIdx.x * blockDim.x + threadIdx.x) * 8; i < total; i += stride) {
    const float* s; size_t loc;
    if (i < o1)      { s = s0; loc = i; }
    else if (i < o2) { s = s1; loc = i - o1; }
    else if (i < o3) { s = s2; loc = i - o2; }
    else if (i < o4) { s = s3; loc = i - o3; }
    else if (i < o5) { s = s4; loc = i - o4; }
    else if (i < o6) { s = s5; loc = i - o5; }
    else             { s = s6; loc = i - o6; }
    float4 a = *(const float4*)(s + loc);
    float4 b = *(const float4*)(s + loc + 4);
    bf16x8 o;
    o[0] = (bf16)a.x; o[1] = (bf16)a.y; o[2] = (bf16)a.z; o[3] = (bf16)a.w;
    o[4] = (bf16)b.x; o[5] = (bf16)b.y; o[6] = (bf16)b.z; o[7] = (bf16)b.w;
    *(bf16x8*)(dst + i) = o;
  }
}

// ---------------------------------------------------------------- GEMM  C[M,N] = A[M,K] * B[N,K]^T
// 128x128 tile, BK=64, 4 waves, gl_lds + swizzle. Chunked XCD swizzle on grid.
template<int N, bool OBF>
__global__ __launch_bounds__(256)
void k_gemm(const bf16* __restrict__ A, const bf16* __restrict__ B,
            void* __restrict__ Cp, const float* __restrict__ bias) {
  constexpr int K = 1024;
  __shared__ bf16 As[128 * 64];
  __shared__ bf16 Bs[128 * 64];
  const int tid = threadIdx.x;
  const int lane = tid & 63, w = tid >> 6;
  const int wr = w >> 1, wc = w & 1;
  const int nbx = N / 128;
  const int bid = ((int)blockIdx.x & 7) * ((int)gridDim.x >> 3) + ((int)blockIdx.x >> 3);
  const int tm = (bid / nbx) * 128, tn = (bid % nbx) * 128;
  const int r0 = lane & 15, kg = lane >> 4;
  f32x4 acc[4][4] = {};
  for (int kk = 0; kk < K; kk += 64) {
#pragma unroll
    for (int i = 0; i < 4; i++) {
      int c = i * 256 + tid;
      int row = c >> 3, kb = c & 7;
      int sb = (kb ^ ((row ^ (row >> 3)) & 7)) * 8;
      gl_lds16(A + (size_t)(tm + row) * K + kk + sb, (char*)As + c * 16);
      gl_lds16(B + (size_t)(tn + row) * K + kk + sb, (char*)Bs + c * 16);
    }
    __syncthreads();
#pragma unroll
    for (int ks = 0; ks < 2; ks++) {
      bf16x8 af[4], bfv[4];
#pragma unroll
      for (int f = 0; f < 4; f++) {
        int rowa = wr * 64 + f * 16 + r0;
        af[f] = *(const bf16x8*)((const char*)As +
                                 ((rowa * 128 + ks * 64 + kg * 16) ^ swz128(rowa)));
        int rowb = wc * 64 + f * 16 + r0;
        bfv[f] = *(const bf16x8*)((const char*)Bs +
                                  ((rowb * 128 + ks * 64 + kg * 16) ^ swz128(rowb)));
      }
#pragma unroll
      for (int mf = 0; mf < 4; mf++)
#pragma unroll
        for (int nf = 0; nf < 4; nf++)
          acc[mf][nf] = MFMA16(af[mf], bfv[nf], acc[mf][nf]);
    }
    __syncthreads();
  }
#pragma unroll
  for (int mf = 0; mf < 4; mf++)
#pragma unroll
    for (int j = 0; j < 4; j++) {
      int row = tm + wr * 64 + mf * 16 + kg * 4 + j;
#pragma unroll
      for (int nf = 0; nf < 4; nf++) {
        int col = tn + wc * 64 + nf * 16 + r0;
        float v = acc[mf][nf][j];
        if constexpr (OBF) {
          ((bf16*)Cp)[(size_t)row * N + col] = (bf16)v;
        } else {
          if (bias) v += bias[col];
          ((float*)Cp)[(size_t)row * N + col] = v;
        }
      }
    }
}

// ---------------------------------------------------------------- flash attention pass (32x32 MFMA)
// NT threads co-stage K/V; each wave owns 32 q (q = lane&31). Softmax in
// log2-domain (Q pre-scaled by scale*log2e). One shfl_xor(32) per quad-pair
// rebuilds PV A-frags. Double-buffered LDS; defer-max THR=11.5 (log2).
template<int NT>
__device__ __forceinline__ void attn_pass32(
    const bf16* __restrict__ Kg, int kstride,
    const bf16* __restrict__ Vg, int vstride,
    int ntiles, const bf16x8* qf, bf16* Ks, bf16* Vt,  // Ks,Vt: [2][4096] bf16
    f32x16* o, float& m, float& rs) {
  const int tid = threadIdx.x;
  const int lane = tid & 63;
  const int lq = lane & 31, kg2 = lane >> 5;

  uint4 vreg[256 / NT][2];

  auto stageK = [&](const bf16* Kt, bf16* dst) {
#pragma unroll
    for (int i = 0; i < 512 / NT; i++) {
      int c = i * NT + tid;
      int key = c >> 3, kb = c & 7;
      int sb = (kb ^ ((key ^ (key >> 3)) & 7)) * 8;  // pre-swizzled source
      gl_lds16(Kt + (size_t)key * kstride + sb, (char*)dst + c * 16);
    }
  };
  auto loadV = [&](const bf16* Vtg) {
#pragma unroll
    for (int i = 0; i < 256 / NT; i++) {
      int c = i * NT + tid;
      int kp = c >> 3, ob = c & 7;
      vreg[i][0] = *(const uint4*)(Vtg + (size_t)(2 * kp) * vstride + ob * 8);
      vreg[i][1] = *(const uint4*)(Vtg + (size_t)(2 * kp + 1) * vstride + ob * 8);
    }
  };
  auto writeV = [&](bf16* dst) {  // transpose to V^T[d][key], b32 pair writes
#pragma unroll
    for (int i = 0; i < 256 / NT; i++) {
      int c = i * NT + tid;
      int kp = c >> 3, ob = c & 7;
      const unsigned* a = (const unsigned*)&vreg[i][0];
      const unsigned* b = (const unsigned*)&vreg[i][1];
#pragma unroll
      for (int e2 = 0; e2 < 4; e2++) {
        unsigned lo = a[e2], hi = b[e2];
        unsigned w0 = (lo & 0xffffu) | (hi << 16);
        unsigned w1 = (lo >> 16) | (hi & 0xffff0000u);
        int d0 = ob * 8 + 2 * e2, d1 = d0 + 1;
        *(unsigned*)((char*)dst + ((d0 * 128 + kp * 4) ^ swz128(d0))) = w0;
        *(unsigned*)((char*)dst + ((d1 * 128 + kp * 4) ^ swz128(d1))) = w1;
      }
    }
  };

  stageK(Kg, Ks);
  loadV(Vg);
  writeV(Vt);
  __syncthreads();

  for (int t = 0; t < ntiles; t++) {
    bf16* KsC = Ks + (t & 1) * 4096;
    bf16* VtC = Vt + (t & 1) * 4096;
    bf16* KsN = Ks + ((t & 1) ^ 1) * 4096;
    bf16* VtN = Vt + ((t & 1) ^ 1) * 4096;
    const bool more = (t + 1 < ntiles);
    if (more) {
      stageK(Kg + (size_t)(t + 1) * 64 * kstride, KsN);
      loadV(Vg + (size_t)(t + 1) * 64 * vstride);
    }

    // ---- S^T = mfma(K, Q)   (log2-scaled)
    f32x16 s[2];
    s[0] = (f32x16)0.f; s[1] = (f32x16)0.f;
    __builtin_amdgcn_s_setprio(1);
#pragma unroll
    for (int kb = 0; kb < 2; kb++) {
      int row = kb * 32 + lq;
#pragma unroll
      for (int dw = 0; dw < 4; dw++) {
        bf16x8 kf = *(const bf16x8*)((const char*)KsC +
                                     ((row * 128 + dw * 32 + kg2 * 16) ^ swz128(row)));
        s[kb] = MFMA32(kf, qf[dw], s[kb]);
      }
    }
    __builtin_amdgcn_s_setprio(0);

    // ---- online softmax (per-lane row; pair (lane, lane^32) shares q = lane&31)
    float vmax = s[0][0];
#pragma unroll
    for (int j = 1; j < 16; j++) vmax = fmaxf(vmax, s[0][j]);
#pragma unroll
    for (int j = 0; j < 16; j++) vmax = fmaxf(vmax, s[1][j]);
    vmax = fmaxf(vmax, __shfl_xor(vmax, 32, 64));
    if (__any(vmax > m + 11.5f)) {  // defer-max (log2 units; 2^11.5 ~ e^8)
      float mn = fmaxf(m, vmax);
      float fac = exp2_fast(m - mn);
      m = mn;
      rs *= fac;
#pragma unroll
      for (int j = 0; j < 16; j++) {
        int rowq = (j & 3) + 8 * (j >> 2) + 4 * kg2;
        float fj = __shfl(fac, rowq, 64);
        o[0][j] *= fj;
        o[1][j] *= fj;
      }
    }
    float tsum = 0.f;
    f32x16 p[2];
#pragma unroll
    for (int kb = 0; kb < 2; kb++)
#pragma unroll
      for (int j = 0; j < 16; j++) {
        float pv = exp2_fast(s[kb][j] - m);
        p[kb][j] = pv;
        tsum += pv;
      }
    tsum += __shfl_xor(tsum, 32, 64);
    rs += tsum;

    // ---- pack P to bf16 quads (lane owns quads 2n+kg2 within each 32-key block)
    unsigned pk[2][4][2];
#pragma unroll
    for (int kb = 0; kb < 2; kb++)
#pragma unroll
      for (int n = 0; n < 4; n++) {
        pk[kb][n][0] = pack2(p[kb][4 * n + 0], p[kb][4 * n + 1]);
        pk[kb][n][1] = pack2(p[kb][4 * n + 2], p[kb][4 * n + 3]);
      }

    // ---- per 16-key window: exchange partner quad, assemble A-frag, PV MFMA
#pragma unroll
    for (int w = 0; w < 4; w++) {
      const int kb = w >> 1, wb = w & 1;
      unsigned pushA = kg2 ? pk[kb][2 * wb][0] : pk[kb][2 * wb + 1][0];
      unsigned pushB = kg2 ? pk[kb][2 * wb][1] : pk[kb][2 * wb + 1][1];
      unsigned rcvA = __shfl_xor(pushA, 32, 64);
      unsigned rcvB = __shfl_xor(pushB, 32, 64);
      u32x4 fu;
      fu[0] = kg2 ? rcvA : pk[kb][2 * wb][0];
      fu[1] = kg2 ? rcvB : pk[kb][2 * wb][1];
      fu[2] = kg2 ? pk[kb][2 * wb + 1][0] : rcvA;
      fu[3] = kg2 ? pk[kb][2 * wb + 1][1] : rcvB;
      bf16x8 pfrag = __builtin_bit_cast(bf16x8, fu);
      __builtin_amdgcn_s_setprio(1);
#pragma unroll
      for (int db = 0; db < 2; db++) {
        int d = db * 32 + lq;
        bf16x8 vf = *(const bf16x8*)((const char*)VtC +
                                     ((d * 128 + w * 32 + kg2 * 16) ^ swz128(d)));
        o[db] = MFMA32(pfrag, vf, o[db]);
      }
      __builtin_amdgcn_s_setprio(0);
    }

    if (more) writeV(VtN);
    __syncthreads();  // drains gl_lds (vmcnt) for next tile
  }
}

// ---------------------------------------------------------------- merged attention
// grid = 64 bh-groups x 12 blocks (8 self-qtiles + 4 cross-qtiles), XCD-chunked.
// 256 threads = 4 waves x 32 q = 128 q rows per block.
__global__ __launch_bounds__(256)
void k_attn(const bf16* __restrict__ QKV, const bf16* __restrict__ QQKV,
            const bf16* __restrict__ KV0, const float* __restrict__ gate,
            bf16* __restrict__ xat, bf16* __restrict__ qat) {
  __shared__ bf16 Ks[2 * 4096], Vt[2 * 4096];
  const int pb = blockIdx.x;
  const int bid = (pb & 7) * 96 + (pb >> 3);  // 768 = 8 x 96 chunks
  const int bh = bid / 12, r = bid % 12;
  const int b = bh >> 4, h = bh & 15;
  const int tid = threadIdx.x, lane = tid & 63, wv = tid >> 6;
  const int lq = lane & 31, kg2 = lane >> 5;
  constexpr float QS = 0.125f * 1.44269504088896f;  // scale * log2(e)

  if (r < 8) {
    // ---------------- self attention: q rows b*1024 + r*128 + wv*32 + [0,32)
    const int qtok = b * 1024 + r * 128 + wv * 32;
    bf16x8 qf[4];
#pragma unroll
    for (int dw = 0; dw < 4; dw++) {
      qf[dw] = *(const bf16x8*)(QKV + (size_t)(qtok + lq) * 3072 + h * 64 + dw * 16 + kg2 * 8);
#pragma unroll
      for (int e = 0; e < 8; e++) qf[dw][e] = (bf16)((float)qf[dw][e] * QS);
    }
    f32x16 o[2];
    o[0] = (f32x16)0.f; o[1] = (f32x16)0.f;
    float m = -__builtin_inff(), rs = 0.f;
    attn_pass32<256>(QKV + (size_t)(b * 1024) * 3072 + 1024 + h * 64, 3072,
                     QKV + (size_t)(b * 1024) * 3072 + 2048 + h * 64, 3072,
                     16, qf, Ks, Vt, o, m, rs);
#pragma unroll
    for (int j = 0; j < 16; j++) {
      int rowq = (j & 3) + 8 * (j >> 2) + 4 * kg2;
      float rsj = __shfl(rs, rowq, 64);
      size_t base = (size_t)(qtok + rowq) * 1024 + h * 64;
      xat[base + lq] = (bf16)(o[0][j] / rsj);
      xat[base + 32 + lq] = (bf16)(o[1][j] / rsj);
    }
  } else {
    // ---------------- cross attention: q rows b*512 + (r-8)*128 + wv*32 + [0,32)
    const int qt = r - 8;
    const int qtok = b * 512 + qt * 128 + wv * 32;
    bf16x8 qf[4];
#pragma unroll
    for (int dw = 0; dw < 4; dw++) {
      qf[dw] = *(const bf16x8*)(QQKV + (size_t)(qtok + lq) * 3072 + h * 64 + dw * 16 + kg2 * 8);
#pragma unroll
      for (int e = 0; e < 8; e++) qf[dw][e] = (bf16)((float)qf[dw][e] * QS);
    }
    const float g = tanhf(gate[h]);  // block-uniform (zero-init param -> skip seg A)
    unsigned pka[2][8] = {};         // packed g*softmax(QK0)V0 result (seg A)
    f32x16 o[2];
    o[0] = (f32x16)0.f; o[1] = (f32x16)0.f;
    float m, rs;
    if (g != 0.0f) {
      m = -__builtin_inff(); rs = 0.f;
      attn_pass32<256>(KV0 + (size_t)(b * 1024) * 2048 + h * 64, 2048,
                       KV0 + (size_t)(b * 1024) * 2048 + 1024 + h * 64, 2048,
                       16, qf, Ks, Vt, o, m, rs);
#pragma unroll
      for (int j2 = 0; j2 < 8; j2++) {
        int j0 = 2 * j2;
        int rq0 = (j0 & 3) + 8 * (j0 >> 2) + 4 * kg2;  // rq1 = rq0 + 1
        float ra = __shfl(rs, rq0, 64);
        float rb = __shfl(rs, rq0 + 1, 64);
        pka[0][j2] = pack2(g * o[0][j0] / ra, g * o[0][j0 + 1] / rb);
        pka[1][j2] = pack2(g * o[1][j0] / ra, g * o[1][j0 + 1] / rb);
      }
      o[0] = (f32x16)0.f; o[1] = (f32x16)0.f;
    }
    m = -__builtin_inff(); rs = 0.f;
    attn_pass32<256>(QQKV + (size_t)(b * 512) * 3072 + 1024 + h * 64, 3072,
                     QQKV + (size_t)(b * 512) * 3072 + 2048 + h * 64, 3072,
                     8, qf, Ks, Vt, o, m, rs);
#pragma unroll
    for (int j = 0; j < 16; j++) {
      int rowq = (j & 3) + 8 * (j >> 2) + 4 * kg2;
      float rsj = __shfl(rs, rowq, 64);
      size_t base = (size_t)(qtok + rowq) * 1024 + h * 64;
      unsigned wa = pka[0][j >> 1], wb = pka[1][j >> 1];
      unsigned short ua = (j & 1) ? (unsigned short)(wa >> 16) : (unsigned short)(wa & 0xffffu);
      unsigned short ub = (j & 1) ? (unsigned short)(wb >> 16) : (unsigned short)(wb & 0xffffu);
      float a0 = (float)__builtin_bit_cast(bf16, ua);
      float a1 = (float)__builtin_bit_cast(bf16, ub);
      qat[base + lq] = (bf16)(o[0][j] / rsj + a0);
      qat[base + 32 + lq] = (bf16)(o[1][j] / rsj + a1);
    }
  }
}

// ---------------------------------------------------------------- launch
extern "C" void kernel_launch(void* const* d_in, const int* in_sizes, int n_in,
                              void* d_out, int out_size, void* d_ws, size_t ws_size,
                              hipStream_t stream) {
  (void)in_sizes; (void)n_in; (void)out_size; (void)ws_size;
  const float* x       = (const float*)d_in[0];
  const float* query   = (const float*)d_in[1];
  const float* w_qkv   = (const float*)d_in[2];
  const float* w_kv    = (const float*)d_in[3];
  const float* w_qlin  = (const float*)d_in[4];
  const float* gate    = (const float*)d_in[5];
  const float* w_proj  = (const float*)d_in[6];
  const float* b_proj  = (const float*)d_in[7];
  const float* w_qproj = (const float*)d_in[8];
  const float* b_qproj = (const float*)d_in[9];
  float* out = (float*)d_out;

  bf16* p = (bf16*)d_ws;
  bf16* xb = p;      p += (size_t)4096 * 1024;   // 4M elems @ 0
  bf16* qb = p;      p += (size_t)2048 * 1024;   // 2M @ 4M
  bf16* wqkvb = p;   p += (size_t)3072 * 1024;   // 3M @ 6M
  bf16* wkvb = p;    p += (size_t)2048 * 1024;   // 2M @ 9M
  bf16* wqlinb = p;  p += (size_t)3072 * 1024;   // 3M @ 11M
  bf16* wprojb = p;  p += (size_t)1024 * 1024;   // 1M @ 14M
  bf16* wqprojb = p; p += (size_t)1024 * 1024;   // 1M @ 15M
  bf16* QKV = p;     p += (size_t)4096 * 3072;
  bf16* KV0 = p;     p += (size_t)4096 * 2048;
  bf16* QQKV = p;    p += (size_t)2048 * 3072;
  bf16* xat = p;     p += (size_t)4096 * 1024;
  bf16* qat = p;     p += (size_t)2048 * 1024;

  k_cast_all<<<2048, 256, 0, stream>>>(x, query, w_qkv, w_kv, w_qlin, w_proj, w_qproj,
                                       (bf16*)d_ws);

  k_gemm<3072, true><<<dim3(32 * 24), 256, 0, stream>>>(xb, wqkvb, QKV, nullptr);
  k_gemm<2048, true><<<dim3(32 * 16), 256, 0, stream>>>(xb, wkvb, KV0, nullptr);
  k_gemm<3072, true><<<dim3(16 * 24), 256, 0, stream>>>(qb, wqlinb, QQKV, nullptr);

  k_attn<<<dim3(768), 256, 0, stream>>>(QKV, QQKV, KV0, gate, xat, qat);

  k_gemm<1024, false><<<dim3(32 * 8), 256, 0, stream>>>(xat, wprojb, out, b_proj);
  k_gemm<1024, false><<<dim3(16 * 8), 256, 0, stream>>>(qat, wqprojb, out + (size_t)4096 * 1024, b_qproj);
}

// Round 4
// 199.878 us; speedup vs baseline: 1.3834x; 1.1913x over previous
//
#include <hip/hip_runtime.h>

// DualAttention: B=4, N=1024, QN=512, C=1024, H=16, D=64
// bf16 MFMA everywhere, fp32 softmax (log2-domain). GEMM epilogues emit V
// pre-transposed (V^T[bh][d][tok]) so attention stages K and V^T identically
// via global_load_lds -- no in-kernel transpose, no P LDS round trip.

using bf16 = __bf16;
typedef __bf16 bf16x4 __attribute__((ext_vector_type(4)));
typedef __bf16 bf16x8 __attribute__((ext_vector_type(8)));
typedef float  f32x4  __attribute__((ext_vector_type(4)));
typedef float  f32x16 __attribute__((ext_vector_type(16)));
typedef unsigned int u32x4 __attribute__((ext_vector_type(4)));

#define MFMA16(a, b, c) __builtin_amdgcn_mfma_f32_16x16x32_bf16((a), (b), (c), 0, 0, 0)
#define MFMA32(a, b, c) __builtin_amdgcn_mfma_f32_32x32x16_bf16((a), (b), (c), 0, 0, 0)

// XOR swizzle for 128B LDS rows: spread row-strided 16B reads across banks.
__device__ __forceinline__ int swz128(int row) { return ((row ^ (row >> 3)) & 7) << 4; }

__device__ __forceinline__ void gl_lds16(const void* g, void* l) {
  __builtin_amdgcn_global_load_lds(
      (const __attribute__((address_space(1))) unsigned int*)g,
      (__attribute__((address_space(3))) unsigned int*)l, 16, 0, 0);
}

__device__ __forceinline__ unsigned pack2(float a, float b) {
  unsigned short ua = __builtin_bit_cast(unsigned short, (bf16)a);
  unsigned short ub = __builtin_bit_cast(unsigned short, (bf16)b);
  return (unsigned)ua | ((unsigned)ub << 16);
}

__device__ __forceinline__ float exp2_fast(float x) {  // v_exp_f32 IS 2^x
  float r;
  asm("v_exp_f32 %0, %1" : "=v"(r) : "v"(x));
  return r;
}

// ---------------------------------------------------------------- fused cast fp32->bf16
// ws layout (elements, M = 1<<20): xb@0(4M) qb@4M(2M) wqkv@6M(3M) wkv@9M(2M)
// wqlin@11M(3M) wproj@14M(1M) wqproj@15M(1M). Must match kernel_launch.
__global__ void k_cast_all(const float* __restrict__ s0, const float* __restrict__ s1,
                           const float* __restrict__ s2, const float* __restrict__ s3,
                           const float* __restrict__ s4, const float* __restrict__ s5,
                           const float* __restrict__ s6, bf16* __restrict__ dst) {
  constexpr size_t MM = 1u << 20;
  constexpr size_t o1 = 4 * MM, o2 = 6 * MM, o3 = 9 * MM, o4 = 11 * MM,
                   o5 = 14 * MM, o6 = 15 * MM, total = 16 * MM;
  size_t stride = (size_t)gridDim.x * blockDim.x * 8;
  for (size_t i = ((size_t)blockIdx.x * blockDim.x + threadIdx.x) * 8; i < total; i += stride) {
    const float* s; size_t loc;
    if (i < o1)      { s = s0; loc = i; }
    else if (i < o2) { s = s1; loc = i - o1; }
    else if (i < o3) { s = s2; loc = i - o2; }
    else if (i < o4) { s = s3; loc = i - o3; }
    else if (i < o5) { s = s4; loc = i - o4; }
    else if (i < o6) { s = s5; loc = i - o5; }
    else             { s = s6; loc = i - o6; }
    float4 a = *(const float4*)(s + loc);
    float4 b = *(const float4*)(s + loc + 4);
    bf16x8 o;
    o[0] = (bf16)a.x; o[1] = (bf16)a.y; o[2] = (bf16)a.z; o[3] = (bf16)a.w;
    o[4] = (bf16)b.x; o[5] = (bf16)b.y; o[6] = (bf16)b.z; o[7] = (bf16)b.w;
    *(bf16x8*)(dst + i) = o;
  }
}

// ---------------------------------------------------------------- GEMM core
// C[M,N] = A[M,1024] * B[N,1024]^T; 128x128 tile, BK=64, 4 waves.
// MODE 0 (proj fused): B/bias selected by tm (<4096: proj, else qproj), fp32 out.
// MODE 1 (XKV, N=5120): cols [0,2048) q,k -> XK rm (stride 3072);
//   [2048,3072) v -> VTa transposed (tokb=10); [3072,4096) xk0 -> XK col-1024;
//   [4096,5120) xv0 -> VTb transposed (tokb=10).
// MODE 2 (qlin, N=3072): [0,2048) qq,qk -> RM stride 2048; [2048,3072) qv -> VTa (tokb=9).
template<int MODE, int N>
__global__ __launch_bounds__(256)
void k_gemm(const bf16* __restrict__ A, const bf16* __restrict__ B0,
            const bf16* __restrict__ B1,
            const float* __restrict__ bias0, const float* __restrict__ bias1,
            bf16* __restrict__ RM, bf16* __restrict__ VTa, bf16* __restrict__ VTb,
            float* __restrict__ OUT) {
  constexpr int K = 1024;
  __shared__ bf16 As[128 * 64];
  __shared__ bf16 Bs[128 * 64];
  const int tid = threadIdx.x;
  const int lane = tid & 63, w = tid >> 6;
  const int wr = w >> 1, wc = w & 1;
  const int nbx = N / 128;
  const int bid = ((int)blockIdx.x & 7) * ((int)gridDim.x >> 3) + ((int)blockIdx.x >> 3);
  const int tm = (bid / nbx) * 128, tn = (bid % nbx) * 128;
  const int r0 = lane & 15, kg = lane >> 4;
  const bf16* Bp = B0;
  if constexpr (MODE == 0) { if (tm >= 4096) Bp = B1; }
  f32x4 acc[4][4] = {};
  for (int kk = 0; kk < K; kk += 64) {
#pragma unroll
    for (int i = 0; i < 4; i++) {
      int c = i * 256 + tid;
      int row = c >> 3, kb = c & 7;
      int sb = (kb ^ ((row ^ (row >> 3)) & 7)) * 8;
      gl_lds16(A + (size_t)(tm + row) * K + kk + sb, (char*)As + c * 16);
      gl_lds16(Bp + (size_t)(tn + row) * K + kk + sb, (char*)Bs + c * 16);
    }
    __syncthreads();
#pragma unroll
    for (int ks = 0; ks < 2; ks++) {
      bf16x8 af[4], bfv[4];
#pragma unroll
      for (int f = 0; f < 4; f++) {
        int rowa = wr * 64 + f * 16 + r0;
        af[f] = *(const bf16x8*)((const char*)As +
                                 ((rowa * 128 + ks * 64 + kg * 16) ^ swz128(rowa)));
        int rowb = wc * 64 + f * 16 + r0;
        bfv[f] = *(const bf16x8*)((const char*)Bs +
                                  ((rowb * 128 + ks * 64 + kg * 16) ^ swz128(rowb)));
      }
#pragma unroll
      for (int mf = 0; mf < 4; mf++)
#pragma unroll
        for (int nf = 0; nf < 4; nf++)
          acc[mf][nf] = MFMA16(af[mf], bfv[nf], acc[mf][nf]);
    }
    __syncthreads();
  }
  // ---------------- epilogue (tn/tm uniform per block; ranges never straddle)
#pragma unroll
  for (int mf = 0; mf < 4; mf++) {
    const int rowb = tm + wr * 64 + mf * 16 + kg * 4;  // 4 consecutive rows (j)
#pragma unroll
    for (int nf = 0; nf < 4; nf++) {
      const int coln = tn + wc * 64 + nf * 16 + r0;
      if constexpr (MODE == 0) {
        const float* bias = (tm < 4096) ? bias0 : bias1;
        float bv = bias[coln & 1023];
#pragma unroll
        for (int j = 0; j < 4; j++)
          OUT[(size_t)(rowb + j) * 1024 + (coln & 1023)] = acc[mf][nf][j] + bv;
      } else {
        bool rm; int rmcol = coln, base = 0, tokb = 10, rs_ = 3072;
        bf16* vt = VTa;
        if constexpr (MODE == 1) {
          if (tn < 2048)      { rm = true; }
          else if (tn < 3072) { rm = false; base = 2048; }
          else if (tn < 4096) { rm = true; rmcol = coln - 1024; }
          else                { rm = false; base = 4096; vt = VTb; }
        } else {
          rs_ = 2048; tokb = 9;
          if (tn < 2048) { rm = true; }
          else           { rm = false; base = 2048; }
        }
        if (rm) {
#pragma unroll
          for (int j = 0; j < 4; j++)
            RM[(size_t)(rowb + j) * rs_ + rmcol] = (bf16)acc[mf][nf][j];
        } else {
          int dg = coln - base, h_ = dg >> 6, dd = dg & 63;
          int bq = rowb >> tokb, tok = rowb & ((1 << tokb) - 1);
          bf16x4 wv;
#pragma unroll
          for (int j = 0; j < 4; j++) wv[j] = (bf16)acc[mf][nf][j];
          *(bf16x4*)(vt + (((size_t)((bq * 16 + h_) * 64 + dd)) << tokb) + tok) = wv;
        }
      }
    }
  }
}

// ---------------------------------------------------------------- flash attention pass (32x32 MFMA)
// K tile t: rows at Kg + (t*64+r)*kRS. V^T tile t: rows at VTg + r*vRS + t*64.
// Both staged via gl_lds with pre-swizzled source. Each wave owns 32 q
// (q = lane&31); softmax in-register (log2-domain); one shfl_xor(32) per
// quad-pair rebuilds PV A-frags. Double-buffered LDS; defer-max THR=11.5.
template<int NT>
__device__ __forceinline__ void attn_pass32(
    const bf16* __restrict__ Kg, int kRS,
    const bf16* __restrict__ VTg, int vRS,
    int ntiles, const bf16x8* qf, bf16* Ks, bf16* Vt,  // Ks,Vt: [2][4096] bf16
    f32x16* o, float& m, float& rs) {
  const int tid = threadIdx.x;
  const int lane = tid & 63;
  const int lq = lane & 31, kg2 = lane >> 5;

  auto stage = [&](const bf16* base, int rstride, int colofs, bf16* dst) {
#pragma unroll
    for (int i = 0; i < 512 / NT; i++) {
      int c = i * NT + tid;
      int r = c >> 3, kb = c & 7;
      int sb = (kb ^ ((r ^ (r >> 3)) & 7)) * 8;  // pre-swizzled source
      gl_lds16(base + (size_t)r * rstride + colofs + sb, (char*)dst + c * 16);
    }
  };

  stage(Kg, kRS, 0, Ks);
  stage(VTg, vRS, 0, Vt);
  __syncthreads();

  for (int t = 0; t < ntiles; t++) {
    bf16* KsC = Ks + (t & 1) * 4096;
    bf16* VtC = Vt + (t & 1) * 4096;
    const bool more = (t + 1 < ntiles);
    if (more) {
      stage(Kg + (size_t)(t + 1) * 64 * kRS, kRS, 0, Ks + ((t & 1) ^ 1) * 4096);
      stage(VTg, vRS, (t + 1) * 64, Vt + ((t & 1) ^ 1) * 4096);
    }

    // ---- S^T = mfma(K, Q)   (log2-scaled)
    f32x16 s[2];
    s[0] = (f32x16)0.f; s[1] = (f32x16)0.f;
    __builtin_amdgcn_s_setprio(1);
#pragma unroll
    for (int kb = 0; kb < 2; kb++) {
      int row = kb * 32 + lq;
#pragma unroll
      for (int dw = 0; dw < 4; dw++) {
        bf16x8 kf = *(const bf16x8*)((const char*)KsC +
                                     ((row * 128 + dw * 32 + kg2 * 16) ^ swz128(row)));
        s[kb] = MFMA32(kf, qf[dw], s[kb]);
      }
    }
    __builtin_amdgcn_s_setprio(0);

    // ---- online softmax (pair (lane, lane^32) shares q = lane&31)
    float vmax = s[0][0];
#pragma unroll
    for (int j = 1; j < 16; j++) vmax = fmaxf(vmax, s[0][j]);
#pragma unroll
    for (int j = 0; j < 16; j++) vmax = fmaxf(vmax, s[1][j]);
    vmax = fmaxf(vmax, __shfl_xor(vmax, 32, 64));
    if (__any(vmax > m + 11.5f)) {  // defer-max (log2 units; 2^11.5 ~ e^8)
      float mn = fmaxf(m, vmax);
      float fac = exp2_fast(m - mn);
      m = mn;
      rs *= fac;
#pragma unroll
      for (int j = 0; j < 16; j++) {
        int rowq = (j & 3) + 8 * (j >> 2) + 4 * kg2;
        float fj = __shfl(fac, rowq, 64);
        o[0][j] *= fj;
        o[1][j] *= fj;
      }
    }
    float tsum = 0.f;
    f32x16 p[2];
#pragma unroll
    for (int kb = 0; kb < 2; kb++)
#pragma unroll
      for (int j = 0; j < 16; j++) {
        float pv = exp2_fast(s[kb][j] - m);
        p[kb][j] = pv;
        tsum += pv;
      }
    tsum += __shfl_xor(tsum, 32, 64);
    rs += tsum;

    // ---- pack P to bf16 quads (lane owns quads 2n+kg2 within each 32-key block)
    unsigned pk[2][4][2];
#pragma unroll
    for (int kb = 0; kb < 2; kb++)
#pragma unroll
      for (int n = 0; n < 4; n++) {
        pk[kb][n][0] = pack2(p[kb][4 * n + 0], p[kb][4 * n + 1]);
        pk[kb][n][1] = pack2(p[kb][4 * n + 2], p[kb][4 * n + 3]);
      }

    // ---- per 16-key window: exchange partner quad, assemble A-frag, PV MFMA
#pragma unroll
    for (int w = 0; w < 4; w++) {
      const int kb = w >> 1, wb = w & 1;
      unsigned pushA = kg2 ? pk[kb][2 * wb][0] : pk[kb][2 * wb + 1][0];
      unsigned pushB = kg2 ? pk[kb][2 * wb][1] : pk[kb][2 * wb + 1][1];
      unsigned rcvA = __shfl_xor(pushA, 32, 64);
      unsigned rcvB = __shfl_xor(pushB, 32, 64);
      u32x4 fu;
      fu[0] = kg2 ? rcvA : pk[kb][2 * wb][0];
      fu[1] = kg2 ? rcvB : pk[kb][2 * wb][1];
      fu[2] = kg2 ? pk[kb][2 * wb + 1][0] : rcvA;
      fu[3] = kg2 ? pk[kb][2 * wb + 1][1] : rcvB;
      bf16x8 pfrag = __builtin_bit_cast(bf16x8, fu);
      __builtin_amdgcn_s_setprio(1);
#pragma unroll
      for (int db = 0; db < 2; db++) {
        int d = db * 32 + lq;
        bf16x8 vf = *(const bf16x8*)((const char*)VtC +
                                     ((d * 128 + w * 32 + kg2 * 16) ^ swz128(d)));
        o[db] = MFMA32(pfrag, vf, o[db]);
      }
      __builtin_amdgcn_s_setprio(0);
    }

    __syncthreads();  // drains gl_lds (vmcnt) for next tile
  }
}

// ---------------------------------------------------------------- merged attention
// grid = 64 bh-groups x 12 blocks (8 self-qtiles + 4 cross-qtiles), XCD-chunked.
// XK[4096][3072]: cols q|k|xk0. QQK[2048][2048]: cols qq|qk.
// VTs/VT0: [bh][64][1024]; VTq: [bh][64][512].
__global__ __launch_bounds__(256)
void k_attn(const bf16* __restrict__ XK, const bf16* __restrict__ QQK,
            const bf16* __restrict__ VTs, const bf16* __restrict__ VT0,
            const bf16* __restrict__ VTq, const float* __restrict__ gate,
            bf16* __restrict__ xat, bf16* __restrict__ qat) {
  __shared__ bf16 Ks[2 * 4096], Vt[2 * 4096];
  const int pb = blockIdx.x;
  const int bid = (pb & 7) * 96 + (pb >> 3);  // 768 = 8 x 96 chunks
  const int bh = bid / 12, r = bid % 12;
  const int b = bh >> 4, h = bh & 15;
  const int tid = threadIdx.x, lane = tid & 63, wv = tid >> 6;
  const int lq = lane & 31, kg2 = lane >> 5;
  constexpr float QS = 0.125f * 1.44269504088896f;  // scale * log2(e)

  if (r < 8) {
    // ---------------- self attention: q rows b*1024 + r*128 + wv*32 + [0,32)
    const int qtok = b * 1024 + r * 128 + wv * 32;
    bf16x8 qf[4];
#pragma unroll
    for (int dw = 0; dw < 4; dw++) {
      qf[dw] = *(const bf16x8*)(XK + (size_t)(qtok + lq) * 3072 + h * 64 + dw * 16 + kg2 * 8);
#pragma unroll
      for (int e = 0; e < 8; e++) qf[dw][e] = (bf16)((float)qf[dw][e] * QS);
    }
    f32x16 o[2];
    o[0] = (f32x16)0.f; o[1] = (f32x16)0.f;
    float m = -__builtin_inff(), rs = 0.f;
    attn_pass32<256>(XK + (size_t)(b * 1024) * 3072 + 1024 + h * 64, 3072,
                     VTs + (size_t)bh * 64 * 1024, 1024,
                     16, qf, Ks, Vt, o, m, rs);
#pragma unroll
    for (int j = 0; j < 16; j++) {
      int rowq = (j & 3) + 8 * (j >> 2) + 4 * kg2;
      float rsj = __shfl(rs, rowq, 64);
      size_t base = (size_t)(qtok + rowq) * 1024 + h * 64;
      xat[base + lq] = (bf16)(o[0][j] / rsj);
      xat[base + 32 + lq] = (bf16)(o[1][j] / rsj);
    }
  } else {
    // ---------------- cross attention: q rows b*512 + (r-8)*128 + wv*32 + [0,32)
    const int qt = r - 8;
    const int qtok = b * 512 + qt * 128 + wv * 32;  // row in QQK [0,2048)
    bf16x8 qf[4];
#pragma unroll
    for (int dw = 0; dw < 4; dw++) {
      qf[dw] = *(const bf16x8*)(QQK + (size_t)(qtok + lq) * 2048 + h * 64 + dw * 16 + kg2 * 8);
#pragma unroll
      for (int e = 0; e < 8; e++) qf[dw][e] = (bf16)((float)qf[dw][e] * QS);
    }
    const float g = tanhf(gate[h]);  // block-uniform (zero-init param -> skip seg A)
    unsigned pka[2][8] = {};         // packed g*softmax(QK0)V0 result (seg A)
    f32x16 o[2];
    o[0] = (f32x16)0.f; o[1] = (f32x16)0.f;
    float m, rs;
    if (g != 0.0f) {
      m = -__builtin_inff(); rs = 0.f;
      attn_pass32<256>(XK + (size_t)(b * 1024) * 3072 + 2048 + h * 64, 3072,
                       VT0 + (size_t)bh * 64 * 1024, 1024,
                       16, qf, Ks, Vt, o, m, rs);
#pragma unroll
      for (int j2 = 0; j2 < 8; j2++) {
        int j0 = 2 * j2;
        int rq0 = (j0 & 3) + 8 * (j0 >> 2) + 4 * kg2;  // rq1 = rq0 + 1
        float ra = __shfl(rs, rq0, 64);
        float rb = __shfl(rs, rq0 + 1, 64);
        pka[0][j2] = pack2(g * o[0][j0] / ra, g * o[0][j0 + 1] / rb);
        pka[1][j2] = pack2(g * o[1][j0] / ra, g * o[1][j0 + 1] / rb);
      }
      o[0] = (f32x16)0.f; o[1] = (f32x16)0.f;
    }
    m = -__builtin_inff(); rs = 0.f;
    attn_pass32<256>(QQK + (size_t)(b * 512) * 2048 + 1024 + h * 64, 2048,
                     VTq + (size_t)bh * 64 * 512, 512,
                     8, qf, Ks, Vt, o, m, rs);
#pragma unroll
    for (int j = 0; j < 16; j++) {
      int rowq = (j & 3) + 8 * (j >> 2) + 4 * kg2;
      float rsj = __shfl(rs, rowq, 64);
      size_t base = (size_t)(qtok + rowq) * 1024 + h * 64;
      unsigned wa = pka[0][j >> 1], wb = pka[1][j >> 1];
      unsigned short ua = (j & 1) ? (unsigned short)(wa >> 16) : (unsigned short)(wa & 0xffffu);
      unsigned short ub = (j & 1) ? (unsigned short)(wb >> 16) : (unsigned short)(wb & 0xffffu);
      float a0 = (float)__builtin_bit_cast(bf16, ua);
      float a1 = (float)__builtin_bit_cast(bf16, ub);
      qat[base + lq] = (bf16)(o[0][j] / rsj + a0);
      qat[base + 32 + lq] = (bf16)(o[1][j] / rsj + a1);
    }
  }
}

// ---------------------------------------------------------------- launch
extern "C" void kernel_launch(void* const* d_in, const int* in_sizes, int n_in,
                              void* d_out, int out_size, void* d_ws, size_t ws_size,
                              hipStream_t stream) {
  (void)in_sizes; (void)n_in; (void)out_size; (void)ws_size;
  const float* x       = (const float*)d_in[0];
  const float* query   = (const float*)d_in[1];
  const float* w_qkv   = (const float*)d_in[2];
  const float* w_kv    = (const float*)d_in[3];
  const float* w_qlin  = (const float*)d_in[4];
  const float* gate    = (const float*)d_in[5];
  const float* w_proj  = (const float*)d_in[6];
  const float* b_proj  = (const float*)d_in[7];
  const float* w_qproj = (const float*)d_in[8];
  const float* b_qproj = (const float*)d_in[9];
  float* out = (float*)d_out;

  bf16* p = (bf16*)d_ws;
  bf16* xb = p;      p += (size_t)4096 * 1024;   // 4M @ 0
  bf16* qb = p;      p += (size_t)2048 * 1024;   // 2M @ 4M
  bf16* wqkvb = p;   p += (size_t)3072 * 1024;   // 3M @ 6M  (adjacent to wkvb!)
  bf16* wkvb = p;    p += (size_t)2048 * 1024;   // 2M @ 9M
  bf16* wqlinb = p;  p += (size_t)3072 * 1024;   // 3M @ 11M
  bf16* wprojb = p;  p += (size_t)1024 * 1024;   // 1M @ 14M
  bf16* wqprojb = p; p += (size_t)1024 * 1024;   // 1M @ 15M
  bf16* XK = p;      p += (size_t)4096 * 3072;   // q|k|xk0 row-major
  bf16* VTs = p;     p += (size_t)64 * 64 * 1024; // self V^T
  bf16* VT0 = p;     p += (size_t)64 * 64 * 1024; // xv0 V^T
  bf16* QQK = p;     p += (size_t)2048 * 2048;   // qq|qk row-major
  bf16* VTq = p;     p += (size_t)64 * 64 * 512;  // qv V^T
  bf16* xat = p;     p += (size_t)4096 * 1024;   // (xat, qat adjacent -> proj A)
  bf16* qat = p;     p += (size_t)2048 * 1024;

  k_cast_all<<<2048, 256, 0, stream>>>(x, query, w_qkv, w_kv, w_qlin, w_proj, w_qproj,
                                       (bf16*)d_ws);

  // fused qkv+kv GEMM: B rows = [w_qkv(3072) | w_kv(2048)] contiguous in ws
  k_gemm<1, 5120><<<dim3(32 * 40), 256, 0, stream>>>(
      xb, wqkvb, nullptr, nullptr, nullptr, XK, VTs, VT0, nullptr);
  // query qkv GEMM
  k_gemm<2, 3072><<<dim3(16 * 24), 256, 0, stream>>>(
      qb, wqlinb, nullptr, nullptr, nullptr, QQK, VTq, nullptr, nullptr);

  k_attn<<<dim3(768), 256, 0, stream>>>(XK, QQK, VTs, VT0, VTq, gate, xat, qat);

  // fused output projections: A = [xat|qat] (6144x1024), out rows map to d_out
  k_gemm<0, 1024><<<dim3(48 * 8), 256, 0, stream>>>(
      xat, wprojb, wqprojb, b_proj, b_qproj, nullptr, nullptr, nullptr, out);
}

// Round 5
// 193.492 us; speedup vs baseline: 1.4291x; 1.0330x over previous
//
#include <hip/hip_runtime.h>

// DualAttention: B=4, N=1024, QN=512, C=1024, H=16, D=64
// bf16 MFMA everywhere, fp32 softmax (log2-domain). GEMM epilogues emit V
// pre-transposed. Big GEMMs: 256x256 tile, BK=32, triple-buffered LDS with
// counted vmcnt + raw s_barrier (no vmcnt(0) drain in the main loop).

using bf16 = __bf16;
typedef __bf16 bf16x4 __attribute__((ext_vector_type(4)));
typedef __bf16 bf16x8 __attribute__((ext_vector_type(8)));
typedef float  f32x4  __attribute__((ext_vector_type(4)));
typedef float  f32x16 __attribute__((ext_vector_type(16)));
typedef unsigned int u32x4 __attribute__((ext_vector_type(4)));

#define MFMA16(a, b, c) __builtin_amdgcn_mfma_f32_16x16x32_bf16((a), (b), (c), 0, 0, 0)
#define MFMA32(a, b, c) __builtin_amdgcn_mfma_f32_32x32x16_bf16((a), (b), (c), 0, 0, 0)

// XOR swizzle for 128B LDS rows (8 granules of 16B).
__device__ __forceinline__ int swz128(int row) { return ((row ^ (row >> 3)) & 7) << 4; }

__device__ __forceinline__ void gl_lds16(const void* g, void* l) {
  __builtin_amdgcn_global_load_lds(
      (const __attribute__((address_space(1))) unsigned int*)g,
      (__attribute__((address_space(3))) unsigned int*)l, 16, 0, 0);
}

__device__ __forceinline__ unsigned pack2(float a, float b) {
  unsigned short ua = __builtin_bit_cast(unsigned short, (bf16)a);
  unsigned short ub = __builtin_bit_cast(unsigned short, (bf16)b);
  return (unsigned)ua | ((unsigned)ub << 16);
}

__device__ __forceinline__ float exp2_fast(float x) {  // v_exp_f32 IS 2^x
  float r;
  asm("v_exp_f32 %0, %1" : "=v"(r) : "v"(x));
  return r;
}

#define WAITV(N) asm volatile("s_waitcnt vmcnt(" #N ")" ::: "memory")
#define RAW_BAR() do { __builtin_amdgcn_s_barrier(); asm volatile("" ::: "memory"); } while (0)

// ---------------------------------------------------------------- fused cast fp32->bf16
// ws layout (elements, M = 1<<20): xb@0(4M) qb@4M(2M) wqkv@6M(3M) wkv@9M(2M)
// wqlin@11M(3M) wproj@14M(1M) wqproj@15M(1M). Must match kernel_launch.
__global__ void k_cast_all(const float* __restrict__ s0, const float* __restrict__ s1,
                           const float* __restrict__ s2, const float* __restrict__ s3,
                           const float* __restrict__ s4, const float* __restrict__ s5,
                           const float* __restrict__ s6, bf16* __restrict__ dst) {
  constexpr size_t MM = 1u << 20;
  constexpr size_t o1 = 4 * MM, o2 = 6 * MM, o3 = 9 * MM, o4 = 11 * MM,
                   o5 = 14 * MM, o6 = 15 * MM, total = 16 * MM;
  size_t stride = (size_t)gridDim.x * blockDim.x * 8;
  for (size_t i = ((size_t)blockIdx.x * blockDim.x + threadIdx.x) * 8; i < total; i += stride) {
    const float* s; size_t loc;
    if (i < o1)      { s = s0; loc = i; }
    else if (i < o2) { s = s1; loc = i - o1; }
    else if (i < o3) { s = s2; loc = i - o2; }
    else if (i < o4) { s = s3; loc = i - o3; }
    else if (i < o5) { s = s4; loc = i - o4; }
    else if (i < o6) { s = s5; loc = i - o5; }
    else             { s = s6; loc = i - o6; }
    float4 a = *(const float4*)(s + loc);
    float4 b = *(const float4*)(s + loc + 4);
    bf16x8 o;
    o[0] = (bf16)a.x; o[1] = (bf16)a.y; o[2] = (bf16)a.z; o[3] = (bf16)a.w;
    o[4] = (bf16)b.x; o[5] = (bf16)b.y; o[6] = (bf16)b.z; o[7] = (bf16)b.w;
    *(bf16x8*)(dst + i) = o;
  }
}

// ---------------------------------------------------------------- big grouped GEMM
// 256x256 tile, BK=32, 512 threads (8 waves, 2x4), triple-buffered LDS,
// counted vmcnt(4) + raw barrier (loads for step t+2 fly across step t's barrier).
// Groups: bid [0,320): XKV (xb x [wqkv|wkv], M=4096 N=5120);
//         bid [320,416): qlin (qb x wqlin, M=2048 N=3072).
// Swizzle (64B rows, 4 granules): granule' = g ^ ((row>>1)&3), both sides.
__global__ __launch_bounds__(512, 2)
void k_gemm_big(const bf16* __restrict__ xb, const bf16* __restrict__ qb,
                const bf16* __restrict__ wqkvb, const bf16* __restrict__ wqlinb,
                bf16* __restrict__ XK, bf16* __restrict__ VTs, bf16* __restrict__ VT0,
                bf16* __restrict__ QQK, bf16* __restrict__ VTq) {
  constexpr int K = 1024, NK = 32;
  __shared__ bf16 As[3 * 256 * 32];
  __shared__ bf16 Bs[3 * 256 * 32];
  const int tid = threadIdx.x;
  const int lane = tid & 63, w = tid >> 6;
  const int wm = w >> 2, wn = w & 3;
  const int r0 = lane & 15, kg = lane >> 4;
  const int bid = ((int)blockIdx.x & 7) * 52 + ((int)blockIdx.x >> 3);  // 416 = 8*52
  int grp, tm, tn;
  const bf16 *Ap, *Bp;
  if (bid < 320) { grp = 0; tm = (bid / 20) * 256; tn = (bid % 20) * 256; Ap = xb; Bp = wqkvb; }
  else { grp = 1; int t = bid - 320; tm = (t / 12) * 256; tn = (t % 12) * 256; Ap = qb; Bp = wqlinb; }

  auto stage = [&](int step, int bi) {
    const int kk = step * 32;
#pragma unroll
    for (int j = 0; j < 2; j++) {
      int c = j * 512 + tid;               // 1024 chunks: row=c>>2, granule=c&3
      int row = c >> 2, kb = c & 3;
      int sg = (kb ^ ((row >> 1) & 3)) * 8;
      gl_lds16(Ap + (size_t)(tm + row) * K + kk + sg, (char*)As + bi * 16384 + c * 16);
    }
#pragma unroll
    for (int j = 0; j < 2; j++) {
      int c = j * 512 + tid;
      int row = c >> 2, kb = c & 3;
      int sg = (kb ^ ((row >> 1) & 3)) * 8;
      gl_lds16(Bp + (size_t)(tn + row) * K + kk + sg, (char*)Bs + bi * 16384 + c * 16);
    }
  };

  f32x4 acc[8][4] = {};
  stage(0, 0);
  stage(1, 1);
  WAITV(4);   // step-0's 4 loads drained; step-1's 4 in flight
  RAW_BAR();

  for (int t = 0; t < NK; t++) {
    const int bi = t % 3;
    const bool more = (t + 2 < NK);
    if (more) stage(t + 2, (t + 2) % 3);   // overwrites buffer read at step t-1
    const char* Ab = (const char*)As + bi * 16384;
    const char* Bb = (const char*)Bs + bi * 16384;
    bf16x8 af[8], bfv[4];
#pragma unroll
    for (int mf = 0; mf < 8; mf++) {
      int row = wm * 128 + mf * 16 + r0;
      af[mf] = *(const bf16x8*)(Ab + row * 64 + ((kg ^ ((row >> 1) & 3)) << 4));
    }
#pragma unroll
    for (int nf = 0; nf < 4; nf++) {
      int row = wn * 64 + nf * 16 + r0;
      bfv[nf] = *(const bf16x8*)(Bb + row * 64 + ((kg ^ ((row >> 1) & 3)) << 4));
    }
    __builtin_amdgcn_s_setprio(1);
#pragma unroll
    for (int mf = 0; mf < 8; mf++)
#pragma unroll
      for (int nf = 0; nf < 4; nf++)
        acc[mf][nf] = MFMA16(af[mf], bfv[nf], acc[mf][nf]);
    __builtin_amdgcn_s_setprio(0);
    if (more) { WAITV(4); } else { WAITV(0); }  // drain step t+1 only
    RAW_BAR();
  }

  // ---------------- epilogue
#pragma unroll
  for (int mf = 0; mf < 8; mf++) {
    const int rowb = tm + wm * 128 + mf * 16 + kg * 4;  // 4 consecutive rows (j)
#pragma unroll
    for (int nf = 0; nf < 4; nf++) {
      const int coln = tn + wn * 64 + nf * 16 + r0;
      bool rm; int rmcol = coln, vbase = 0, tokb = 10, rs_ = 3072;
      bf16* vt = VTs;
      bf16* rmp = XK;
      if (grp == 0) {
        if (tn < 2048)      { rm = true; }
        else if (tn < 3072) { rm = false; vbase = 2048; vt = VTs; }
        else if (tn < 4096) { rm = true; rmcol = coln - 1024; }
        else                { rm = false; vbase = 4096; vt = VT0; }
      } else {
        rs_ = 2048; tokb = 9; rmp = QQK;
        if (tn < 2048) { rm = true; }
        else           { rm = false; vbase = 2048; vt = VTq; }
      }
      if (rm) {
#pragma unroll
        for (int j = 0; j < 4; j++)
          rmp[(size_t)(rowb + j) * rs_ + rmcol] = (bf16)acc[mf][nf][j];
      } else {
        int dg = coln - vbase, h_ = dg >> 6, dd = dg & 63;
        int bq = rowb >> tokb, tok = rowb & ((1 << tokb) - 1);
        bf16x4 wv;
#pragma unroll
        for (int j = 0; j < 4; j++) wv[j] = (bf16)acc[mf][nf][j];
        *(bf16x4*)(vt + (((size_t)((bq * 16 + h_) * 64 + dd)) << tokb) + tok) = wv;
      }
    }
  }
}

// ---------------------------------------------------------------- proj GEMM (128x128, proven)
// C[6144,1024] = [xat|qat] x [w_proj|w_qproj]^T + bias, fp32 out to d_out.
__global__ __launch_bounds__(256)
void k_gemm_proj(const bf16* __restrict__ A, const bf16* __restrict__ B0,
                 const bf16* __restrict__ B1, const float* __restrict__ bias0,
                 const float* __restrict__ bias1, float* __restrict__ OUT) {
  constexpr int K = 1024, N = 1024;
  __shared__ bf16 As[128 * 64];
  __shared__ bf16 Bs[128 * 64];
  const int tid = threadIdx.x;
  const int lane = tid & 63, w = tid >> 6;
  const int wr = w >> 1, wc = w & 1;
  const int nbx = N / 128;
  const int bid = ((int)blockIdx.x & 7) * ((int)gridDim.x >> 3) + ((int)blockIdx.x >> 3);
  const int tm = (bid / nbx) * 128, tn = (bid % nbx) * 128;
  const int r0 = lane & 15, kg = lane >> 4;
  const bf16* Bp = (tm < 4096) ? B0 : B1;
  const float* bias = (tm < 4096) ? bias0 : bias1;
  f32x4 acc[4][4] = {};
  for (int kk = 0; kk < K; kk += 64) {
#pragma unroll
    for (int i = 0; i < 4; i++) {
      int c = i * 256 + tid;
      int row = c >> 3, kb = c & 7;
      int sb = (kb ^ ((row ^ (row >> 3)) & 7)) * 8;
      gl_lds16(A + (size_t)(tm + row) * K + kk + sb, (char*)As + c * 16);
      gl_lds16(Bp + (size_t)(tn + row) * K + kk + sb, (char*)Bs + c * 16);
    }
    __syncthreads();
#pragma unroll
    for (int ks = 0; ks < 2; ks++) {
      bf16x8 af[4], bfv[4];
#pragma unroll
      for (int f = 0; f < 4; f++) {
        int rowa = wr * 64 + f * 16 + r0;
        af[f] = *(const bf16x8*)((const char*)As +
                                 ((rowa * 128 + ks * 64 + kg * 16) ^ swz128(rowa)));
        int rowb = wc * 64 + f * 16 + r0;
        bfv[f] = *(const bf16x8*)((const char*)Bs +
                                  ((rowb * 128 + ks * 64 + kg * 16) ^ swz128(rowb)));
      }
#pragma unroll
      for (int mf = 0; mf < 4; mf++)
#pragma unroll
        for (int nf = 0; nf < 4; nf++)
          acc[mf][nf] = MFMA16(af[mf], bfv[nf], acc[mf][nf]);
    }
    __syncthreads();
  }
#pragma unroll
  for (int mf = 0; mf < 4; mf++)
#pragma unroll
    for (int j = 0; j < 4; j++) {
      int row = tm + wr * 64 + mf * 16 + kg * 4 + j;
#pragma unroll
      for (int nf = 0; nf < 4; nf++) {
        int col = tn + wc * 64 + nf * 16 + r0;
        OUT[(size_t)row * 1024 + col] = acc[mf][nf][j] + bias[col];
      }
    }
}

// ---------------------------------------------------------------- flash attention pass
// Triple-buffered K/V^T staging via gl_lds, counted vmcnt(4) + raw barrier.
// Each wave owns 32 q (q = lane&31); softmax in-register (log2-domain);
// one shfl_xor(32) per quad-pair rebuilds PV A-frags. defer-max THR=11.5.
template<int NT>
__device__ __forceinline__ void attn_pass32(
    const bf16* __restrict__ Kg, int kRS,
    const bf16* __restrict__ VTg, int vRS,
    int ntiles, const bf16x8* qf, bf16* Ks, bf16* Vt,  // Ks,Vt: [3][4096] bf16
    f32x16* o, float& m, float& rs) {
  const int tid = threadIdx.x;
  const int lane = tid & 63;
  const int lq = lane & 31, kg2 = lane >> 5;

  auto stage = [&](int t) {
    bf16* kd = Ks + (t % 3) * 4096;
    bf16* vd = Vt + (t % 3) * 4096;
    const bf16* kt = Kg + (size_t)t * 64 * kRS;
#pragma unroll
    for (int i = 0; i < 512 / NT; i++) {
      int c = i * NT + tid;
      int r = c >> 3, kb = c & 7;
      int sb = (kb ^ ((r ^ (r >> 3)) & 7)) * 8;  // pre-swizzled source
      gl_lds16(kt + (size_t)r * kRS + sb, (char*)kd + c * 16);
    }
#pragma unroll
    for (int i = 0; i < 512 / NT; i++) {
      int c = i * NT + tid;
      int r = c >> 3, kb = c & 7;
      int sb = (kb ^ ((r ^ (r >> 3)) & 7)) * 8;
      gl_lds16(VTg + (size_t)r * vRS + t * 64 + sb, (char*)vd + c * 16);
    }
  };

  stage(0);
  stage(1);
  WAITV(4);   // tile-0 staged; tile-1 in flight
  RAW_BAR();

  for (int t = 0; t < ntiles; t++) {
    const char* KsC = (const char*)(Ks + (t % 3) * 4096);
    const char* VtC = (const char*)(Vt + (t % 3) * 4096);
    const bool more = (t + 2 < ntiles);
    if (more) stage(t + 2);

    // ---- S^T = mfma(K, Q)   (log2-scaled)
    f32x16 s[2];
    s[0] = (f32x16)0.f; s[1] = (f32x16)0.f;
    __builtin_amdgcn_s_setprio(1);
#pragma unroll
    for (int kb = 0; kb < 2; kb++) {
      int row = kb * 32 + lq;
#pragma unroll
      for (int dw = 0; dw < 4; dw++) {
        bf16x8 kf = *(const bf16x8*)(KsC + ((row * 128 + dw * 32 + kg2 * 16) ^ swz128(row)));
        s[kb] = MFMA32(kf, qf[dw], s[kb]);
      }
    }
    __builtin_amdgcn_s_setprio(0);

    // ---- online softmax (pair (lane, lane^32) shares q = lane&31)
    float vmax = s[0][0];
#pragma unroll
    for (int j = 1; j < 16; j++) vmax = fmaxf(vmax, s[0][j]);
#pragma unroll
    for (int j = 0; j < 16; j++) vmax = fmaxf(vmax, s[1][j]);
    vmax = fmaxf(vmax, __shfl_xor(vmax, 32, 64));
    if (__any(vmax > m + 11.5f)) {  // defer-max (log2 units; 2^11.5 ~ e^8)
      float mn = fmaxf(m, vmax);
      float fac = exp2_fast(m - mn);
      m = mn;
      rs *= fac;
#pragma unroll
      for (int j = 0; j < 16; j++) {
        int rowq = (j & 3) + 8 * (j >> 2) + 4 * kg2;
        float fj = __shfl(fac, rowq, 64);
        o[0][j] *= fj;
        o[1][j] *= fj;
      }
    }
    float tsum = 0.f;
    f32x16 p[2];
#pragma unroll
    for (int kb = 0; kb < 2; kb++)
#pragma unroll
      for (int j = 0; j < 16; j++) {
        float pv = exp2_fast(s[kb][j] - m);
        p[kb][j] = pv;
        tsum += pv;
      }
    tsum += __shfl_xor(tsum, 32, 64);
    rs += tsum;

    // ---- pack P to bf16 quads (lane owns quads 2n+kg2 within each 32-key block)
    unsigned pk[2][4][2];
#pragma unroll
    for (int kb = 0; kb < 2; kb++)
#pragma unroll
      for (int n = 0; n < 4; n++) {
        pk[kb][n][0] = pack2(p[kb][4 * n + 0], p[kb][4 * n + 1]);
        pk[kb][n][1] = pack2(p[kb][4 * n + 2], p[kb][4 * n + 3]);
      }

    // ---- per 16-key window: exchange partner quad, assemble A-frag, PV MFMA
#pragma unroll
    for (int w = 0; w < 4; w++) {
      const int kb = w >> 1, wb = w & 1;
      unsigned pushA = kg2 ? pk[kb][2 * wb][0] : pk[kb][2 * wb + 1][0];
      unsigned pushB = kg2 ? pk[kb][2 * wb][1] : pk[kb][2 * wb + 1][1];
      unsigned rcvA = __shfl_xor(pushA, 32, 64);
      unsigned rcvB = __shfl_xor(pushB, 32, 64);
      u32x4 fu;
      fu[0] = kg2 ? rcvA : pk[kb][2 * wb][0];
      fu[1] = kg2 ? rcvB : pk[kb][2 * wb][1];
      fu[2] = kg2 ? pk[kb][2 * wb + 1][0] : rcvA;
      fu[3] = kg2 ? pk[kb][2 * wb + 1][1] : rcvB;
      bf16x8 pfrag = __builtin_bit_cast(bf16x8, fu);
      __builtin_amdgcn_s_setprio(1);
#pragma unroll
      for (int db = 0; db < 2; db++) {
        int d = db * 32 + lq;
        bf16x8 vf = *(const bf16x8*)(VtC + ((d * 128 + w * 32 + kg2 * 16) ^ swz128(d)));
        o[db] = MFMA32(pfrag, vf, o[db]);
      }
      __builtin_amdgcn_s_setprio(0);
    }

    if (more) { WAITV(4); } else { WAITV(0); }  // drain tile t+1 only
    RAW_BAR();
  }
}

// ---------------------------------------------------------------- merged attention
// grid = 64 bh-groups x 12 blocks (8 self-qtiles + 4 cross-qtiles), XCD-chunked.
// XK[4096][3072]: cols q|k|xk0. QQK[2048][2048]: cols qq|qk.
// VTs/VT0: [bh][64][1024]; VTq: [bh][64][512].
__global__ __launch_bounds__(256)
void k_attn(const bf16* __restrict__ XK, const bf16* __restrict__ QQK,
            const bf16* __restrict__ VTs, const bf16* __restrict__ VT0,
            const bf16* __restrict__ VTq, const float* __restrict__ gate,
            bf16* __restrict__ xat, bf16* __restrict__ qat) {
  __shared__ bf16 Ks[3 * 4096], Vt[3 * 4096];
  const int pb = blockIdx.x;
  const int bid = (pb & 7) * 96 + (pb >> 3);  // 768 = 8 x 96 chunks
  const int bh = bid / 12, r = bid % 12;
  const int b = bh >> 4, h = bh & 15;
  const int tid = threadIdx.x, lane = tid & 63, wv = tid >> 6;
  const int lq = lane & 31, kg2 = lane >> 5;
  constexpr float QS = 0.125f * 1.44269504088896f;  // scale * log2(e)

  if (r < 8) {
    // ---------------- self attention: q rows b*1024 + r*128 + wv*32 + [0,32)
    const int qtok = b * 1024 + r * 128 + wv * 32;
    bf16x8 qf[4];
#pragma unroll
    for (int dw = 0; dw < 4; dw++) {
      qf[dw] = *(const bf16x8*)(XK + (size_t)(qtok + lq) * 3072 + h * 64 + dw * 16 + kg2 * 8);
#pragma unroll
      for (int e = 0; e < 8; e++) qf[dw][e] = (bf16)((float)qf[dw][e] * QS);
    }
    f32x16 o[2];
    o[0] = (f32x16)0.f; o[1] = (f32x16)0.f;
    float m = -__builtin_inff(), rs = 0.f;
    attn_pass32<256>(XK + (size_t)(b * 1024) * 3072 + 1024 + h * 64, 3072,
                     VTs + (size_t)bh * 64 * 1024, 1024,
                     16, qf, Ks, Vt, o, m, rs);
#pragma unroll
    for (int j = 0; j < 16; j++) {
      int rowq = (j & 3) + 8 * (j >> 2) + 4 * kg2;
      float rsj = __shfl(rs, rowq, 64);
      size_t base = (size_t)(qtok + rowq) * 1024 + h * 64;
      xat[base + lq] = (bf16)(o[0][j] / rsj);
      xat[base + 32 + lq] = (bf16)(o[1][j] / rsj);
    }
  } else {
    // ---------------- cross attention: q rows b*512 + (r-8)*128 + wv*32 + [0,32)
    const int qt = r - 8;
    const int qtok = b * 512 + qt * 128 + wv * 32;
    bf16x8 qf[4];
#pragma unroll
    for (int dw = 0; dw < 4; dw++) {
      qf[dw] = *(const bf16x8*)(QQK + (size_t)(qtok + lq) * 2048 + h * 64 + dw * 16 + kg2 * 8);
#pragma unroll
      for (int e = 0; e < 8; e++) qf[dw][e] = (bf16)((float)qf[dw][e] * QS);
    }
    const float g = tanhf(gate[h]);  // block-uniform (zero-init param -> skip seg A)
    unsigned pka[2][8] = {};         // packed g*softmax(QK0)V0 result (seg A)
    f32x16 o[2];
    o[0] = (f32x16)0.f; o[1] = (f32x16)0.f;
    float m, rs;
    if (g != 0.0f) {
      m = -__builtin_inff(); rs = 0.f;
      attn_pass32<256>(XK + (size_t)(b * 1024) * 3072 + 2048 + h * 64, 3072,
                       VT0 + (size_t)bh * 64 * 1024, 1024,
                       16, qf, Ks, Vt, o, m, rs);
#pragma unroll
      for (int j2 = 0; j2 < 8; j2++) {
        int j0 = 2 * j2;
        int rq0 = (j0 & 3) + 8 * (j0 >> 2) + 4 * kg2;  // rq1 = rq0 + 1
        float ra = __shfl(rs, rq0, 64);
        float rb = __shfl(rs, rq0 + 1, 64);
        pka[0][j2] = pack2(g * o[0][j0] / ra, g * o[0][j0 + 1] / rb);
        pka[1][j2] = pack2(g * o[1][j0] / ra, g * o[1][j0 + 1] / rb);
      }
      o[0] = (f32x16)0.f; o[1] = (f32x16)0.f;
    }
    m = -__builtin_inff(); rs = 0.f;
    attn_pass32<256>(QQK + (size_t)(b * 512) * 2048 + 1024 + h * 64, 2048,
                     VTq + (size_t)bh * 64 * 512, 512,
                     8, qf, Ks, Vt, o, m, rs);
#pragma unroll
    for (int j = 0; j < 16; j++) {
      int rowq = (j & 3) + 8 * (j >> 2) + 4 * kg2;
      float rsj = __shfl(rs, rowq, 64);
      size_t base = (size_t)(qtok + rowq) * 1024 + h * 64;
      unsigned wa = pka[0][j >> 1], wb = pka[1][j >> 1];
      unsigned short ua = (j & 1) ? (unsigned short)(wa >> 16) : (unsigned short)(wa & 0xffffu);
      unsigned short ub = (j & 1) ? (unsigned short)(wb >> 16) : (unsigned short)(wb & 0xffffu);
      float a0 = (float)__builtin_bit_cast(bf16, ua);
      float a1 = (float)__builtin_bit_cast(bf16, ub);
      qat[base + lq] = (bf16)(o[0][j] / rsj + a0);
      qat[base + 32 + lq] = (bf16)(o[1][j] / rsj + a1);
    }
  }
}

// ---------------------------------------------------------------- launch
extern "C" void kernel_launch(void* const* d_in, const int* in_sizes, int n_in,
                              void* d_out, int out_size, void* d_ws, size_t ws_size,
                              hipStream_t stream) {
  (void)in_sizes; (void)n_in; (void)out_size; (void)ws_size;
  const float* x       = (const float*)d_in[0];
  const float* query   = (const float*)d_in[1];
  const float* w_qkv   = (const float*)d_in[2];
  const float* w_kv    = (const float*)d_in[3];
  const float* w_qlin  = (const float*)d_in[4];
  const float* gate    = (const float*)d_in[5];
  const float* w_proj  = (const float*)d_in[6];
  const float* b_proj  = (const float*)d_in[7];
  const float* w_qproj = (const float*)d_in[8];
  const float* b_qproj = (const float*)d_in[9];
  float* out = (float*)d_out;

  bf16* p = (bf16*)d_ws;
  bf16* xb = p;      p += (size_t)4096 * 1024;   // 4M @ 0
  bf16* qb = p;      p += (size_t)2048 * 1024;   // 2M @ 4M
  bf16* wqkvb = p;   p += (size_t)3072 * 1024;   // 3M @ 6M (adjacent to wkvb)
  bf16* wkvb = p;    p += (size_t)2048 * 1024;   // 2M @ 9M
  bf16* wqlinb = p;  p += (size_t)3072 * 1024;   // 3M @ 11M
  bf16* wprojb = p;  p += (size_t)1024 * 1024;   // 1M @ 14M
  bf16* wqprojb = p; p += (size_t)1024 * 1024;   // 1M @ 15M
  bf16* XK = p;      p += (size_t)4096 * 3072;   // q|k|xk0 row-major
  bf16* VTs = p;     p += (size_t)64 * 64 * 1024; // self V^T
  bf16* VT0 = p;     p += (size_t)64 * 64 * 1024; // xv0 V^T
  bf16* QQK = p;     p += (size_t)2048 * 2048;   // qq|qk row-major
  bf16* VTq = p;     p += (size_t)64 * 64 * 512;  // qv V^T
  bf16* xat = p;     p += (size_t)4096 * 1024;   // (xat, qat adjacent -> proj A)
  bf16* qat = p;     p += (size_t)2048 * 1024;
  (void)wkvb;

  k_cast_all<<<2048, 256, 0, stream>>>(x, query, w_qkv, w_kv, w_qlin, w_proj, w_qproj,
                                       (bf16*)d_ws);

  // grouped big GEMM: XKV (320 blocks) + qlin (96 blocks)
  k_gemm_big<<<dim3(416), 512, 0, stream>>>(xb, qb, wqkvb, wqlinb,
                                            XK, VTs, VT0, QQK, VTq);

  k_attn<<<dim3(768), 256, 0, stream>>>(XK, QQK, VTs, VT0, VTq, gate, xat, qat);

  // fused output projections: A = [xat|qat] (6144x1024)
  k_gemm_proj<<<dim3(48 * 8), 256, 0, stream>>>(xat, wprojb, wqprojb, b_proj, b_qproj, out);
}

// Round 6
// 179.601 us; speedup vs baseline: 1.5396x; 1.0773x over previous
//
#include <hip/hip_runtime.h>

// DualAttention: B=4, N=1024, QN=512, C=1024, H=16, D=64
// bf16 MFMA everywhere, fp32 softmax (log2-domain). GEMM epilogues emit V
// pre-transposed. Big GEMMs: 256x256 tile, BK=64 in two k-halves, 8-phase
// schedule (ds_read || gl_lds stage || MFMA), counted vmcnt(4) at tile
// boundaries only. 128 KB LDS, 1 block/CU, 8 waves self-overlapping.

using bf16 = __bf16;
typedef __bf16 bf16x4 __attribute__((ext_vector_type(4)));
typedef __bf16 bf16x8 __attribute__((ext_vector_type(8)));
typedef float  f32x4  __attribute__((ext_vector_type(4)));
typedef float  f32x16 __attribute__((ext_vector_type(16)));
typedef unsigned int u32x4 __attribute__((ext_vector_type(4)));

#define MFMA16(a, b, c) __builtin_amdgcn_mfma_f32_16x16x32_bf16((a), (b), (c), 0, 0, 0)
#define MFMA32(a, b, c) __builtin_amdgcn_mfma_f32_32x32x16_bf16((a), (b), (c), 0, 0, 0)

// XOR swizzle for 128B LDS rows (8 granules of 16B).
__device__ __forceinline__ int swz128(int row) { return ((row ^ (row >> 3)) & 7) << 4; }

__device__ __forceinline__ void gl_lds16(const void* g, void* l) {
  __builtin_amdgcn_global_load_lds(
      (const __attribute__((address_space(1))) unsigned int*)g,
      (__attribute__((address_space(3))) unsigned int*)l, 16, 0, 0);
}

__device__ __forceinline__ unsigned pack2(float a, float b) {
  unsigned short ua = __builtin_bit_cast(unsigned short, (bf16)a);
  unsigned short ub = __builtin_bit_cast(unsigned short, (bf16)b);
  return (unsigned)ua | ((unsigned)ub << 16);
}

__device__ __forceinline__ float exp2_fast(float x) {  // v_exp_f32 IS 2^x
  float r;
  asm("v_exp_f32 %0, %1" : "=v"(r) : "v"(x));
  return r;
}

#define WAITV(N) asm volatile("s_waitcnt vmcnt(" #N ")" ::: "memory")
#define LGKM0()  asm volatile("s_waitcnt lgkmcnt(0)" ::: "memory")
#define SCHED0() __builtin_amdgcn_sched_barrier(0)
#define RAW_BAR() do { __builtin_amdgcn_s_barrier(); asm volatile("" ::: "memory"); } while (0)

// ---------------------------------------------------------------- fused cast fp32->bf16
// ws layout (elements, M = 1<<20): xb@0(4M) qb@4M(2M) wqkv@6M(3M) wkv@9M(2M)
// wqlin@11M(3M) wproj@14M(1M) wqproj@15M(1M). Must match kernel_launch.
__global__ void k_cast_all(const float* __restrict__ s0, const float* __restrict__ s1,
                           const float* __restrict__ s2, const float* __restrict__ s3,
                           const float* __restrict__ s4, const float* __restrict__ s5,
                           const float* __restrict__ s6, bf16* __restrict__ dst) {
  constexpr size_t MM = 1u << 20;
  constexpr size_t o1 = 4 * MM, o2 = 6 * MM, o3 = 9 * MM, o4 = 11 * MM,
                   o5 = 14 * MM, o6 = 15 * MM, total = 16 * MM;
  size_t stride = (size_t)gridDim.x * blockDim.x * 8;
  for (size_t i = ((size_t)blockIdx.x * blockDim.x + threadIdx.x) * 8; i < total; i += stride) {
    const float* s; size_t loc;
    if (i < o1)      { s = s0; loc = i; }
    else if (i < o2) { s = s1; loc = i - o1; }
    else if (i < o3) { s = s2; loc = i - o2; }
    else if (i < o4) { s = s3; loc = i - o3; }
    else if (i < o5) { s = s4; loc = i - o4; }
    else if (i < o6) { s = s5; loc = i - o5; }
    else             { s = s6; loc = i - o6; }
    float4 a = *(const float4*)(s + loc);
    float4 b = *(const float4*)(s + loc + 4);
    bf16x8 o;
    o[0] = (bf16)a.x; o[1] = (bf16)a.y; o[2] = (bf16)a.z; o[3] = (bf16)a.w;
    o[4] = (bf16)b.x; o[5] = (bf16)b.y; o[6] = (bf16)b.z; o[7] = (bf16)b.w;
    *(bf16x8*)(dst + i) = o;
  }
}

// ---------------------------------------------------------------- big grouped GEMM (8-phase)
// 256x256 tile, BK=64 (2 k-halves of 32), 512 threads (8 waves 2Mx4N).
// LDS: A,B each [2 buf][2 kh][256 rows][32 k] bf16 = 64 KB -> 128 KB total.
// Per tile j (reads buf[j&1]): 4 phases (mh,kh) = (0,0),(1,0),(0,1),(1,1).
//   ph1: read A(kh0,mh0)x4 + B(kh0)x4 | stage T(j+1) A-kh1 -> buf[j&1^1]
//   ph2: read A(kh0,mh1)x4           | stage T(j+1) B-kh1 -> buf[j&1^1]
//   ph3: read A(kh1,mh0)x4 + B(kh1)x4| stage T(j+2) A-kh0 -> buf[j&1]  (kh0 free since ph2 bar)
//   ph4: read A(kh1,mh1)x4           | stage T(j+2) B-kh0 -> buf[j&1]  (B-kh0 free since ph1 bar)
// Each phase: reads+stage -> barrier -> lgkmcnt(0) -> 16 MFMA -> barrier.
// Tile boundary: vmcnt(4) (keeps T(j+2)-kh0 in flight, forces T(j+1) staged).
// Groups: bid [0,320): XKV (xb x [wqkv|wkv], M=4096 N=5120);
//         bid [320,416): qlin (qb x wqlin, M=2048 N=3072).
__global__ __launch_bounds__(512)
void k_gemm_big(const bf16* __restrict__ xb, const bf16* __restrict__ qb,
                const bf16* __restrict__ wqkvb, const bf16* __restrict__ wqlinb,
                bf16* __restrict__ XK, bf16* __restrict__ VTs, bf16* __restrict__ VT0,
                bf16* __restrict__ QQK, bf16* __restrict__ VTq) {
  constexpr int K = 1024, NT = 16;
  __shared__ bf16 As[2 * 2 * 256 * 32];
  __shared__ bf16 Bs[2 * 2 * 256 * 32];
  const int tid = threadIdx.x;
  const int lane = tid & 63, w = tid >> 6;
  const int wm = w >> 2, wn = w & 3;
  const int r0 = lane & 15, kg = lane >> 4;
  const int bid = ((int)blockIdx.x & 7) * 52 + ((int)blockIdx.x >> 3);  // 416 = 8*52
  int grp, tm, tn;
  const bf16 *Ap, *Bp;
  if (bid < 320) { grp = 0; tm = (bid / 20) * 256; tn = (bid % 20) * 256; Ap = xb; Bp = wqkvb; }
  else { grp = 1; int t = bid - 320; tm = (t / 12) * 256; tn = (t % 12) * 256; Ap = qb; Bp = wqlinb; }

  // stage one half-tile: (tile T, matrix mat [0=A,1=B], k-half kh); 2 gl_lds/thread
  auto stage = [&](int T, int mat, int kh) {
    const bf16* src = mat ? Bp : Ap;
    const int t0 = mat ? tn : tm;
    char* base = (char*)(mat ? (void*)Bs : (void*)As) + (((T & 1) * 2 + kh) << 14);
#pragma unroll
    for (int i = 0; i < 2; i++) {
      int c = i * 512 + tid;
      int row = c >> 2, g = c & 3;
      int sg = (g ^ ((row >> 1) & 3)) * 8;  // pre-swizzled source granule
      gl_lds16(src + (size_t)(t0 + row) * K + T * 64 + kh * 32 + sg, base + c * 16);
    }
  };
  auto ldA = [&](int bi, int kh, int row) -> bf16x8 {
    return *(const bf16x8*)((const char*)As + ((bi * 2 + kh) << 14) + row * 64 +
                            ((kg ^ ((row >> 1) & 3)) << 4));
  };
  auto ldB = [&](int bi, int kh, int row) -> bf16x8 {
    return *(const bf16x8*)((const char*)Bs + ((bi * 2 + kh) << 14) + row * 64 +
                            ((kg ^ ((row >> 1) & 3)) << 4));
  };

  f32x4 acc[8][4] = {};

  // prologue: T0 fully + T1 kh0; leaves T1-kh0 (4 loads) in flight
  stage(0, 0, 0); stage(0, 1, 0); stage(0, 0, 1); stage(0, 1, 1);
  stage(1, 0, 0); stage(1, 1, 0);
  WAITV(4);
  RAW_BAR();

  for (int j = 0; j < NT; ++j) {
    const int bi = j & 1;
    bf16x8 af[4], bfk[4];
    // ---- phase 1: (mh0, kh0)
#pragma unroll
    for (int i = 0; i < 4; i++) af[i] = ldA(bi, 0, wm * 128 + i * 16 + r0);
#pragma unroll
    for (int nf = 0; nf < 4; nf++) bfk[nf] = ldB(bi, 0, wn * 64 + nf * 16 + r0);
    if (j + 1 < NT) stage(j + 1, 0, 1);
    RAW_BAR(); LGKM0(); SCHED0();
    __builtin_amdgcn_s_setprio(1);
#pragma unroll
    for (int i = 0; i < 4; i++)
#pragma unroll
      for (int nf = 0; nf < 4; nf++) acc[i][nf] = MFMA16(af[i], bfk[nf], acc[i][nf]);
    __builtin_amdgcn_s_setprio(0);
    RAW_BAR();
    // ---- phase 2: (mh1, kh0)
#pragma unroll
    for (int i = 0; i < 4; i++) af[i] = ldA(bi, 0, wm * 128 + 64 + i * 16 + r0);
    if (j + 1 < NT) stage(j + 1, 1, 1);
    RAW_BAR(); LGKM0(); SCHED0();
    __builtin_amdgcn_s_setprio(1);
#pragma unroll
    for (int i = 0; i < 4; i++)
#pragma unroll
      for (int nf = 0; nf < 4; nf++) acc[4 + i][nf] = MFMA16(af[i], bfk[nf], acc[4 + i][nf]);
    __builtin_amdgcn_s_setprio(0);
    RAW_BAR();
    // ---- phase 3: (mh0, kh1)
#pragma unroll
    for (int i = 0; i < 4; i++) af[i] = ldA(bi, 1, wm * 128 + i * 16 + r0);
#pragma unroll
    for (int nf = 0; nf < 4; nf++) bfk[nf] = ldB(bi, 1, wn * 64 + nf * 16 + r0);
    if (j + 2 < NT) stage(j + 2, 0, 0);
    RAW_BAR(); LGKM0(); SCHED0();
    __builtin_amdgcn_s_setprio(1);
#pragma unroll
    for (int i = 0; i < 4; i++)
#pragma unroll
      for (int nf = 0; nf < 4; nf++) acc[i][nf] = MFMA16(af[i], bfk[nf], acc[i][nf]);
    __builtin_amdgcn_s_setprio(0);
    RAW_BAR();
    // ---- phase 4: (mh1, kh1)
#pragma unroll
    for (int i = 0; i < 4; i++) af[i] = ldA(bi, 1, wm * 128 + 64 + i * 16 + r0);
    if (j + 2 < NT) stage(j + 2, 1, 0);
    RAW_BAR(); LGKM0(); SCHED0();
    __builtin_amdgcn_s_setprio(1);
#pragma unroll
    for (int i = 0; i < 4; i++)
#pragma unroll
      for (int nf = 0; nf < 4; nf++) acc[4 + i][nf] = MFMA16(af[i], bfk[nf], acc[4 + i][nf]);
    __builtin_amdgcn_s_setprio(0);
    // tile boundary: T(j+1) must be fully staged; T(j+2)-kh0 may stay in flight
    if (j < NT - 2) { WAITV(4); } else { WAITV(0); }
    RAW_BAR();
  }

  // ---------------- epilogue (tn/tm uniform per block; ranges never straddle)
#pragma unroll
  for (int mf = 0; mf < 8; mf++) {
    const int rowb = tm + wm * 128 + mf * 16 + kg * 4;  // 4 consecutive rows (j)
#pragma unroll
    for (int nf = 0; nf < 4; nf++) {
      const int coln = tn + wn * 64 + nf * 16 + r0;
      bool rm; int rmcol = coln, vbase = 0, tokb = 10, rs_ = 3072;
      bf16* vt = VTs;
      bf16* rmp = XK;
      if (grp == 0) {
        if (tn < 2048)      { rm = true; }
        else if (tn < 3072) { rm = false; vbase = 2048; vt = VTs; }
        else if (tn < 4096) { rm = true; rmcol = coln - 1024; }
        else                { rm = false; vbase = 4096; vt = VT0; }
      } else {
        rs_ = 2048; tokb = 9; rmp = QQK;
        if (tn < 2048) { rm = true; }
        else           { rm = false; vbase = 2048; vt = VTq; }
      }
      if (rm) {
#pragma unroll
        for (int j = 0; j < 4; j++)
          rmp[(size_t)(rowb + j) * rs_ + rmcol] = (bf16)acc[mf][nf][j];
      } else {
        int dg = coln - vbase, h_ = dg >> 6, dd = dg & 63;
        int bq = rowb >> tokb, tok = rowb & ((1 << tokb) - 1);
        bf16x4 wv;
#pragma unroll
        for (int j = 0; j < 4; j++) wv[j] = (bf16)acc[mf][nf][j];
        *(bf16x4*)(vt + (((size_t)((bq * 16 + h_) * 64 + dd)) << tokb) + tok) = wv;
      }
    }
  }
}

// ---------------------------------------------------------------- proj GEMM (128x128, proven)
// C[6144,1024] = [xat|qat] x [w_proj|w_qproj]^T + bias, fp32 out to d_out.
__global__ __launch_bounds__(256)
void k_gemm_proj(const bf16* __restrict__ A, const bf16* __restrict__ B0,
                 const bf16* __restrict__ B1, const float* __restrict__ bias0,
                 const float* __restrict__ bias1, float* __restrict__ OUT) {
  constexpr int K = 1024, N = 1024;
  __shared__ bf16 As[128 * 64];
  __shared__ bf16 Bs[128 * 64];
  const int tid = threadIdx.x;
  const int lane = tid & 63, w = tid >> 6;
  const int wr = w >> 1, wc = w & 1;
  const int nbx = N / 128;
  const int bid = ((int)blockIdx.x & 7) * ((int)gridDim.x >> 3) + ((int)blockIdx.x >> 3);
  const int tm = (bid / nbx) * 128, tn = (bid % nbx) * 128;
  const int r0 = lane & 15, kg = lane >> 4;
  const bf16* Bp = (tm < 4096) ? B0 : B1;
  const float* bias = (tm < 4096) ? bias0 : bias1;
  f32x4 acc[4][4] = {};
  for (int kk = 0; kk < K; kk += 64) {
#pragma unroll
    for (int i = 0; i < 4; i++) {
      int c = i * 256 + tid;
      int row = c >> 3, kb = c & 7;
      int sb = (kb ^ ((row ^ (row >> 3)) & 7)) * 8;
      gl_lds16(A + (size_t)(tm + row) * K + kk + sb, (char*)As + c * 16);
      gl_lds16(Bp + (size_t)(tn + row) * K + kk + sb, (char*)Bs + c * 16);
    }
    __syncthreads();
#pragma unroll
    for (int ks = 0; ks < 2; ks++) {
      bf16x8 af[4], bfv[4];
#pragma unroll
      for (int f = 0; f < 4; f++) {
        int rowa = wr * 64 + f * 16 + r0;
        af[f] = *(const bf16x8*)((const char*)As +
                                 ((rowa * 128 + ks * 64 + kg * 16) ^ swz128(rowa)));
        int rowb = wc * 64 + f * 16 + r0;
        bfv[f] = *(const bf16x8*)((const char*)Bs +
                                  ((rowb * 128 + ks * 64 + kg * 16) ^ swz128(rowb)));
      }
#pragma unroll
      for (int mf = 0; mf < 4; mf++)
#pragma unroll
        for (int nf = 0; nf < 4; nf++)
          acc[mf][nf] = MFMA16(af[mf], bfv[nf], acc[mf][nf]);
    }
    __syncthreads();
  }
#pragma unroll
  for (int mf = 0; mf < 4; mf++)
#pragma unroll
    for (int j = 0; j < 4; j++) {
      int row = tm + wr * 64 + mf * 16 + kg * 4 + j;
#pragma unroll
      for (int nf = 0; nf < 4; nf++) {
        int col = tn + wc * 64 + nf * 16 + r0;
        OUT[(size_t)row * 1024 + col] = acc[mf][nf][j] + bias[col];
      }
    }
}

// ---------------------------------------------------------------- flash attention pass
// Triple-buffered K/V^T staging via gl_lds, counted vmcnt(4) + raw barrier.
// Each wave owns 32 q (q = lane&31); softmax in-register (log2-domain);
// one shfl_xor(32) per quad-pair rebuilds PV A-frags. defer-max THR=11.5.
template<int NT>
__device__ __forceinline__ void attn_pass32(
    const bf16* __restrict__ Kg, int kRS,
    const bf16* __restrict__ VTg, int vRS,
    int ntiles, const bf16x8* qf, bf16* Ks, bf16* Vt,  // Ks,Vt: [3][4096] bf16
    f32x16* o, float& m, float& rs) {
  const int tid = threadIdx.x;
  const int lane = tid & 63;
  const int lq = lane & 31, kg2 = lane >> 5;

  auto stage = [&](int t) {
    bf16* kd = Ks + (t % 3) * 4096;
    bf16* vd = Vt + (t % 3) * 4096;
    const bf16* kt = Kg + (size_t)t * 64 * kRS;
#pragma unroll
    for (int i = 0; i < 512 / NT; i++) {
      int c = i * NT + tid;
      int r = c >> 3, kb = c & 7;
      int sb = (kb ^ ((r ^ (r >> 3)) & 7)) * 8;  // pre-swizzled source
      gl_lds16(kt + (size_t)r * kRS + sb, (char*)kd + c * 16);
    }
#pragma unroll
    for (int i = 0; i < 512 / NT; i++) {
      int c = i * NT + tid;
      int r = c >> 3, kb = c & 7;
      int sb = (kb ^ ((r ^ (r >> 3)) & 7)) * 8;
      gl_lds16(VTg + (size_t)r * vRS + t * 64 + sb, (char*)vd + c * 16);
    }
  };

  stage(0);
  stage(1);
  WAITV(4);   // tile-0 staged; tile-1 in flight
  RAW_BAR();

  for (int t = 0; t < ntiles; t++) {
    const char* KsC = (const char*)(Ks + (t % 3) * 4096);
    const char* VtC = (const char*)(Vt + (t % 3) * 4096);
    const bool more = (t + 2 < ntiles);
    if (more) stage(t + 2);

    // ---- S^T = mfma(K, Q)   (log2-scaled)
    f32x16 s[2];
    s[0] = (f32x16)0.f; s[1] = (f32x16)0.f;
    __builtin_amdgcn_s_setprio(1);
#pragma unroll
    for (int kb = 0; kb < 2; kb++) {
      int row = kb * 32 + lq;
#pragma unroll
      for (int dw = 0; dw < 4; dw++) {
        bf16x8 kf = *(const bf16x8*)(KsC + ((row * 128 + dw * 32 + kg2 * 16) ^ swz128(row)));
        s[kb] = MFMA32(kf, qf[dw], s[kb]);
      }
    }
    __builtin_amdgcn_s_setprio(0);

    // ---- online softmax (pair (lane, lane^32) shares q = lane&31)
    float vmax = s[0][0];
#pragma unroll
    for (int j = 1; j < 16; j++) vmax = fmaxf(vmax, s[0][j]);
#pragma unroll
    for (int j = 0; j < 16; j++) vmax = fmaxf(vmax, s[1][j]);
    vmax = fmaxf(vmax, __shfl_xor(vmax, 32, 64));
    if (__any(vmax > m + 11.5f)) {  // defer-max (log2 units; 2^11.5 ~ e^8)
      float mn = fmaxf(m, vmax);
      float fac = exp2_fast(m - mn);
      m = mn;
      rs *= fac;
#pragma unroll
      for (int j = 0; j < 16; j++) {
        int rowq = (j & 3) + 8 * (j >> 2) + 4 * kg2;
        float fj = __shfl(fac, rowq, 64);
        o[0][j] *= fj;
        o[1][j] *= fj;
      }
    }
    float tsum = 0.f;
    f32x16 p[2];
#pragma unroll
    for (int kb = 0; kb < 2; kb++)
#pragma unroll
      for (int j = 0; j < 16; j++) {
        float pv = exp2_fast(s[kb][j] - m);
        p[kb][j] = pv;
        tsum += pv;
      }
    tsum += __shfl_xor(tsum, 32, 64);
    rs += tsum;

    // ---- pack P to bf16 quads (lane owns quads 2n+kg2 within each 32-key block)
    unsigned pk[2][4][2];
#pragma unroll
    for (int kb = 0; kb < 2; kb++)
#pragma unroll
      for (int n = 0; n < 4; n++) {
        pk[kb][n][0] = pack2(p[kb][4 * n + 0], p[kb][4 * n + 1]);
        pk[kb][n][1] = pack2(p[kb][4 * n + 2], p[kb][4 * n + 3]);
      }

    // ---- per 16-key window: exchange partner quad, assemble A-frag, PV MFMA
#pragma unroll
    for (int w = 0; w < 4; w++) {
      const int kb = w >> 1, wb = w & 1;
      unsigned pushA = kg2 ? pk[kb][2 * wb][0] : pk[kb][2 * wb + 1][0];
      unsigned pushB = kg2 ? pk[kb][2 * wb][1] : pk[kb][2 * wb + 1][1];
      unsigned rcvA = __shfl_xor(pushA, 32, 64);
      unsigned rcvB = __shfl_xor(pushB, 32, 64);
      u32x4 fu;
      fu[0] = kg2 ? rcvA : pk[kb][2 * wb][0];
      fu[1] = kg2 ? rcvB : pk[kb][2 * wb][1];
      fu[2] = kg2 ? pk[kb][2 * wb + 1][0] : rcvA;
      fu[3] = kg2 ? pk[kb][2 * wb + 1][1] : rcvB;
      bf16x8 pfrag = __builtin_bit_cast(bf16x8, fu);
      __builtin_amdgcn_s_setprio(1);
#pragma unroll
      for (int db = 0; db < 2; db++) {
        int d = db * 32 + lq;
        bf16x8 vf = *(const bf16x8*)(VtC + ((d * 128 + w * 32 + kg2 * 16) ^ swz128(d)));
        o[db] = MFMA32(pfrag, vf, o[db]);
      }
      __builtin_amdgcn_s_setprio(0);
    }

    if (more) { WAITV(4); } else { WAITV(0); }  // drain tile t+1 only
    RAW_BAR();
  }
}

// ---------------------------------------------------------------- merged attention
// grid = 64 bh-groups x 12 blocks (8 self-qtiles + 4 cross-qtiles), XCD-chunked.
// XK[4096][3072]: cols q|k|xk0. QQK[2048][2048]: cols qq|qk.
// VTs/VT0: [bh][64][1024]; VTq: [bh][64][512].
__global__ __launch_bounds__(256)
void k_attn(const bf16* __restrict__ XK, const bf16* __restrict__ QQK,
            const bf16* __restrict__ VTs, const bf16* __restrict__ VT0,
            const bf16* __restrict__ VTq, const float* __restrict__ gate,
            bf16* __restrict__ xat, bf16* __restrict__ qat) {
  __shared__ bf16 Ks[3 * 4096], Vt[3 * 4096];
  const int pb = blockIdx.x;
  const int bid = (pb & 7) * 96 + (pb >> 3);  // 768 = 8 x 96 chunks
  const int bh = bid / 12, r = bid % 12;
  const int b = bh >> 4, h = bh & 15;
  const int tid = threadIdx.x, lane = tid & 63, wv = tid >> 6;
  const int lq = lane & 31, kg2 = lane >> 5;
  constexpr float QS = 0.125f * 1.44269504088896f;  // scale * log2(e)

  if (r < 8) {
    // ---------------- self attention: q rows b*1024 + r*128 + wv*32 + [0,32)
    const int qtok = b * 1024 + r * 128 + wv * 32;
    bf16x8 qf[4];
#pragma unroll
    for (int dw = 0; dw < 4; dw++) {
      qf[dw] = *(const bf16x8*)(XK + (size_t)(qtok + lq) * 3072 + h * 64 + dw * 16 + kg2 * 8);
#pragma unroll
      for (int e = 0; e < 8; e++) qf[dw][e] = (bf16)((float)qf[dw][e] * QS);
    }
    f32x16 o[2];
    o[0] = (f32x16)0.f; o[1] = (f32x16)0.f;
    float m = -__builtin_inff(), rs = 0.f;
    attn_pass32<256>(XK + (size_t)(b * 1024) * 3072 + 1024 + h * 64, 3072,
                     VTs + (size_t)bh * 64 * 1024, 1024,
                     16, qf, Ks, Vt, o, m, rs);
#pragma unroll
    for (int j = 0; j < 16; j++) {
      int rowq = (j & 3) + 8 * (j >> 2) + 4 * kg2;
      float rsj = __shfl(rs, rowq, 64);
      size_t base = (size_t)(qtok + rowq) * 1024 + h * 64;
      xat[base + lq] = (bf16)(o[0][j] / rsj);
      xat[base + 32 + lq] = (bf16)(o[1][j] / rsj);
    }
  } else {
    // ---------------- cross attention: q rows b*512 + (r-8)*128 + wv*32 + [0,32)
    const int qt = r - 8;
    const int qtok = b * 512 + qt * 128 + wv * 32;
    bf16x8 qf[4];
#pragma unroll
    for (int dw = 0; dw < 4; dw++) {
      qf[dw] = *(const bf16x8*)(QQK + (size_t)(qtok + lq) * 2048 + h * 64 + dw * 16 + kg2 * 8);
#pragma unroll
      for (int e = 0; e < 8; e++) qf[dw][e] = (bf16)((float)qf[dw][e] * QS);
    }
    const float g = tanhf(gate[h]);  // block-uniform (zero-init param -> skip seg A)
    unsigned pka[2][8] = {};         // packed g*softmax(QK0)V0 result (seg A)
    f32x16 o[2];
    o[0] = (f32x16)0.f; o[1] = (f32x16)0.f;
    float m, rs;
    if (g != 0.0f) {
      m = -__builtin_inff(); rs = 0.f;
      attn_pass32<256>(XK + (size_t)(b * 1024) * 3072 + 2048 + h * 64, 3072,
                       VT0 + (size_t)bh * 64 * 1024, 1024,
                       16, qf, Ks, Vt, o, m, rs);
#pragma unroll
      for (int j2 = 0; j2 < 8; j2++) {
        int j0 = 2 * j2;
        int rq0 = (j0 & 3) + 8 * (j0 >> 2) + 4 * kg2;  // rq1 = rq0 + 1
        float ra = __shfl(rs, rq0, 64);
        float rb = __shfl(rs, rq0 + 1, 64);
        pka[0][j2] = pack2(g * o[0][j0] / ra, g * o[0][j0 + 1] / rb);
        pka[1][j2] = pack2(g * o[1][j0] / ra, g * o[1][j0 + 1] / rb);
      }
      o[0] = (f32x16)0.f; o[1] = (f32x16)0.f;
    }
    m = -__builtin_inff(); rs = 0.f;
    attn_pass32<256>(QQK + (size_t)(b * 512) * 2048 + 1024 + h * 64, 2048,
                     VTq + (size_t)bh * 64 * 512, 512,
                     8, qf, Ks, Vt, o, m, rs);
#pragma unroll
    for (int j = 0; j < 16; j++) {
      int rowq = (j & 3) + 8 * (j >> 2) + 4 * kg2;
      float rsj = __shfl(rs, rowq, 64);
      size_t base = (size_t)(qtok + rowq) * 1024 + h * 64;
      unsigned wa = pka[0][j >> 1], wb = pka[1][j >> 1];
      unsigned short ua = (j & 1) ? (unsigned short)(wa >> 16) : (unsigned short)(wa & 0xffffu);
      unsigned short ub = (j & 1) ? (unsigned short)(wb >> 16) : (unsigned short)(wb & 0xffffu);
      float a0 = (float)__builtin_bit_cast(bf16, ua);
      float a1 = (float)__builtin_bit_cast(bf16, ub);
      qat[base + lq] = (bf16)(o[0][j] / rsj + a0);
      qat[base + 32 + lq] = (bf16)(o[1][j] / rsj + a1);
    }
  }
}

// ---------------------------------------------------------------- launch
extern "C" void kernel_launch(void* const* d_in, const int* in_sizes, int n_in,
                              void* d_out, int out_size, void* d_ws, size_t ws_size,
                              hipStream_t stream) {
  (void)in_sizes; (void)n_in; (void)out_size; (void)ws_size;
  const float* x       = (const float*)d_in[0];
  const float* query   = (const float*)d_in[1];
  const float* w_qkv   = (const float*)d_in[2];
  const float* w_kv    = (const float*)d_in[3];
  const float* w_qlin  = (const float*)d_in[4];
  const float* gate    = (const float*)d_in[5];
  const float* w_proj  = (const float*)d_in[6];
  const float* b_proj  = (const float*)d_in[7];
  const float* w_qproj = (const float*)d_in[8];
  const float* b_qproj = (const float*)d_in[9];
  float* out = (float*)d_out;

  bf16* p = (bf16*)d_ws;
  bf16* xb = p;      p += (size_t)4096 * 1024;   // 4M @ 0
  bf16* qb = p;      p += (size_t)2048 * 1024;   // 2M @ 4M
  bf16* wqkvb = p;   p += (size_t)3072 * 1024;   // 3M @ 6M (adjacent to wkvb)
  bf16* wkvb = p;    p += (size_t)2048 * 1024;   // 2M @ 9M
  bf16* wqlinb = p;  p += (size_t)3072 * 1024;   // 3M @ 11M
  bf16* wprojb = p;  p += (size_t)1024 * 1024;   // 1M @ 14M
  bf16* wqprojb = p; p += (size_t)1024 * 1024;   // 1M @ 15M
  bf16* XK = p;      p += (size_t)4096 * 3072;   // q|k|xk0 row-major
  bf16* VTs = p;     p += (size_t)64 * 64 * 1024; // self V^T
  bf16* VT0 = p;     p += (size_t)64 * 64 * 1024; // xv0 V^T
  bf16* QQK = p;     p += (size_t)2048 * 2048;   // qq|qk row-major
  bf16* VTq = p;     p += (size_t)64 * 64 * 512;  // qv V^T
  bf16* xat = p;     p += (size_t)4096 * 1024;   // (xat, qat adjacent -> proj A)
  bf16* qat = p;     p += (size_t)2048 * 1024;
  (void)wkvb;

  k_cast_all<<<2048, 256, 0, stream>>>(x, query, w_qkv, w_kv, w_qlin, w_proj, w_qproj,
                                       (bf16*)d_ws);

  // grouped big GEMM: XKV (320 blocks) + qlin (96 blocks), 8-phase schedule
  k_gemm_big<<<dim3(416), 512, 0, stream>>>(xb, qb, wqkvb, wqlinb,
                                            XK, VTs, VT0, QQK, VTq);

  k_attn<<<dim3(768), 256, 0, stream>>>(XK, QQK, VTs, VT0, VTq, gate, xat, qat);

  // fused output projections: A = [xat|qat] (6144x1024)
  k_gemm_proj<<<dim3(48 * 8), 256, 0, stream>>>(xat, wprojb, wqprojb, b_proj, b_qproj, out);
}

// Round 7
// 178.273 us; speedup vs baseline: 1.5511x; 1.0075x over previous
//
#include <hip/hip_runtime.h>

// DualAttention: B=4, N=1024, QN=512, C=1024, H=16, D=64
// bf16 MFMA everywhere, fp32 softmax (log2-domain). GEMM epilogues emit V
// pre-transposed. Big GEMMs: 256x256 tile, BK=64 in two k-halves, 8-phase
// schedule, counted vmcnt(4) at tile boundaries. Attention: swapped QK^T,
// in-register softmax with TREE reductions, 2-buffer LDS staging.

using bf16 = __bf16;
typedef __bf16 bf16x4 __attribute__((ext_vector_type(4)));
typedef __bf16 bf16x8 __attribute__((ext_vector_type(8)));
typedef float  f32x4  __attribute__((ext_vector_type(4)));
typedef float  f32x16 __attribute__((ext_vector_type(16)));
typedef unsigned int u32x4 __attribute__((ext_vector_type(4)));

#define MFMA16(a, b, c) __builtin_amdgcn_mfma_f32_16x16x32_bf16((a), (b), (c), 0, 0, 0)
#define MFMA32(a, b, c) __builtin_amdgcn_mfma_f32_32x32x16_bf16((a), (b), (c), 0, 0, 0)

// XOR swizzle for 128B LDS rows (8 granules of 16B).
__device__ __forceinline__ int swz128(int row) { return ((row ^ (row >> 3)) & 7) << 4; }

__device__ __forceinline__ void gl_lds16(const void* g, void* l) {
  __builtin_amdgcn_global_load_lds(
      (const __attribute__((address_space(1))) unsigned int*)g,
      (__attribute__((address_space(3))) unsigned int*)l, 16, 0, 0);
}

__device__ __forceinline__ unsigned pack2(float a, float b) {
  unsigned short ua = __builtin_bit_cast(unsigned short, (bf16)a);
  unsigned short ub = __builtin_bit_cast(unsigned short, (bf16)b);
  return (unsigned)ua | ((unsigned)ub << 16);
}

__device__ __forceinline__ float exp2_fast(float x) {  // v_exp_f32 IS 2^x
  float r;
  asm("v_exp_f32 %0, %1" : "=v"(r) : "v"(x));
  return r;
}

#define WAITV(N) asm volatile("s_waitcnt vmcnt(" #N ")" ::: "memory")
#define LGKM0()  asm volatile("s_waitcnt lgkmcnt(0)" ::: "memory")
#define SCHED0() __builtin_amdgcn_sched_barrier(0)
#define RAW_BAR() do { __builtin_amdgcn_s_barrier(); asm volatile("" ::: "memory"); } while (0)

// ---------------------------------------------------------------- fused cast fp32->bf16
// ws layout (elements, M = 1<<20): xb@0(4M) qb@4M(2M) wqkv@6M(3M) wkv@9M(2M)
// wqlin@11M(3M) wproj@14M(1M) wqproj@15M(1M). Must match kernel_launch.
__global__ void k_cast_all(const float* __restrict__ s0, const float* __restrict__ s1,
                           const float* __restrict__ s2, const float* __restrict__ s3,
                           const float* __restrict__ s4, const float* __restrict__ s5,
                           const float* __restrict__ s6, bf16* __restrict__ dst) {
  constexpr size_t MM = 1u << 20;
  constexpr size_t o1 = 4 * MM, o2 = 6 * MM, o3 = 9 * MM, o4 = 11 * MM,
                   o5 = 14 * MM, o6 = 15 * MM, total = 16 * MM;
  size_t stride = (size_t)gridDim.x * blockDim.x * 8;
  for (size_t i = ((size_t)blockIdx.x * blockDim.x + threadIdx.x) * 8; i < total; i += stride) {
    const float* s; size_t loc;
    if (i < o1)      { s = s0; loc = i; }
    else if (i < o2) { s = s1; loc = i - o1; }
    else if (i < o3) { s = s2; loc = i - o2; }
    else if (i < o4) { s = s3; loc = i - o3; }
    else if (i < o5) { s = s4; loc = i - o4; }
    else if (i < o6) { s = s5; loc = i - o5; }
    else             { s = s6; loc = i - o6; }
    float4 a = *(const float4*)(s + loc);
    float4 b = *(const float4*)(s + loc + 4);
    bf16x8 o;
    o[0] = (bf16)a.x; o[1] = (bf16)a.y; o[2] = (bf16)a.z; o[3] = (bf16)a.w;
    o[4] = (bf16)b.x; o[5] = (bf16)b.y; o[6] = (bf16)b.z; o[7] = (bf16)b.w;
    *(bf16x8*)(dst + i) = o;
  }
}

// ---------------------------------------------------------------- big grouped GEMM (8-phase)
// 256x256 tile, BK=64 (2 k-halves of 32), 512 threads (8 waves 2Mx4N).
// LDS: A,B each [2 buf][2 kh][256 rows][32 k] bf16 = 64 KB -> 128 KB total.
// Per tile j (reads buf[j&1]): 4 phases (mh,kh); each phase:
//   {ds_read frags | stage half-tile} -> barrier -> lgkmcnt(0) -> 16 MFMA -> barrier.
// Tile boundary: vmcnt(4) (keeps T(j+2)-kh0 in flight, forces T(j+1) staged).
// Groups: bid [0,320): XKV (xb x [wqkv|wkv], M=4096 N=5120);
//         bid [320,416): qlin (qb x wqlin, M=2048 N=3072).
__global__ __launch_bounds__(512)
void k_gemm_big(const bf16* __restrict__ xb, const bf16* __restrict__ qb,
                const bf16* __restrict__ wqkvb, const bf16* __restrict__ wqlinb,
                bf16* __restrict__ XK, bf16* __restrict__ VTs, bf16* __restrict__ VT0,
                bf16* __restrict__ QQK, bf16* __restrict__ VTq) {
  constexpr int K = 1024, NT = 16;
  __shared__ bf16 As[2 * 2 * 256 * 32];
  __shared__ bf16 Bs[2 * 2 * 256 * 32];
  const int tid = threadIdx.x;
  const int lane = tid & 63, w = tid >> 6;
  const int wm = w >> 2, wn = w & 3;
  const int r0 = lane & 15, kg = lane >> 4;
  const int bid = ((int)blockIdx.x & 7) * 52 + ((int)blockIdx.x >> 3);  // 416 = 8*52
  int grp, tm, tn;
  const bf16 *Ap, *Bp;
  if (bid < 320) { grp = 0; tm = (bid / 20) * 256; tn = (bid % 20) * 256; Ap = xb; Bp = wqkvb; }
  else { grp = 1; int t = bid - 320; tm = (t / 12) * 256; tn = (t % 12) * 256; Ap = qb; Bp = wqlinb; }

  auto stage = [&](int T, int mat, int kh) {
    const bf16* src = mat ? Bp : Ap;
    const int t0 = mat ? tn : tm;
    char* base = (char*)(mat ? (void*)Bs : (void*)As) + (((T & 1) * 2 + kh) << 14);
#pragma unroll
    for (int i = 0; i < 2; i++) {
      int c = i * 512 + tid;
      int row = c >> 2, g = c & 3;
      int sg = (g ^ ((row >> 1) & 3)) * 8;  // pre-swizzled source granule
      gl_lds16(src + (size_t)(t0 + row) * K + T * 64 + kh * 32 + sg, base + c * 16);
    }
  };
  auto ldA = [&](int bi, int kh, int row) -> bf16x8 {
    return *(const bf16x8*)((const char*)As + ((bi * 2 + kh) << 14) + row * 64 +
                            ((kg ^ ((row >> 1) & 3)) << 4));
  };
  auto ldB = [&](int bi, int kh, int row) -> bf16x8 {
    return *(const bf16x8*)((const char*)Bs + ((bi * 2 + kh) << 14) + row * 64 +
                            ((kg ^ ((row >> 1) & 3)) << 4));
  };

  f32x4 acc[8][4] = {};

  stage(0, 0, 0); stage(0, 1, 0); stage(0, 0, 1); stage(0, 1, 1);
  stage(1, 0, 0); stage(1, 1, 0);
  WAITV(4);
  RAW_BAR();

  for (int j = 0; j < NT; ++j) {
    const int bi = j & 1;
    bf16x8 af[4], bfk[4];
    // ---- phase 1: (mh0, kh0)
#pragma unroll
    for (int i = 0; i < 4; i++) af[i] = ldA(bi, 0, wm * 128 + i * 16 + r0);
#pragma unroll
    for (int nf = 0; nf < 4; nf++) bfk[nf] = ldB(bi, 0, wn * 64 + nf * 16 + r0);
    if (j + 1 < NT) stage(j + 1, 0, 1);
    RAW_BAR(); LGKM0(); SCHED0();
    __builtin_amdgcn_s_setprio(1);
#pragma unroll
    for (int i = 0; i < 4; i++)
#pragma unroll
      for (int nf = 0; nf < 4; nf++) acc[i][nf] = MFMA16(af[i], bfk[nf], acc[i][nf]);
    __builtin_amdgcn_s_setprio(0);
    RAW_BAR();
    // ---- phase 2: (mh1, kh0)
#pragma unroll
    for (int i = 0; i < 4; i++) af[i] = ldA(bi, 0, wm * 128 + 64 + i * 16 + r0);
    if (j + 1 < NT) stage(j + 1, 1, 1);
    RAW_BAR(); LGKM0(); SCHED0();
    __builtin_amdgcn_s_setprio(1);
#pragma unroll
    for (int i = 0; i < 4; i++)
#pragma unroll
      for (int nf = 0; nf < 4; nf++) acc[4 + i][nf] = MFMA16(af[i], bfk[nf], acc[4 + i][nf]);
    __builtin_amdgcn_s_setprio(0);
    RAW_BAR();
    // ---- phase 3: (mh0, kh1)
#pragma unroll
    for (int i = 0; i < 4; i++) af[i] = ldA(bi, 1, wm * 128 + i * 16 + r0);
#pragma unroll
    for (int nf = 0; nf < 4; nf++) bfk[nf] = ldB(bi, 1, wn * 64 + nf * 16 + r0);
    if (j + 2 < NT) stage(j + 2, 0, 0);
    RAW_BAR(); LGKM0(); SCHED0();
    __builtin_amdgcn_s_setprio(1);
#pragma unroll
    for (int i = 0; i < 4; i++)
#pragma unroll
      for (int nf = 0; nf < 4; nf++) acc[i][nf] = MFMA16(af[i], bfk[nf], acc[i][nf]);
    __builtin_amdgcn_s_setprio(0);
    RAW_BAR();
    // ---- phase 4: (mh1, kh1)
#pragma unroll
    for (int i = 0; i < 4; i++) af[i] = ldA(bi, 1, wm * 128 + 64 + i * 16 + r0);
    if (j + 2 < NT) stage(j + 2, 1, 0);
    RAW_BAR(); LGKM0(); SCHED0();
    __builtin_amdgcn_s_setprio(1);
#pragma unroll
    for (int i = 0; i < 4; i++)
#pragma unroll
      for (int nf = 0; nf < 4; nf++) acc[4 + i][nf] = MFMA16(af[i], bfk[nf], acc[4 + i][nf]);
    __builtin_amdgcn_s_setprio(0);
    if (j < NT - 2) { WAITV(4); } else { WAITV(0); }
    RAW_BAR();
  }

  // ---------------- epilogue (tn/tm uniform per block; ranges never straddle)
#pragma unroll
  for (int mf = 0; mf < 8; mf++) {
    const int rowb = tm + wm * 128 + mf * 16 + kg * 4;  // 4 consecutive rows (j)
#pragma unroll
    for (int nf = 0; nf < 4; nf++) {
      const int coln = tn + wn * 64 + nf * 16 + r0;
      bool rm; int rmcol = coln, vbase = 0, tokb = 10, rs_ = 3072;
      bf16* vt = VTs;
      bf16* rmp = XK;
      if (grp == 0) {
        if (tn < 2048)      { rm = true; }
        else if (tn < 3072) { rm = false; vbase = 2048; vt = VTs; }
        else if (tn < 4096) { rm = true; rmcol = coln - 1024; }
        else                { rm = false; vbase = 4096; vt = VT0; }
      } else {
        rs_ = 2048; tokb = 9; rmp = QQK;
        if (tn < 2048) { rm = true; }
        else           { rm = false; vbase = 2048; vt = VTq; }
      }
      if (rm) {
#pragma unroll
        for (int j = 0; j < 4; j++)
          rmp[(size_t)(rowb + j) * rs_ + rmcol] = (bf16)acc[mf][nf][j];
      } else {
        int dg = coln - vbase, h_ = dg >> 6, dd = dg & 63;
        int bq = rowb >> tokb, tok = rowb & ((1 << tokb) - 1);
        bf16x4 wv;
#pragma unroll
        for (int j = 0; j < 4; j++) wv[j] = (bf16)acc[mf][nf][j];
        *(bf16x4*)(vt + (((size_t)((bq * 16 + h_) * 64 + dd)) << tokb) + tok) = wv;
      }
    }
  }
}

// ---------------------------------------------------------------- proj GEMM (128x128, proven)
// C[6144,1024] = [xat|qat] x [w_proj|w_qproj]^T + bias, fp32 out to d_out.
__global__ __launch_bounds__(256)
void k_gemm_proj(const bf16* __restrict__ A, const bf16* __restrict__ B0,
                 const bf16* __restrict__ B1, const float* __restrict__ bias0,
                 const float* __restrict__ bias1, float* __restrict__ OUT) {
  constexpr int K = 1024, N = 1024;
  __shared__ bf16 As[128 * 64];
  __shared__ bf16 Bs[128 * 64];
  const int tid = threadIdx.x;
  const int lane = tid & 63, w = tid >> 6;
  const int wr = w >> 1, wc = w & 1;
  const int nbx = N / 128;
  const int bid = ((int)blockIdx.x & 7) * ((int)gridDim.x >> 3) + ((int)blockIdx.x >> 3);
  const int tm = (bid / nbx) * 128, tn = (bid % nbx) * 128;
  const int r0 = lane & 15, kg = lane >> 4;
  const bf16* Bp = (tm < 4096) ? B0 : B1;
  const float* bias = (tm < 4096) ? bias0 : bias1;
  f32x4 acc[4][4] = {};
  for (int kk = 0; kk < K; kk += 64) {
#pragma unroll
    for (int i = 0; i < 4; i++) {
      int c = i * 256 + tid;
      int row = c >> 3, kb = c & 7;
      int sb = (kb ^ ((row ^ (row >> 3)) & 7)) * 8;
      gl_lds16(A + (size_t)(tm + row) * K + kk + sb, (char*)As + c * 16);
      gl_lds16(Bp + (size_t)(tn + row) * K + kk + sb, (char*)Bs + c * 16);
    }
    __syncthreads();
#pragma unroll
    for (int ks = 0; ks < 2; ks++) {
      bf16x8 af[4], bfv[4];
#pragma unroll
      for (int f = 0; f < 4; f++) {
        int rowa = wr * 64 + f * 16 + r0;
        af[f] = *(const bf16x8*)((const char*)As +
                                 ((rowa * 128 + ks * 64 + kg * 16) ^ swz128(rowa)));
        int rowb = wc * 64 + f * 16 + r0;
        bfv[f] = *(const bf16x8*)((const char*)Bs +
                                  ((rowb * 128 + ks * 64 + kg * 16) ^ swz128(rowb)));
      }
#pragma unroll
      for (int mf = 0; mf < 4; mf++)
#pragma unroll
        for (int nf = 0; nf < 4; nf++)
          acc[mf][nf] = MFMA16(af[mf], bfv[nf], acc[mf][nf]);
    }
    __syncthreads();
  }
#pragma unroll
  for (int mf = 0; mf < 4; mf++)
#pragma unroll
    for (int j = 0; j < 4; j++) {
      int row = tm + wr * 64 + mf * 16 + kg * 4 + j;
#pragma unroll
      for (int nf = 0; nf < 4; nf++) {
        int col = tn + wc * 64 + nf * 16 + r0;
        OUT[(size_t)row * 1024 + col] = acc[mf][nf][j] + bias[col];
      }
    }
}

// ---------------------------------------------------------------- flash attention pass
// 2-buffer K/V^T staging via gl_lds; stage(t+1) issued at tile top, vmcnt(0)
// + barrier at tile end (loads land under the compute phase). Each wave owns
// 32 q (q = lane&31); softmax in-register (log2-domain) with TREE reductions;
// exp computed in place over s. One shfl_xor(32) per quad-pair rebuilds PV
// A-frags. defer-max THR=11.5 (log2).
template<int NT>
__device__ __forceinline__ void attn_pass32(
    const bf16* __restrict__ Kg, int kRS,
    const bf16* __restrict__ VTg, int vRS,
    int ntiles, const bf16x8* qf, bf16* Ks, bf16* Vt,  // Ks,Vt: [2][4096] bf16
    f32x16* o, float& m, float& rs) {
  const int tid = threadIdx.x;
  const int lane = tid & 63;
  const int lq = lane & 31, kg2 = lane >> 5;

  auto stage = [&](int t) {
    bf16* kd = Ks + (t & 1) * 4096;
    bf16* vd = Vt + (t & 1) * 4096;
    const bf16* kt = Kg + (size_t)t * 64 * kRS;
#pragma unroll
    for (int i = 0; i < 512 / NT; i++) {
      int c = i * NT + tid;
      int r = c >> 3, kb = c & 7;
      int sb = (kb ^ ((r ^ (r >> 3)) & 7)) * 8;  // pre-swizzled source
      gl_lds16(kt + (size_t)r * kRS + sb, (char*)kd + c * 16);
    }
#pragma unroll
    for (int i = 0; i < 512 / NT; i++) {
      int c = i * NT + tid;
      int r = c >> 3, kb = c & 7;
      int sb = (kb ^ ((r ^ (r >> 3)) & 7)) * 8;
      gl_lds16(VTg + (size_t)r * vRS + t * 64 + sb, (char*)vd + c * 16);
    }
  };

  stage(0);
  WAITV(0);
  RAW_BAR();

  for (int t = 0; t < ntiles; t++) {
    const char* KsC = (const char*)(Ks + (t & 1) * 4096);
    const char* VtC = (const char*)(Vt + (t & 1) * 4096);
    if (t + 1 < ntiles) stage(t + 1);  // lands under this tile's compute

    // ---- S^T = mfma(K, Q)   (log2-scaled)
    f32x16 s[2];
    s[0] = (f32x16)0.f; s[1] = (f32x16)0.f;
    __builtin_amdgcn_s_setprio(1);
#pragma unroll
    for (int kb = 0; kb < 2; kb++) {
      int row = kb * 32 + lq;
#pragma unroll
      for (int dw = 0; dw < 4; dw++) {
        bf16x8 kf = *(const bf16x8*)(KsC + ((row * 128 + dw * 32 + kg2 * 16) ^ swz128(row)));
        s[kb] = MFMA32(kf, qf[dw], s[kb]);
      }
    }
    __builtin_amdgcn_s_setprio(0);

    // ---- online softmax: TREE max (depth 5 vs 31-chain)
    float mm[8];
#pragma unroll
    for (int j = 0; j < 8; j++)
      mm[j] = fmaxf(fmaxf(s[0][j], s[0][j + 8]), fmaxf(s[1][j], s[1][j + 8]));
    float a0 = fmaxf(mm[0], mm[1]), a1 = fmaxf(mm[2], mm[3]);
    float a2 = fmaxf(mm[4], mm[5]), a3 = fmaxf(mm[6], mm[7]);
    float vmax = fmaxf(fmaxf(a0, a1), fmaxf(a2, a3));
    vmax = fmaxf(vmax, __shfl_xor(vmax, 32, 64));
    if (__any(vmax > m + 11.5f)) {  // defer-max (log2 units; 2^11.5 ~ e^8)
      float mn = fmaxf(m, vmax);
      float fac = exp2_fast(m - mn);
      m = mn;
      rs *= fac;
#pragma unroll
      for (int j = 0; j < 16; j++) {
        int rowq = (j & 3) + 8 * (j >> 2) + 4 * kg2;
        float fj = __shfl(fac, rowq, 64);
        o[0][j] *= fj;
        o[1][j] *= fj;
      }
    }
    // ---- exp in place over s; 4-accumulator sum tree
    float t0 = 0.f, t1 = 0.f, t2 = 0.f, t3 = 0.f;
#pragma unroll
    for (int kb = 0; kb < 2; kb++)
#pragma unroll
      for (int j = 0; j < 16; j += 4) {
        float p0 = exp2_fast(s[kb][j + 0] - m);
        float p1 = exp2_fast(s[kb][j + 1] - m);
        float p2 = exp2_fast(s[kb][j + 2] - m);
        float p3 = exp2_fast(s[kb][j + 3] - m);
        s[kb][j + 0] = p0; s[kb][j + 1] = p1; s[kb][j + 2] = p2; s[kb][j + 3] = p3;
        t0 += p0; t1 += p1; t2 += p2; t3 += p3;
      }
    float tsum = (t0 + t1) + (t2 + t3);
    tsum += __shfl_xor(tsum, 32, 64);
    rs += tsum;

    // ---- pack P (in s) to bf16 quads (lane owns quads 2n+kg2 per 32-key block)
    unsigned pk[2][4][2];
#pragma unroll
    for (int kb = 0; kb < 2; kb++)
#pragma unroll
      for (int n = 0; n < 4; n++) {
        pk[kb][n][0] = pack2(s[kb][4 * n + 0], s[kb][4 * n + 1]);
        pk[kb][n][1] = pack2(s[kb][4 * n + 2], s[kb][4 * n + 3]);
      }

    // ---- per 16-key window: exchange partner quad, assemble A-frag, PV MFMA
#pragma unroll
    for (int w = 0; w < 4; w++) {
      const int kb = w >> 1, wb = w & 1;
      unsigned pushA = kg2 ? pk[kb][2 * wb][0] : pk[kb][2 * wb + 1][0];
      unsigned pushB = kg2 ? pk[kb][2 * wb][1] : pk[kb][2 * wb + 1][1];
      unsigned rcvA = __shfl_xor(pushA, 32, 64);
      unsigned rcvB = __shfl_xor(pushB, 32, 64);
      u32x4 fu;
      fu[0] = kg2 ? rcvA : pk[kb][2 * wb][0];
      fu[1] = kg2 ? rcvB : pk[kb][2 * wb][1];
      fu[2] = kg2 ? pk[kb][2 * wb + 1][0] : rcvA;
      fu[3] = kg2 ? pk[kb][2 * wb + 1][1] : rcvB;
      bf16x8 pfrag = __builtin_bit_cast(bf16x8, fu);
      __builtin_amdgcn_s_setprio(1);
#pragma unroll
      for (int db = 0; db < 2; db++) {
        int d = db * 32 + lq;
        bf16x8 vf = *(const bf16x8*)(VtC + ((d * 128 + w * 32 + kg2 * 16) ^ swz128(d)));
        o[db] = MFMA32(pfrag, vf, o[db]);
      }
      __builtin_amdgcn_s_setprio(0);
    }

    WAITV(0);   // drain tile t+1's staging (issued at top, landed under compute)
    RAW_BAR();
  }
}

// ---------------------------------------------------------------- merged attention
// grid = 768 blocks XCD-chunked: bid [0,512) self (bh = bid>>3, qtile = bid&7),
// bid [512,768) cross (bh = (bid-512)>>2, qtile = (bid-512)&3).
// XK[4096][3072]: cols q|k|xk0. QQK[2048][2048]: cols qq|qk.
// VTs/VT0: [bh][64][1024]; VTq: [bh][64][512].
__global__ __launch_bounds__(256)
void k_attn(const bf16* __restrict__ XK, const bf16* __restrict__ QQK,
            const bf16* __restrict__ VTs, const bf16* __restrict__ VT0,
            const bf16* __restrict__ VTq, const float* __restrict__ gate,
            bf16* __restrict__ xat, bf16* __restrict__ qat) {
  __shared__ bf16 Ks[2 * 4096], Vt[2 * 4096];
  const int pb = blockIdx.x;
  const int bid = (pb & 7) * 96 + (pb >> 3);  // 768 = 8 x 96 chunks
  const int tid = threadIdx.x, lane = tid & 63, wv = tid >> 6;
  const int lq = lane & 31, kg2 = lane >> 5;
  constexpr float QS = 0.125f * 1.44269504088896f;  // scale * log2(e)

  if (bid < 512) {
    // ---------------- self attention
    const int bh = bid >> 3, r = bid & 7;
    const int b = bh >> 4, h = bh & 15;
    const int qtok = b * 1024 + r * 128 + wv * 32;
    bf16x8 qf[4];
#pragma unroll
    for (int dw = 0; dw < 4; dw++) {
      qf[dw] = *(const bf16x8*)(XK + (size_t)(qtok + lq) * 3072 + h * 64 + dw * 16 + kg2 * 8);
#pragma unroll
      for (int e = 0; e < 8; e++) qf[dw][e] = (bf16)((float)qf[dw][e] * QS);
    }
    f32x16 o[2];
    o[0] = (f32x16)0.f; o[1] = (f32x16)0.f;
    float m = -__builtin_inff(), rs = 0.f;
    attn_pass32<256>(XK + (size_t)(b * 1024) * 3072 + 1024 + h * 64, 3072,
                     VTs + (size_t)bh * 64 * 1024, 1024,
                     16, qf, Ks, Vt, o, m, rs);
#pragma unroll
    for (int j = 0; j < 16; j++) {
      int rowq = (j & 3) + 8 * (j >> 2) + 4 * kg2;
      float rsj = __shfl(rs, rowq, 64);
      size_t base = (size_t)(qtok + rowq) * 1024 + h * 64;
      xat[base + lq] = (bf16)(o[0][j] / rsj);
      xat[base + 32 + lq] = (bf16)(o[1][j] / rsj);
    }
  } else {
    // ---------------- cross attention
    const int c = bid - 512;
    const int bh = c >> 2, qt = c & 3;
    const int b = bh >> 4, h = bh & 15;
    const int qtok = b * 512 + qt * 128 + wv * 32;
    bf16x8 qf[4];
#pragma unroll
    for (int dw = 0; dw < 4; dw++) {
      qf[dw] = *(const bf16x8*)(QQK + (size_t)(qtok + lq) * 2048 + h * 64 + dw * 16 + kg2 * 8);
#pragma unroll
      for (int e = 0; e < 8; e++) qf[dw][e] = (bf16)((float)qf[dw][e] * QS);
    }
    const float g = tanhf(gate[h]);  // block-uniform (zero-init param -> skip seg A)
    unsigned pka[2][8] = {};         // packed g*softmax(QK0)V0 result (seg A)
    f32x16 o[2];
    o[0] = (f32x16)0.f; o[1] = (f32x16)0.f;
    float m, rs;
    if (g != 0.0f) {
      m = -__builtin_inff(); rs = 0.f;
      attn_pass32<256>(XK + (size_t)(b * 1024) * 3072 + 2048 + h * 64, 3072,
                       VT0 + (size_t)bh * 64 * 1024, 1024,
                       16, qf, Ks, Vt, o, m, rs);
#pragma unroll
      for (int j2 = 0; j2 < 8; j2++) {
        int j0 = 2 * j2;
        int rq0 = (j0 & 3) + 8 * (j0 >> 2) + 4 * kg2;  // rq1 = rq0 + 1
        float ra = __shfl(rs, rq0, 64);
        float rb = __shfl(rs, rq0 + 1, 64);
        pka[0][j2] = pack2(g * o[0][j0] / ra, g * o[0][j0 + 1] / rb);
        pka[1][j2] = pack2(g * o[1][j0] / ra, g * o[1][j0 + 1] / rb);
      }
      o[0] = (f32x16)0.f; o[1] = (f32x16)0.f;
    }
    m = -__builtin_inff(); rs = 0.f;
    attn_pass32<256>(QQK + (size_t)(b * 512) * 2048 + 1024 + h * 64, 2048,
                     VTq + (size_t)bh * 64 * 512, 512,
                     8, qf, Ks, Vt, o, m, rs);
#pragma unroll
    for (int j = 0; j < 16; j++) {
      int rowq = (j & 3) + 8 * (j >> 2) + 4 * kg2;
      float rsj = __shfl(rs, rowq, 64);
      size_t base = (size_t)(qtok + rowq) * 1024 + h * 64;
      unsigned wa = pka[0][j >> 1], wb = pka[1][j >> 1];
      unsigned short ua = (j & 1) ? (unsigned short)(wa >> 16) : (unsigned short)(wa & 0xffffu);
      unsigned short ub = (j & 1) ? (unsigned short)(wb >> 16) : (unsigned short)(wb & 0xffffu);
      float a0 = (float)__builtin_bit_cast(bf16, ua);
      float a1 = (float)__builtin_bit_cast(bf16, ub);
      qat[base + lq] = (bf16)(o[0][j] / rsj + a0);
      qat[base + 32 + lq] = (bf16)(o[1][j] / rsj + a1);
    }
  }
}

// ---------------------------------------------------------------- launch
extern "C" void kernel_launch(void* const* d_in, const int* in_sizes, int n_in,
                              void* d_out, int out_size, void* d_ws, size_t ws_size,
                              hipStream_t stream) {
  (void)in_sizes; (void)n_in; (void)out_size; (void)ws_size;
  const float* x       = (const float*)d_in[0];
  const float* query   = (const float*)d_in[1];
  const float* w_qkv   = (const float*)d_in[2];
  const float* w_kv    = (const float*)d_in[3];
  const float* w_qlin  = (const float*)d_in[4];
  const float* gate    = (const float*)d_in[5];
  const float* w_proj  = (const float*)d_in[6];
  const float* b_proj  = (const float*)d_in[7];
  const float* w_qproj = (const float*)d_in[8];
  const float* b_qproj = (const float*)d_in[9];
  float* out = (float*)d_out;

  bf16* p = (bf16*)d_ws;
  bf16* xb = p;      p += (size_t)4096 * 1024;   // 4M @ 0
  bf16* qb = p;      p += (size_t)2048 * 1024;   // 2M @ 4M
  bf16* wqkvb = p;   p += (size_t)3072 * 1024;   // 3M @ 6M (adjacent to wkvb)
  bf16* wkvb = p;    p += (size_t)2048 * 1024;   // 2M @ 9M
  bf16* wqlinb = p;  p += (size_t)3072 * 1024;   // 3M @ 11M
  bf16* wprojb = p;  p += (size_t)1024 * 1024;   // 1M @ 14M
  bf16* wqprojb = p; p += (size_t)1024 * 1024;   // 1M @ 15M
  bf16* XK = p;      p += (size_t)4096 * 3072;   // q|k|xk0 row-major
  bf16* VTs = p;     p += (size_t)64 * 64 * 1024; // self V^T
  bf16* VT0 = p;     p += (size_t)64 * 64 * 1024; // xv0 V^T
  bf16* QQK = p;     p += (size_t)2048 * 2048;   // qq|qk row-major
  bf16* VTq = p;     p += (size_t)64 * 64 * 512;  // qv V^T
  bf16* xat = p;     p += (size_t)4096 * 1024;   // (xat, qat adjacent -> proj A)
  bf16* qat = p;     p += (size_t)2048 * 1024;
  (void)wkvb;

  k_cast_all<<<2048, 256, 0, stream>>>(x, query, w_qkv, w_kv, w_qlin, w_proj, w_qproj,
                                       (bf16*)d_ws);

  // grouped big GEMM: XKV (320 blocks) + qlin (96 blocks), 8-phase schedule
  k_gemm_big<<<dim3(416), 512, 0, stream>>>(xb, qb, wqkvb, wqlinb,
                                            XK, VTs, VT0, QQK, VTq);

  k_attn<<<dim3(768), 256, 0, stream>>>(XK, QQK, VTs, VT0, VTq, gate, xat, qat);

  // fused output projections: A = [xat|qat] (6144x1024)
  k_gemm_proj<<<dim3(48 * 8), 256, 0, stream>>>(xat, wprojb, wqprojb, b_proj, b_qproj, out);
}

// Round 8
// 174.128 us; speedup vs baseline: 1.5880x; 1.0238x over previous
//
#include <hip/hip_runtime.h>

// DualAttention: B=4, N=1024, QN=512, C=1024, H=16, D=64
// bf16 MFMA everywhere, fp32 softmax (log2-domain). GEMM epilogues emit V
// pre-transposed. Big GEMMs: 256x256 tile, BK=64, 8-phase schedule, counted
// vmcnt(4). Attention: swapped QK^T, in-register softmax, T15 pipeline
// (QK(t) MFMA || PV(t-1) MFMA per iteration; P held packed in registers).

using bf16 = __bf16;
typedef __bf16 bf16x4 __attribute__((ext_vector_type(4)));
typedef __bf16 bf16x8 __attribute__((ext_vector_type(8)));
typedef float  f32x4  __attribute__((ext_vector_type(4)));
typedef float  f32x16 __attribute__((ext_vector_type(16)));
typedef unsigned int u32x4 __attribute__((ext_vector_type(4)));

#define MFMA16(a, b, c) __builtin_amdgcn_mfma_f32_16x16x32_bf16((a), (b), (c), 0, 0, 0)
#define MFMA32(a, b, c) __builtin_amdgcn_mfma_f32_32x32x16_bf16((a), (b), (c), 0, 0, 0)

// XOR swizzle for 128B LDS rows (8 granules of 16B).
__device__ __forceinline__ int swz128(int row) { return ((row ^ (row >> 3)) & 7) << 4; }

__device__ __forceinline__ void gl_lds16(const void* g, void* l) {
  __builtin_amdgcn_global_load_lds(
      (const __attribute__((address_space(1))) unsigned int*)g,
      (__attribute__((address_space(3))) unsigned int*)l, 16, 0, 0);
}

__device__ __forceinline__ unsigned pack2(float a, float b) {
  unsigned short ua = __builtin_bit_cast(unsigned short, (bf16)a);
  unsigned short ub = __builtin_bit_cast(unsigned short, (bf16)b);
  return (unsigned)ua | ((unsigned)ub << 16);
}

__device__ __forceinline__ float exp2_fast(float x) {  // v_exp_f32 IS 2^x
  float r;
  asm("v_exp_f32 %0, %1" : "=v"(r) : "v"(x));
  return r;
}

#define WAITV(N) asm volatile("s_waitcnt vmcnt(" #N ")" ::: "memory")
#define LGKM0()  asm volatile("s_waitcnt lgkmcnt(0)" ::: "memory")
#define SCHED0() __builtin_amdgcn_sched_barrier(0)
#define RAW_BAR() do { __builtin_amdgcn_s_barrier(); asm volatile("" ::: "memory"); } while (0)

// ---------------------------------------------------------------- fused cast fp32->bf16
// ws layout (elements, M = 1<<20): xb@0(4M) qb@4M(2M) wqkv@6M(3M) wkv@9M(2M)
// wqlin@11M(3M) wproj@14M(1M) wqproj@15M(1M). Must match kernel_launch.
__global__ void k_cast_all(const float* __restrict__ s0, const float* __restrict__ s1,
                           const float* __restrict__ s2, const float* __restrict__ s3,
                           const float* __restrict__ s4, const float* __restrict__ s5,
                           const float* __restrict__ s6, bf16* __restrict__ dst) {
  constexpr size_t MM = 1u << 20;
  constexpr size_t o1 = 4 * MM, o2 = 6 * MM, o3 = 9 * MM, o4 = 11 * MM,
                   o5 = 14 * MM, o6 = 15 * MM, total = 16 * MM;
  size_t stride = (size_t)gridDim.x * blockDim.x * 8;
  for (size_t i = ((size_t)blockIdx.x * blockDim.x + threadIdx.x) * 8; i < total; i += stride) {
    const float* s; size_t loc;
    if (i < o1)      { s = s0; loc = i; }
    else if (i < o2) { s = s1; loc = i - o1; }
    else if (i < o3) { s = s2; loc = i - o2; }
    else if (i < o4) { s = s3; loc = i - o3; }
    else if (i < o5) { s = s4; loc = i - o4; }
    else if (i < o6) { s = s5; loc = i - o5; }
    else             { s = s6; loc = i - o6; }
    float4 a = *(const float4*)(s + loc);
    float4 b = *(const float4*)(s + loc + 4);
    bf16x8 o;
    o[0] = (bf16)a.x; o[1] = (bf16)a.y; o[2] = (bf16)a.z; o[3] = (bf16)a.w;
    o[4] = (bf16)b.x; o[5] = (bf16)b.y; o[6] = (bf16)b.z; o[7] = (bf16)b.w;
    *(bf16x8*)(dst + i) = o;
  }
}

// ---------------------------------------------------------------- big grouped GEMM (8-phase)
// 256x256 tile, BK=64 (2 k-halves of 32), 512 threads (8 waves 2Mx4N).
// LDS: A,B each [2 buf][2 kh][256 rows][32 k] bf16 = 64 KB -> 128 KB total.
// Per tile j: 4 phases; each {ds_read frags | stage half-tile} -> barrier ->
// lgkmcnt(0) -> 16 MFMA -> barrier. Boundary: vmcnt(4).
// Groups: bid [0,320): XKV (xb x [wqkv|wkv], M=4096 N=5120);
//         bid [320,416): qlin (qb x wqlin, M=2048 N=3072).
__global__ __launch_bounds__(512)
void k_gemm_big(const bf16* __restrict__ xb, const bf16* __restrict__ qb,
                const bf16* __restrict__ wqkvb, const bf16* __restrict__ wqlinb,
                bf16* __restrict__ XK, bf16* __restrict__ VTs, bf16* __restrict__ VT0,
                bf16* __restrict__ QQK, bf16* __restrict__ VTq) {
  constexpr int K = 1024, NT = 16;
  __shared__ bf16 As[2 * 2 * 256 * 32];
  __shared__ bf16 Bs[2 * 2 * 256 * 32];
  const int tid = threadIdx.x;
  const int lane = tid & 63, w = tid >> 6;
  const int wm = w >> 2, wn = w & 3;
  const int r0 = lane & 15, kg = lane >> 4;
  const int bid = ((int)blockIdx.x & 7) * 52 + ((int)blockIdx.x >> 3);  // 416 = 8*52
  int grp, tm, tn;
  const bf16 *Ap, *Bp;
  if (bid < 320) { grp = 0; tm = (bid / 20) * 256; tn = (bid % 20) * 256; Ap = xb; Bp = wqkvb; }
  else { grp = 1; int t = bid - 320; tm = (t / 12) * 256; tn = (t % 12) * 256; Ap = qb; Bp = wqlinb; }

  auto stage = [&](int T, int mat, int kh) {
    const bf16* src = mat ? Bp : Ap;
    const int t0 = mat ? tn : tm;
    char* base = (char*)(mat ? (void*)Bs : (void*)As) + (((T & 1) * 2 + kh) << 14);
#pragma unroll
    for (int i = 0; i < 2; i++) {
      int c = i * 512 + tid;
      int row = c >> 2, g = c & 3;
      int sg = (g ^ ((row >> 1) & 3)) * 8;  // pre-swizzled source granule
      gl_lds16(src + (size_t)(t0 + row) * K + T * 64 + kh * 32 + sg, base + c * 16);
    }
  };
  auto ldA = [&](int bi, int kh, int row) -> bf16x8 {
    return *(const bf16x8*)((const char*)As + ((bi * 2 + kh) << 14) + row * 64 +
                            ((kg ^ ((row >> 1) & 3)) << 4));
  };
  auto ldB = [&](int bi, int kh, int row) -> bf16x8 {
    return *(const bf16x8*)((const char*)Bs + ((bi * 2 + kh) << 14) + row * 64 +
                            ((kg ^ ((row >> 1) & 3)) << 4));
  };

  f32x4 acc[8][4] = {};

  stage(0, 0, 0); stage(0, 1, 0); stage(0, 0, 1); stage(0, 1, 1);
  stage(1, 0, 0); stage(1, 1, 0);
  WAITV(4);
  RAW_BAR();

  for (int j = 0; j < NT; ++j) {
    const int bi = j & 1;
    bf16x8 af[4], bfk[4];
    // ---- phase 1: (mh0, kh0)
#pragma unroll
    for (int i = 0; i < 4; i++) af[i] = ldA(bi, 0, wm * 128 + i * 16 + r0);
#pragma unroll
    for (int nf = 0; nf < 4; nf++) bfk[nf] = ldB(bi, 0, wn * 64 + nf * 16 + r0);
    if (j + 1 < NT) stage(j + 1, 0, 1);
    RAW_BAR(); LGKM0(); SCHED0();
    __builtin_amdgcn_s_setprio(1);
#pragma unroll
    for (int i = 0; i < 4; i++)
#pragma unroll
      for (int nf = 0; nf < 4; nf++) acc[i][nf] = MFMA16(af[i], bfk[nf], acc[i][nf]);
    __builtin_amdgcn_s_setprio(0);
    RAW_BAR();
    // ---- phase 2: (mh1, kh0)
#pragma unroll
    for (int i = 0; i < 4; i++) af[i] = ldA(bi, 0, wm * 128 + 64 + i * 16 + r0);
    if (j + 1 < NT) stage(j + 1, 1, 1);
    RAW_BAR(); LGKM0(); SCHED0();
    __builtin_amdgcn_s_setprio(1);
#pragma unroll
    for (int i = 0; i < 4; i++)
#pragma unroll
      for (int nf = 0; nf < 4; nf++) acc[4 + i][nf] = MFMA16(af[i], bfk[nf], acc[4 + i][nf]);
    __builtin_amdgcn_s_setprio(0);
    RAW_BAR();
    // ---- phase 3: (mh0, kh1)
#pragma unroll
    for (int i = 0; i < 4; i++) af[i] = ldA(bi, 1, wm * 128 + i * 16 + r0);
#pragma unroll
    for (int nf = 0; nf < 4; nf++) bfk[nf] = ldB(bi, 1, wn * 64 + nf * 16 + r0);
    if (j + 2 < NT) stage(j + 2, 0, 0);
    RAW_BAR(); LGKM0(); SCHED0();
    __builtin_amdgcn_s_setprio(1);
#pragma unroll
    for (int i = 0; i < 4; i++)
#pragma unroll
      for (int nf = 0; nf < 4; nf++) acc[i][nf] = MFMA16(af[i], bfk[nf], acc[i][nf]);
    __builtin_amdgcn_s_setprio(0);
    RAW_BAR();
    // ---- phase 4: (mh1, kh1)
#pragma unroll
    for (int i = 0; i < 4; i++) af[i] = ldA(bi, 1, wm * 128 + 64 + i * 16 + r0);
    if (j + 2 < NT) stage(j + 2, 1, 0);
    RAW_BAR(); LGKM0(); SCHED0();
    __builtin_amdgcn_s_setprio(1);
#pragma unroll
    for (int i = 0; i < 4; i++)
#pragma unroll
      for (int nf = 0; nf < 4; nf++) acc[4 + i][nf] = MFMA16(af[i], bfk[nf], acc[4 + i][nf]);
    __builtin_amdgcn_s_setprio(0);
    if (j < NT - 2) { WAITV(4); } else { WAITV(0); }
    RAW_BAR();
  }

  // ---------------- epilogue (tn/tm uniform per block; ranges never straddle)
#pragma unroll
  for (int mf = 0; mf < 8; mf++) {
    const int rowb = tm + wm * 128 + mf * 16 + kg * 4;  // 4 consecutive rows (j)
#pragma unroll
    for (int nf = 0; nf < 4; nf++) {
      const int coln = tn + wn * 64 + nf * 16 + r0;
      bool rm; int rmcol = coln, vbase = 0, tokb = 10, rs_ = 3072;
      bf16* vt = VTs;
      bf16* rmp = XK;
      if (grp == 0) {
        if (tn < 2048)      { rm = true; }
        else if (tn < 3072) { rm = false; vbase = 2048; vt = VTs; }
        else if (tn < 4096) { rm = true; rmcol = coln - 1024; }
        else                { rm = false; vbase = 4096; vt = VT0; }
      } else {
        rs_ = 2048; tokb = 9; rmp = QQK;
        if (tn < 2048) { rm = true; }
        else           { rm = false; vbase = 2048; vt = VTq; }
      }
      if (rm) {
#pragma unroll
        for (int j = 0; j < 4; j++)
          rmp[(size_t)(rowb + j) * rs_ + rmcol] = (bf16)acc[mf][nf][j];
      } else {
        int dg = coln - vbase, h_ = dg >> 6, dd = dg & 63;
        int bq = rowb >> tokb, tok = rowb & ((1 << tokb) - 1);
        bf16x4 wv;
#pragma unroll
        for (int j = 0; j < 4; j++) wv[j] = (bf16)acc[mf][nf][j];
        *(bf16x4*)(vt + (((size_t)((bq * 16 + h_) * 64 + dd)) << tokb) + tok) = wv;
      }
    }
  }
}

// ---------------------------------------------------------------- proj GEMM (128x128, proven)
// C[6144,1024] = [xat|qat] x [w_proj|w_qproj]^T + bias, fp32 out to d_out.
__global__ __launch_bounds__(256)
void k_gemm_proj(const bf16* __restrict__ A, const bf16* __restrict__ B0,
                 const bf16* __restrict__ B1, const float* __restrict__ bias0,
                 const float* __restrict__ bias1, float* __restrict__ OUT) {
  constexpr int K = 1024, N = 1024;
  __shared__ bf16 As[128 * 64];
  __shared__ bf16 Bs[128 * 64];
  const int tid = threadIdx.x;
  const int lane = tid & 63, w = tid >> 6;
  const int wr = w >> 1, wc = w & 1;
  const int nbx = N / 128;
  const int bid = ((int)blockIdx.x & 7) * ((int)gridDim.x >> 3) + ((int)blockIdx.x >> 3);
  const int tm = (bid / nbx) * 128, tn = (bid % nbx) * 128;
  const int r0 = lane & 15, kg = lane >> 4;
  const bf16* Bp = (tm < 4096) ? B0 : B1;
  const float* bias = (tm < 4096) ? bias0 : bias1;
  f32x4 acc[4][4] = {};
  for (int kk = 0; kk < K; kk += 64) {
#pragma unroll
    for (int i = 0; i < 4; i++) {
      int c = i * 256 + tid;
      int row = c >> 3, kb = c & 7;
      int sb = (kb ^ ((row ^ (row >> 3)) & 7)) * 8;
      gl_lds16(A + (size_t)(tm + row) * K + kk + sb, (char*)As + c * 16);
      gl_lds16(Bp + (size_t)(tn + row) * K + kk + sb, (char*)Bs + c * 16);
    }
    __syncthreads();
#pragma unroll
    for (int ks = 0; ks < 2; ks++) {
      bf16x8 af[4], bfv[4];
#pragma unroll
      for (int f = 0; f < 4; f++) {
        int rowa = wr * 64 + f * 16 + r0;
        af[f] = *(const bf16x8*)((const char*)As +
                                 ((rowa * 128 + ks * 64 + kg * 16) ^ swz128(rowa)));
        int rowb = wc * 64 + f * 16 + r0;
        bfv[f] = *(const bf16x8*)((const char*)Bs +
                                  ((rowb * 128 + ks * 64 + kg * 16) ^ swz128(rowb)));
      }
#pragma unroll
      for (int mf = 0; mf < 4; mf++)
#pragma unroll
        for (int nf = 0; nf < 4; nf++)
          acc[mf][nf] = MFMA16(af[mf], bfv[nf], acc[mf][nf]);
    }
    __syncthreads();
  }
#pragma unroll
  for (int mf = 0; mf < 4; mf++)
#pragma unroll
    for (int j = 0; j < 4; j++) {
      int row = tm + wr * 64 + mf * 16 + kg * 4 + j;
#pragma unroll
      for (int nf = 0; nf < 4; nf++) {
        int col = tn + wc * 64 + nf * 16 + r0;
        OUT[(size_t)row * 1024 + col] = acc[mf][nf][j] + bias[col];
      }
    }
}

// ---------------------------------------------------------------- flash attention pass (T15)
// Iteration t computes QK^T(t) and PV(t-1) as independent MFMA streams; P(t)
// is packed into registers (pkp) and consumed next iteration. K double-buffer,
// V TRIPLE-buffer (PV lags one tile). One barrier/tile. Online softmax in
// log2-domain, tree reductions, defer-max THR=11.5. Ordering exactness: PV(t-1)
// lands in o before softmax(t)'s rescale multiplies o (compiler-enforced dep).
template<int NTH>
__device__ __forceinline__ void attn_pass32(
    const bf16* __restrict__ Kg, int kRS,
    const bf16* __restrict__ VTg, int vRS,
    int ntiles, const bf16x8* qf, bf16* Ks, bf16* Vt,  // Ks:[2][4096], Vt:[3][4096]
    f32x16* o, float& m, float& rs) {
  const int tid = threadIdx.x;
  const int lane = tid & 63;
  const int lq = lane & 31, kg2 = lane >> 5;

  auto stageKV = [&](int t) {
    bf16* kd = Ks + (t & 1) * 4096;
    bf16* vd = Vt + (t % 3) * 4096;
    const bf16* kt = Kg + (size_t)t * 64 * kRS;
#pragma unroll
    for (int i = 0; i < 512 / NTH; i++) {
      int c = i * NTH + tid;
      int r = c >> 3, kb = c & 7;
      int sb = (kb ^ ((r ^ (r >> 3)) & 7)) * 8;  // pre-swizzled source
      gl_lds16(kt + (size_t)r * kRS + sb, (char*)kd + c * 16);
    }
#pragma unroll
    for (int i = 0; i < 512 / NTH; i++) {
      int c = i * NTH + tid;
      int r = c >> 3, kb = c & 7;
      int sb = (kb ^ ((r ^ (r >> 3)) & 7)) * 8;
      gl_lds16(VTg + (size_t)r * vRS + t * 64 + sb, (char*)vd + c * 16);
    }
  };

  unsigned pkp[2][4][2];  // packed P of previous tile

  // QK^T + online softmax + pack -> pkp (pure function of staged K buffer)
  auto qk_softmax = [&](const char* KsC) {
    f32x16 s[2];
    s[0] = (f32x16)0.f; s[1] = (f32x16)0.f;
    __builtin_amdgcn_s_setprio(1);
#pragma unroll
    for (int kb = 0; kb < 2; kb++) {
      int row = kb * 32 + lq;
#pragma unroll
      for (int dw = 0; dw < 4; dw++) {
        bf16x8 kf = *(const bf16x8*)(KsC + ((row * 128 + dw * 32 + kg2 * 16) ^ swz128(row)));
        s[kb] = MFMA32(kf, qf[dw], s[kb]);
      }
    }
    __builtin_amdgcn_s_setprio(0);
    // tree max
    float mm[8];
#pragma unroll
    for (int j = 0; j < 8; j++)
      mm[j] = fmaxf(fmaxf(s[0][j], s[0][j + 8]), fmaxf(s[1][j], s[1][j + 8]));
    float a0 = fmaxf(mm[0], mm[1]), a1 = fmaxf(mm[2], mm[3]);
    float a2 = fmaxf(mm[4], mm[5]), a3 = fmaxf(mm[6], mm[7]);
    float vmax = fmaxf(fmaxf(a0, a1), fmaxf(a2, a3));
    vmax = fmaxf(vmax, __shfl_xor(vmax, 32, 64));
    if (__any(vmax > m + 11.5f)) {  // defer-max (log2 units)
      float mn = fmaxf(m, vmax);
      float fac = exp2_fast(m - mn);
      m = mn;
      rs *= fac;
#pragma unroll
      for (int j = 0; j < 16; j++) {
        int rowq = (j & 3) + 8 * (j >> 2) + 4 * kg2;
        float fj = __shfl(fac, rowq, 64);
        o[0][j] *= fj;
        o[1][j] *= fj;
      }
    }
    float t0 = 0.f, t1 = 0.f, t2 = 0.f, t3 = 0.f;
#pragma unroll
    for (int kb = 0; kb < 2; kb++)
#pragma unroll
      for (int j = 0; j < 16; j += 4) {
        float p0 = exp2_fast(s[kb][j + 0] - m);
        float p1 = exp2_fast(s[kb][j + 1] - m);
        float p2 = exp2_fast(s[kb][j + 2] - m);
        float p3 = exp2_fast(s[kb][j + 3] - m);
        s[kb][j + 0] = p0; s[kb][j + 1] = p1; s[kb][j + 2] = p2; s[kb][j + 3] = p3;
        t0 += p0; t1 += p1; t2 += p2; t3 += p3;
      }
    float tsum = (t0 + t1) + (t2 + t3);
    tsum += __shfl_xor(tsum, 32, 64);
    rs += tsum;
#pragma unroll
    for (int kb = 0; kb < 2; kb++)
#pragma unroll
      for (int n = 0; n < 4; n++) {
        pkp[kb][n][0] = pack2(s[kb][4 * n + 0], s[kb][4 * n + 1]);
        pkp[kb][n][1] = pack2(s[kb][4 * n + 2], s[kb][4 * n + 3]);
      }
  };

  // PV using pkp (previous tile's P) against a staged V^T buffer
  auto pv = [&](const char* VtC) {
#pragma unroll
    for (int w = 0; w < 4; w++) {
      const int kb = w >> 1, wb = w & 1;
      unsigned pushA = kg2 ? pkp[kb][2 * wb][0] : pkp[kb][2 * wb + 1][0];
      unsigned pushB = kg2 ? pkp[kb][2 * wb][1] : pkp[kb][2 * wb + 1][1];
      unsigned rcvA = __shfl_xor(pushA, 32, 64);
      unsigned rcvB = __shfl_xor(pushB, 32, 64);
      u32x4 fu;
      fu[0] = kg2 ? rcvA : pkp[kb][2 * wb][0];
      fu[1] = kg2 ? rcvB : pkp[kb][2 * wb][1];
      fu[2] = kg2 ? pkp[kb][2 * wb + 1][0] : rcvA;
      fu[3] = kg2 ? pkp[kb][2 * wb + 1][1] : rcvB;
      bf16x8 pfrag = __builtin_bit_cast(bf16x8, fu);
      __builtin_amdgcn_s_setprio(1);
#pragma unroll
      for (int db = 0; db < 2; db++) {
        int d = db * 32 + lq;
        bf16x8 vf = *(const bf16x8*)(VtC + ((d * 128 + w * 32 + kg2 * 16) ^ swz128(d)));
        o[db] = MFMA32(pfrag, vf, o[db]);
      }
      __builtin_amdgcn_s_setprio(0);
    }
  };

  RAW_BAR();  // entry: previous pass (if any) done reading this LDS
  stageKV(0);
  if (ntiles > 1) { stageKV(1); WAITV(4); } else { WAITV(0); }
  RAW_BAR();
  // tile 0: QK + softmax only (PV deferred)
  qk_softmax((const char*)(Ks + 0));

  for (int t = 1; t < ntiles; t++) {
    WAITV(0);   // stage(t) (issued last iteration) fully landed
    RAW_BAR();  // ...visible to all waves; all waves done with body(t-1) reads
    if (t + 1 < ntiles) stageKV(t + 1);  // overwrites Ks[(t-1)&1], Vt[(t+1)%3] (free)
    // body: QK(t) and PV(t-1) are independent MFMA streams (scheduler interleaves);
    // softmax(t) overlaps PV's shadow; rescale (rare) depends on o after PV lands.
    const char* KsC = (const char*)(Ks + (t & 1) * 4096);
    const char* VtP = (const char*)(Vt + ((t - 1) % 3) * 4096);
    pv(VtP);           // consumes pkp(t-1)
    qk_softmax(KsC);   // produces pkp(t); s-dep places it after QK MFMAs
  }
  // epilogue: PV of last tile
  pv((const char*)(Vt + ((ntiles - 1) % 3) * 4096));
}

// ---------------------------------------------------------------- merged attention
// grid = 768 blocks XCD-chunked: bid [0,512) self (bh = bid>>3, qtile = bid&7),
// bid [512,768) cross (bh = (bid-512)>>2, qtile = (bid-512)&3).
// XK[4096][3072]: cols q|k|xk0. QQK[2048][2048]: cols qq|qk.
// VTs/VT0: [bh][64][1024]; VTq: [bh][64][512].
__global__ __launch_bounds__(256)
void k_attn(const bf16* __restrict__ XK, const bf16* __restrict__ QQK,
            const bf16* __restrict__ VTs, const bf16* __restrict__ VT0,
            const bf16* __restrict__ VTq, const float* __restrict__ gate,
            bf16* __restrict__ xat, bf16* __restrict__ qat) {
  __shared__ bf16 Ks[2 * 4096], Vt[3 * 4096];
  const int pb = blockIdx.x;
  const int bid = (pb & 7) * 96 + (pb >> 3);  // 768 = 8 x 96 chunks
  const int tid = threadIdx.x, lane = tid & 63, wv = tid >> 6;
  const int lq = lane & 31, kg2 = lane >> 5;
  constexpr float QS = 0.125f * 1.44269504088896f;  // scale * log2(e)

  if (bid < 512) {
    // ---------------- self attention
    const int bh = bid >> 3, r = bid & 7;
    const int b = bh >> 4, h = bh & 15;
    const int qtok = b * 1024 + r * 128 + wv * 32;
    bf16x8 qf[4];
#pragma unroll
    for (int dw = 0; dw < 4; dw++) {
      qf[dw] = *(const bf16x8*)(XK + (size_t)(qtok + lq) * 3072 + h * 64 + dw * 16 + kg2 * 8);
#pragma unroll
      for (int e = 0; e < 8; e++) qf[dw][e] = (bf16)((float)qf[dw][e] * QS);
    }
    f32x16 o[2];
    o[0] = (f32x16)0.f; o[1] = (f32x16)0.f;
    float m = -__builtin_inff(), rs = 0.f;
    attn_pass32<256>(XK + (size_t)(b * 1024) * 3072 + 1024 + h * 64, 3072,
                     VTs + (size_t)bh * 64 * 1024, 1024,
                     16, qf, Ks, Vt, o, m, rs);
#pragma unroll
    for (int j = 0; j < 16; j++) {
      int rowq = (j & 3) + 8 * (j >> 2) + 4 * kg2;
      float rsj = __shfl(rs, rowq, 64);
      size_t base = (size_t)(qtok + rowq) * 1024 + h * 64;
      xat[base + lq] = (bf16)(o[0][j] / rsj);
      xat[base + 32 + lq] = (bf16)(o[1][j] / rsj);
    }
  } else {
    // ---------------- cross attention
    const int c = bid - 512;
    const int bh = c >> 2, qt = c & 3;
    const int b = bh >> 4, h = bh & 15;
    const int qtok = b * 512 + qt * 128 + wv * 32;
    bf16x8 qf[4];
#pragma unroll
    for (int dw = 0; dw < 4; dw++) {
      qf[dw] = *(const bf16x8*)(QQK + (size_t)(qtok + lq) * 2048 + h * 64 + dw * 16 + kg2 * 8);
#pragma unroll
      for (int e = 0; e < 8; e++) qf[dw][e] = (bf16)((float)qf[dw][e] * QS);
    }
    const float g = tanhf(gate[h]);  // block-uniform (zero-init param -> skip seg A)
    unsigned pka[2][8] = {};         // packed g*softmax(QK0)V0 result (seg A)
    f32x16 o[2];
    o[0] = (f32x16)0.f; o[1] = (f32x16)0.f;
    float m, rs;
    if (g != 0.0f) {
      m = -__builtin_inff(); rs = 0.f;
      attn_pass32<256>(XK + (size_t)(b * 1024) * 3072 + 2048 + h * 64, 3072,
                       VT0 + (size_t)bh * 64 * 1024, 1024,
                       16, qf, Ks, Vt, o, m, rs);
#pragma unroll
      for (int j2 = 0; j2 < 8; j2++) {
        int j0 = 2 * j2;
        int rq0 = (j0 & 3) + 8 * (j0 >> 2) + 4 * kg2;  // rq1 = rq0 + 1
        float ra = __shfl(rs, rq0, 64);
        float rb = __shfl(rs, rq0 + 1, 64);
        pka[0][j2] = pack2(g * o[0][j0] / ra, g * o[0][j0 + 1] / rb);
        pka[1][j2] = pack2(g * o[1][j0] / ra, g * o[1][j0 + 1] / rb);
      }
      o[0] = (f32x16)0.f; o[1] = (f32x16)0.f;
    }
    m = -__builtin_inff(); rs = 0.f;
    attn_pass32<256>(QQK + (size_t)(b * 512) * 2048 + 1024 + h * 64, 2048,
                     VTq + (size_t)bh * 64 * 512, 512,
                     8, qf, Ks, Vt, o, m, rs);
#pragma unroll
    for (int j = 0; j < 16; j++) {
      int rowq = (j & 3) + 8 * (j >> 2) + 4 * kg2;
      float rsj = __shfl(rs, rowq, 64);
      size_t base = (size_t)(qtok + rowq) * 1024 + h * 64;
      unsigned wa = pka[0][j >> 1], wb = pka[1][j >> 1];
      unsigned short ua = (j & 1) ? (unsigned short)(wa >> 16) : (unsigned short)(wa & 0xffffu);
      unsigned short ub = (j & 1) ? (unsigned short)(wb >> 16) : (unsigned short)(wb & 0xffffu);
      float a0 = (float)__builtin_bit_cast(bf16, ua);
      float a1 = (float)__builtin_bit_cast(bf16, ub);
      qat[base + lq] = (bf16)(o[0][j] / rsj + a0);
      qat[base + 32 + lq] = (bf16)(o[1][j] / rsj + a1);
    }
  }
}

// ---------------------------------------------------------------- launch
extern "C" void kernel_launch(void* const* d_in, const int* in_sizes, int n_in,
                              void* d_out, int out_size, void* d_ws, size_t ws_size,
                              hipStream_t stream) {
  (void)in_sizes; (void)n_in; (void)out_size; (void)ws_size;
  const float* x       = (const float*)d_in[0];
  const float* query   = (const float*)d_in[1];
  const float* w_qkv   = (const float*)d_in[2];
  const float* w_kv    = (const float*)d_in[3];
  const float* w_qlin  = (const float*)d_in[4];
  const float* gate    = (const float*)d_in[5];
  const float* w_proj  = (const float*)d_in[6];
  const float* b_proj  = (const float*)d_in[7];
  const float* w_qproj = (const float*)d_in[8];
  const float* b_qproj = (const float*)d_in[9];
  float* out = (float*)d_out;

  bf16* p = (bf16*)d_ws;
  bf16* xb = p;      p += (size_t)4096 * 1024;   // 4M @ 0
  bf16* qb = p;      p += (size_t)2048 * 1024;   // 2M @ 4M
  bf16* wqkvb = p;   p += (size_t)3072 * 1024;   // 3M @ 6M (adjacent to wkvb)
  bf16* wkvb = p;    p += (size_t)2048 * 1024;   // 2M @ 9M
  bf16* wqlinb = p;  p += (size_t)3072 * 1024;   // 3M @ 11M
  bf16* wprojb = p;  p += (size_t)1024 * 1024;   // 1M @ 14M
  bf16* wqprojb = p; p += (size_t)1024 * 1024;   // 1M @ 15M
  bf16* XK = p;      p += (size_t)4096 * 3072;   // q|k|xk0 row-major
  bf16* VTs = p;     p += (size_t)64 * 64 * 1024; // self V^T
  bf16* VT0 = p;     p += (size_t)64 * 64 * 1024; // xv0 V^T
  bf16* QQK = p;     p += (size_t)2048 * 2048;   // qq|qk row-major
  bf16* VTq = p;     p += (size_t)64 * 64 * 512;  // qv V^T
  bf16* xat = p;     p += (size_t)4096 * 1024;   // (xat, qat adjacent -> proj A)
  bf16* qat = p;     p += (size_t)2048 * 1024;
  (void)wkvb;

  k_cast_all<<<2048, 256, 0, stream>>>(x, query, w_qkv, w_kv, w_qlin, w_proj, w_qproj,
                                       (bf16*)d_ws);

  // grouped big GEMM: XKV (320 blocks) + qlin (96 blocks), 8-phase schedule
  k_gemm_big<<<dim3(416), 512, 0, stream>>>(xb, qb, wqkvb, wqlinb,
                                            XK, VTs, VT0, QQK, VTq);

  k_attn<<<dim3(768), 256, 0, stream>>>(XK, QQK, VTs, VT0, VTq, gate, xat, qat);

  // fused output projections: A = [xat|qat] (6144x1024)
  k_gemm_proj<<<dim3(48 * 8), 256, 0, stream>>>(xat, wprojb, wqprojb, b_proj, b_qproj, out);
}